// Round 1
// baseline (3391.800 us; speedup 1.0000x reference)
//
#include <hip/hip_runtime.h>
#include <math.h>

#define FEATD 128
#define DIM 64
#define NB 256

__device__ __forceinline__ float sigmoidf_(float x){ return 1.f/(1.f+__expf(-x)); }

__device__ __forceinline__ int lower_bound_i(const int* __restrict__ a, int n, int key){
  int lo=0, hi=n;
  while(lo<hi){ int mid=(lo+hi)>>1; if(a[mid]<key) lo=mid+1; else hi=mid; }
  return lo;
}

// ---- GCN norm: degree count (col targets, excl self-loop) ----
__global__ void k_count(const int* __restrict__ col, int* __restrict__ deg, int E){
  int i=blockIdx.x*blockDim.x+threadIdx.x;
  if(i<E) atomicAdd(&deg[col[i]],1);
}

__global__ void k_dinv(const int* __restrict__ deg, float* __restrict__ dinv, int n){
  int i=blockIdx.x*blockDim.x+threadIdx.x;
  if(i<n) dinv[i]=rsqrtf((float)(deg[i]+1)); // +1 self-loop
}

// ---- exclusive scan of deg -> row_ptr (single block) ----
__global__ __launch_bounds__(1024) void k_scan(const int* __restrict__ deg, int* __restrict__ rp, int n){
  __shared__ int s[1024];
  int t=threadIdx.x;
  int chunk=(n+1023)>>10;
  int lo=t*chunk, hi=min(lo+chunk,n);
  int acc=0;
  for(int i=lo;i<hi;i++) acc+=deg[i];
  s[t]=acc; __syncthreads();
  for(int off=1;off<1024;off<<=1){
    int v=(t>=off)? s[t-off]:0;
    __syncthreads();
    s[t]+=v;
    __syncthreads();
  }
  int pre=(t>0)? s[t-1]:0;
  for(int i=lo;i<hi;i++){ rp[i]=pre; pre+=deg[i]; }
  if(t==1023) rp[n]=s[1023];
}

// ---- CSR fill (keyed by col/target), stores src + norm ----
__global__ void k_fill(const int* __restrict__ row, const int* __restrict__ col,
                       const float* __restrict__ dinv, const int* __restrict__ rp,
                       int* __restrict__ fill, int* __restrict__ csrc, float* __restrict__ cnorm, int E){
  int i=blockIdx.x*blockDim.x+threadIdx.x;
  if(i>=E) return;
  int r=row[i], c=col[i];
  int pos=atomicAdd(&fill[c],1);
  int idx=rp[c]+pos;
  csrc[idx]=r;
  cnorm[idx]=dinv[r]*dinv[c];
}

// ---- row GEMM: Y[n,0:64] = act(X[n,:K] @ W[K,64] (+bias)) ----
template<int K, bool BIAS_RELU>
__global__ __launch_bounds__(256) void k_rowgemm(const float* __restrict__ X, const float* __restrict__ W,
                                                 const float* __restrict__ bias, float* __restrict__ Y, int n){
  __shared__ float Ws[K*64];
  __shared__ float Xs[4][K];
  for(int i=threadIdx.x;i<K*64;i+=256) Ws[i]=W[i];
  int lane=threadIdx.x&63, grp=threadIdx.x>>6;
  int ngrp=(n+3)>>2;
  for(int g=blockIdx.x; g<ngrp; g+=gridDim.x){
    __syncthreads();
    for(int i=threadIdx.x;i<4*K;i+=256){
      int ln=i/K, kk=i%K; int node=g*4+ln;
      Xs[ln][kk]=(node<n)? X[(size_t)node*K+kk]:0.f;
    }
    __syncthreads();
    int node=g*4+grp;
    if(node<n){
      float acc = BIAS_RELU? bias[lane]:0.f;
      #pragma unroll
      for(int k=0;k<K;k++) acc += Xs[grp][k]*Ws[k*64+lane];
      Y[(size_t)node*64+lane] = BIAS_RELU? fmaxf(acc,0.f):acc;
    }
  }
}

// ---- gather-aggregate: m = relu(segment_sum(norm*hw[src]) + selfloop + conv_b) ----
__global__ __launch_bounds__(256) void k_aggregate(const float* __restrict__ hw, const int* __restrict__ rp,
                        const int* __restrict__ csrc, const float* __restrict__ cnorm,
                        const float* __restrict__ dinv, const float* __restrict__ cb,
                        float* __restrict__ m, int n){
  int node=blockIdx.x*4+(threadIdx.x>>6);
  int lane=threadIdx.x&63;
  if(node>=n) return;
  float dv=dinv[node];
  float acc=dv*dv*hw[(size_t)node*64+lane];
  int s=rp[node], e=rp[node+1];
  for(int j=s;j<e;j++){
    acc += cnorm[j]*hw[(size_t)csrc[j]*64+lane];
  }
  m[(size_t)node*64+lane]=fmaxf(acc+cb[lane],0.f);
}

// ---- fused GRU cell: h = GRU(m, h). Weights staged in LDS (pad+1 rows). ----
__global__ __launch_bounds__(256) void k_gru(const float* __restrict__ m, float* __restrict__ h,
                  const float* __restrict__ wih, const float* __restrict__ whh,
                  const float* __restrict__ bih, const float* __restrict__ bhh, int n){
  __shared__ float wi[192*65];
  __shared__ float wh[192*65];
  __shared__ float ms[16][64];
  __shared__ float hs[16][64];
  for(int i=threadIdx.x;i<192*64;i+=256){
    int g=i>>6,k=i&63;
    wi[g*65+k]=wih[i];
    wh[g*65+k]=whh[i];
  }
  int lane=threadIdx.x&63, w=threadIdx.x>>6;
  float br  = bih[lane]    + bhh[lane];
  float bz  = bih[64+lane] + bhh[64+lane];
  float bni = bih[128+lane];
  float bnh = bhh[128+lane];
  int ngrp=(n+15)>>4;
  for(int g=blockIdx.x; g<ngrp; g+=gridDim.x){
    int base=g*16;
    __syncthreads();
    for(int i=threadIdx.x;i<1024;i+=256){
      int ln=i>>6, k=i&63; int node=base+ln;
      ms[ln][k]=(node<n)? m[(size_t)node*64+k]:0.f;
      hs[ln][k]=(node<n)? h[(size_t)node*64+k]:0.f;
    }
    __syncthreads();
    float gr[4]={0,0,0,0}, gz[4]={0,0,0,0}, gn[4]={0,0,0,0};
    float ur[4]={0,0,0,0}, uz[4]={0,0,0,0}, un[4]={0,0,0,0};
    int w4=w*4;
    for(int k=0;k<64;k++){
      float a0=wi[lane*65+k], a1=wi[(64+lane)*65+k], a2=wi[(128+lane)*65+k];
      float c0=wh[lane*65+k], c1=wh[(64+lane)*65+k], c2=wh[(128+lane)*65+k];
      #pragma unroll
      for(int j=0;j<4;j++){
        float mk=ms[w4+j][k], hk=hs[w4+j][k];
        gr[j]+=a0*mk; gz[j]+=a1*mk; gn[j]+=a2*mk;
        ur[j]+=c0*hk; uz[j]+=c1*hk; un[j]+=c2*hk;
      }
    }
    #pragma unroll
    for(int j=0;j<4;j++){
      int node=base+w4+j;
      if(node<n){
        float r =sigmoidf_(gr[j]+ur[j]+br);
        float z =sigmoidf_(gz[j]+uz[j]+bz);
        float nc=tanhf(gn[j]+bni + r*(un[j]+bnh));
        float hold=hs[w4+j][lane];
        h[(size_t)node*64+lane]=(1.f-z)*nc+z*hold;
      }
    }
  }
}

// ---- Set2Set LSTM cell, block per graph ----
__global__ __launch_bounds__(256) void k_lstm(float* __restrict__ qstar, float* __restrict__ hl, float* __restrict__ cl,
                   const float* __restrict__ wih, const float* __restrict__ whh,
                   const float* __restrict__ bih, const float* __restrict__ bhh){
  int b=blockIdx.x, j=threadIdx.x;
  __shared__ float qs[128];
  __shared__ float hsh[64];
  __shared__ float gates[256];
  if(j<128) qs[j]=qstar[b*128+j];
  else if(j<192) hsh[j-128]=hl[b*64+(j-128)];
  __syncthreads();
  float acc=bih[j]+bhh[j];
  const float* wi=wih+(size_t)j*128;
  #pragma unroll 8
  for(int k=0;k<128;k++) acc+=qs[k]*wi[k];
  const float* w2=whh+(size_t)j*64;
  #pragma unroll 8
  for(int k=0;k<64;k++) acc+=hsh[k]*w2[k];
  gates[j]=acc;
  __syncthreads();
  if(j<64){
    float i_=gates[j], f_=gates[64+j], g_=gates[128+j], o_=gates[192+j];
    float c=sigmoidf_(f_)*cl[b*64+j]+sigmoidf_(i_)*tanhf(g_);
    float hn=sigmoidf_(o_)*tanhf(c);
    cl[b*64+j]=c; hl[b*64+j]=hn;
    qstar[b*128+j]=hn;
  }
}

// ---- attention: e[n] = dot(out[n], q[batch[n]]), per-graph max ----
__global__ __launch_bounds__(256) void k_attn_emax(const float* __restrict__ out, const float* __restrict__ hl,
                        const int* __restrict__ batch, float* __restrict__ e, float* __restrict__ emax, int n){
  int b=blockIdx.x;
  __shared__ float qs[64];
  __shared__ float wmax[4];
  int tid=threadIdx.x, lane=tid&63, w=tid>>6;
  if(tid<64) qs[tid]=hl[b*64+tid];
  int lo=lower_bound_i(batch,n,b), hi=lower_bound_i(batch,n,b+1);
  __syncthreads();
  float mx=-1e30f;
  for(int i=lo+w;i<hi;i+=4){
    float v=out[(size_t)i*64+lane]*qs[lane];
    #pragma unroll
    for(int off=32;off;off>>=1) v+=__shfl_xor(v,off);
    if(lane==0) e[i]=v;
    mx=fmaxf(mx,v);
  }
  if(lane==0) wmax[w]=mx;
  __syncthreads();
  if(tid==0){
    float m2=fmaxf(fmaxf(wmax[0],wmax[1]),fmaxf(wmax[2],wmax[3]));
    emax[b]=(hi>lo)? m2:0.f;
  }
}

// ---- attention: denom + weighted read -> q_star[b, 64:128] ----
__global__ __launch_bounds__(256) void k_attn_read(const float* __restrict__ out, const int* __restrict__ batch,
                        const float* __restrict__ e, const float* __restrict__ emax,
                        float* __restrict__ qstar, int n){
  int b=blockIdx.x, tid=threadIdx.x, lane=tid&63, w=tid>>6;
  int lo=lower_bound_i(batch,n,b), hi=lower_bound_i(batch,n,b+1);
  float em=emax[b];
  __shared__ float red[256];
  float s=0.f;
  for(int i=lo+tid;i<hi;i+=256) s+=__expf(e[i]-em);
  red[tid]=s; __syncthreads();
  for(int off=128;off;off>>=1){
    if(tid<off) red[tid]+=red[tid+off];
    __syncthreads();
  }
  float inv=(hi>lo && red[0]>0.f)? 1.f/red[0]:0.f;
  float acc=0.f;
  for(int i=lo+w;i<hi;i+=4){
    float a=__expf(e[i]-em)*inv;
    acc+=a*out[(size_t)i*64+lane];
  }
  __shared__ float part[4][64];
  part[w][lane]=acc; __syncthreads();
  if(tid<64){
    qstar[b*128+64+tid]=part[0][tid]+part[1][tid]+part[2][tid]+part[3][tid];
  }
}

extern "C" void kernel_launch(void* const* d_in, const int* in_sizes, int n_in,
                              void* d_out, int out_size, void* d_ws, size_t ws_size,
                              hipStream_t stream){
  const float* x      =(const float*)d_in[0];
  const int*   ei     =(const int*)d_in[1];
  const int*   batch  =(const int*)d_in[2];
  const float* lin0_w =(const float*)d_in[3];
  const float* lin0_b =(const float*)d_in[4];
  const float* conv_w =(const float*)d_in[5];
  const float* conv_b =(const float*)d_in[6];
  const float* gwih   =(const float*)d_in[7];
  const float* gwhh   =(const float*)d_in[8];
  const float* gbih   =(const float*)d_in[9];
  const float* gbhh   =(const float*)d_in[10];
  const float* lwih   =(const float*)d_in[11];
  const float* lwhh   =(const float*)d_in[12];
  const float* lbih   =(const float*)d_in[13];
  const float* lbhh   =(const float*)d_in[14];

  int N = in_sizes[0]/FEATD;
  int E = in_sizes[1]/2;
  const int* row = ei;
  const int* col = ei + E;

  float* qstar = (float*)d_out;            // [256,128] — final q_star output
  float* h     = (float*)d_out + NB*2*DIM; // [N,64] 'feat' region doubles as h/out buffer

  char* ws=(char*)d_ws;
  size_t off=0;
  auto alloc=[&](size_t bytes)->void*{ void* p=ws+off; off=(off+bytes+255)&~(size_t)255; return p; };
  int*   deg  =(int*)  alloc((size_t)N*4);
  float* dinv =(float*)alloc((size_t)N*4);
  int*   rp   =(int*)  alloc((size_t)(N+1)*4);
  int*   fill =(int*)  alloc((size_t)N*4);
  int*   csrc =(int*)  alloc((size_t)E*4);
  float* cnorm=(float*)alloc((size_t)E*4);
  float* hw   =(float*)alloc((size_t)N*64*4);
  float* m    =(float*)alloc((size_t)N*64*4);
  float* e    =(float*)alloc((size_t)N*4);
  float* emax =(float*)alloc((size_t)NB*4);
  float* hl   =(float*)alloc((size_t)NB*DIM*4);
  float* cl   =(float*)alloc((size_t)NB*DIM*4);

  hipMemsetAsync(deg ,0,(size_t)N*4,stream);
  hipMemsetAsync(fill,0,(size_t)N*4,stream);
  hipMemsetAsync(hl  ,0,(size_t)NB*DIM*4,stream);
  hipMemsetAsync(cl  ,0,(size_t)NB*DIM*4,stream);
  hipMemsetAsync(qstar,0,(size_t)NB*2*DIM*4,stream);

  k_count<<<(E+255)/256,256,0,stream>>>(col,deg,E);
  k_dinv <<<(N+255)/256,256,0,stream>>>(deg,dinv,N);
  k_scan <<<1,1024,0,stream>>>(deg,rp,N);
  k_fill <<<(E+255)/256,256,0,stream>>>(row,col,dinv,rp,fill,csrc,cnorm,E);

  k_rowgemm<128,true><<<2048,256,0,stream>>>(x,lin0_w,lin0_b,h,N);

  for(int it=0;it<3;it++){
    k_rowgemm<64,false><<<2048,256,0,stream>>>(h,conv_w,nullptr,hw,N);
    k_aggregate<<<(N+3)/4,256,0,stream>>>(hw,rp,csrc,cnorm,dinv,conv_b,m,N);
    k_gru<<<1024,256,0,stream>>>(m,h,gwih,gwhh,gbih,gbhh,N);
  }

  for(int st=0;st<3;st++){
    k_lstm     <<<NB,256,0,stream>>>(qstar,hl,cl,lwih,lwhh,lbih,lbhh);
    k_attn_emax<<<NB,256,0,stream>>>(h,hl,batch,e,emax,N);
    k_attn_read<<<NB,256,0,stream>>>(h,batch,e,emax,qstar,N);
  }
}

// Round 2
// 1766.839 us; speedup vs baseline: 1.9197x; 1.9197x over previous
//
#include <hip/hip_runtime.h>
#include <math.h>

#define FEATD 128
#define DIM 64
#define NB 256

typedef short bf16x8 __attribute__((ext_vector_type(8)));
typedef float f32x4 __attribute__((ext_vector_type(4)));

__device__ __forceinline__ float sigmoidf_(float x){ return 1.f/(1.f+__expf(-x)); }

__device__ __forceinline__ unsigned short f2bf(float f){
  unsigned u = __float_as_uint(f);
  unsigned r = (u + 0x7FFFu + ((u>>16)&1u)) >> 16;
  return (unsigned short)r;
}
__device__ __forceinline__ float bf2f(unsigned short s){
  return __uint_as_float(((unsigned)s)<<16);
}

__device__ __forceinline__ int lower_bound_i(const int* __restrict__ a, int n, int key){
  int lo=0, hi=n;
  while(lo<hi){ int mid=(lo+hi)>>1; if(a[mid]<key) lo=mid+1; else hi=mid; }
  return lo;
}

// ======================= CSR setup =======================
__global__ void k_count(const int* __restrict__ col, int* __restrict__ deg, int E){
  int i=blockIdx.x*blockDim.x+threadIdx.x;
  if(i<E) atomicAdd(&deg[col[i]],1);
}

__global__ void k_dinv(const int* __restrict__ deg, float* __restrict__ dinv, int n){
  int i=blockIdx.x*blockDim.x+threadIdx.x;
  if(i<n) dinv[i]=rsqrtf((float)(deg[i]+1)); // +1 self-loop
}

__global__ __launch_bounds__(1024) void k_scan(const int* __restrict__ deg, int* __restrict__ rp, int n){
  __shared__ int s[1024];
  int t=threadIdx.x;
  int chunk=(n+1023)>>10;
  int lo=t*chunk, hi=min(lo+chunk,n);
  int acc=0;
  for(int i=lo;i<hi;i++) acc+=deg[i];
  s[t]=acc; __syncthreads();
  for(int off=1;off<1024;off<<=1){
    int v=(t>=off)? s[t-off]:0;
    __syncthreads();
    s[t]+=v;
    __syncthreads();
  }
  int pre=(t>0)? s[t-1]:0;
  for(int i=lo;i<hi;i++){ rp[i]=pre; pre+=deg[i]; }
  if(t==1023) rp[n]=s[1023];
}

__global__ void k_fill(const int* __restrict__ row, const int* __restrict__ col,
                       const float* __restrict__ dinv, const int* __restrict__ rp,
                       int* __restrict__ fill, int* __restrict__ csrc, float* __restrict__ cnorm, int E){
  int i=blockIdx.x*blockDim.x+threadIdx.x;
  if(i>=E) return;
  int r=row[i], c=col[i];
  int pos=atomicAdd(&fill[c],1);
  int idx=rp[c]+pos;
  csrc[idx]=r;
  cnorm[idx]=dinv[r]*dinv[c];
}

// ======================= MFMA B-fragment prep =======================
// Fragment convention (mfma_f32_16x16x32_bf16):
//   A: lane l holds row (l&15), k = s*32 + (l>>4)*8 + r   (r=0..7)
//   B: lane l holds col (l&15), k = s*32 + (l>>4)*8 + r
//   D: lane l holds col (l&15), row = (l>>4)*4 + reg
// B frags stored flat: Bf[((t*S + s)*64 + lane)*8 + r] = W[k][c], t=c/16, S=K/32.

__global__ void k_prep_plain(const float* __restrict__ W, unsigned short* __restrict__ Bf, int K, int C){
  int i=blockIdx.x*blockDim.x+threadIdx.x;
  if(i>=K*C) return;
  int k=i/C, c=i%C;
  int t=c>>4, s=k>>5, lane=(c&15)|(((k>>3)&3)<<4), r=k&7;
  int S=K>>5;
  Bf[(((t*S)+s)*64+lane)*8+r]=f2bf(W[(size_t)k*C+c]);
}

// Assembled GRU weights: X=[m|h] (K=128), cols: [0,64)=r-preact, [64,128)=z-preact,
// [128,192)=in_ (m only), [192,256)=hn (h only). gate rows in w_ih/w_hh: r=0..63, z=64..127, n=128..191.
__global__ void k_prep_gru(const float* __restrict__ wih, const float* __restrict__ whh,
                           unsigned short* __restrict__ Bf){
  int i=blockIdx.x*blockDim.x+threadIdx.x;
  if(i>=128*256) return;
  int k=i>>8, c=i&255;
  float v;
  if(c<128){          // r,z: g=c
    v = (k<64) ? wih[c*64+k] : whh[c*64+(k-64)];
  } else if(c<192){   // in_: g=c
    v = (k<64) ? wih[c*64+k] : 0.f;
  } else {            // hn: g=c-64
    v = (k<64) ? 0.f : whh[(c-64)*64+(k-64)];
  }
  int t=c>>4, s=k>>5, lane=(c&15)|(((k>>3)&3)<<4), r=k&7;
  Bf[(((t*4)+s)*64+lane)*8+r]=f2bf(v);
}

// ======================= lin0: h = relu(x @ W + b), also h->bf16 into Abuf[:,64:128] ===================
__global__ __launch_bounds__(256) void k_lin0(const float* __restrict__ x, const unsigned short* __restrict__ Bf,
                      const float* __restrict__ bias, float* __restrict__ h,
                      unsigned short* __restrict__ Abuf, int ngrp){
  int l=threadIdx.x&63;
  int g=blockIdx.x*4+(threadIdx.x>>6);
  if(g>=ngrp) return;
  int row16=l&15, koff=(l>>4)*8;
  f32x4 acc[4]={};
  const float* xr = x + (size_t)(g*16+row16)*128 + koff;
  #pragma unroll
  for(int s=0;s<4;s++){
    f32x4 a0=*(const f32x4*)(xr+s*32);
    f32x4 a1=*(const f32x4*)(xr+s*32+4);
    bf16x8 af;
    #pragma unroll
    for(int r=0;r<4;r++){ af[r]=(short)f2bf(a0[r]); af[4+r]=(short)f2bf(a1[r]); }
    #pragma unroll
    for(int t=0;t<4;t++){
      bf16x8 bf=*(const bf16x8*)(Bf+(((t*4)+s)*64+l)*8);
      acc[t]=__builtin_amdgcn_mfma_f32_16x16x32_bf16(af,bf,acc[t],0,0,0);
    }
  }
  int rbase=g*16+(l>>4)*4;
  #pragma unroll
  for(int t=0;t<4;t++){
    int c=t*16+(l&15);
    float b=bias[c];
    #pragma unroll
    for(int j=0;j<4;j++){
      int node=rbase+j;
      float v=fmaxf(acc[t][j]+b,0.f);
      h[(size_t)node*64+c]=v;
      Abuf[(size_t)node*128+64+c]=f2bf(v);
    }
  }
}

// ======================= conv: hw(bf16) = h(bf16) @ conv_w =======================
__global__ __launch_bounds__(256) void k_conv(const unsigned short* __restrict__ Abuf, const unsigned short* __restrict__ Bf,
                      unsigned short* __restrict__ hw, int ngrp){
  int l=threadIdx.x&63;
  int g=blockIdx.x*4+(threadIdx.x>>6);
  if(g>=ngrp) return;
  int row16=l&15, koff=(l>>4)*8;
  f32x4 acc[4]={};
  const unsigned short* ar = Abuf + (size_t)(g*16+row16)*128 + 64 + koff;
  #pragma unroll
  for(int s=0;s<2;s++){
    bf16x8 af=*(const bf16x8*)(ar+s*32);
    #pragma unroll
    for(int t=0;t<4;t++){
      bf16x8 bf=*(const bf16x8*)(Bf+(((t*2)+s)*64+l)*8);
      acc[t]=__builtin_amdgcn_mfma_f32_16x16x32_bf16(af,bf,acc[t],0,0,0);
    }
  }
  int rbase=g*16+(l>>4)*4;
  #pragma unroll
  for(int t=0;t<4;t++){
    int c=t*16+(l&15);
    #pragma unroll
    for(int j=0;j<4;j++){
      hw[(size_t)(rbase+j)*64+c]=f2bf(acc[t][j]);
    }
  }
}

// ======================= aggregate: m(bf16 into Abuf[:,0:64]) = relu(segsum(norm*hw[src]) + selfloop + cb) =========
__global__ __launch_bounds__(256) void k_aggregate(const unsigned short* __restrict__ hw, const int* __restrict__ rp,
                        const int* __restrict__ csrc, const float* __restrict__ cnorm,
                        const float* __restrict__ dinv, const float* __restrict__ cb,
                        unsigned short* __restrict__ Abuf, int n){
  int node=blockIdx.x*4+(threadIdx.x>>6);
  int lane=threadIdx.x&63;
  if(node>=n) return;
  float dv=dinv[node];
  float acc=dv*dv*bf2f(hw[(size_t)node*64+lane]);
  int s=rp[node], e=rp[node+1];
  for(int j=s;j<e;j++){
    acc += cnorm[j]*bf2f(hw[(size_t)csrc[j]*64+lane]);
  }
  Abuf[(size_t)node*128+lane]=f2bf(fmaxf(acc+cb[lane],0.f));
}

// ======================= fused GRU: one [N,128]@[128,256] MFMA GEMM + in-register gates ===================
__global__ __launch_bounds__(256) void k_gru(unsigned short* Abuf, const unsigned short* __restrict__ Bf,
                     const float* __restrict__ bih, const float* __restrict__ bhh,
                     float* h, int ngrp){
  int l=threadIdx.x&63;
  int g=blockIdx.x*4+(threadIdx.x>>6);
  if(g>=ngrp) return;
  int row16=l&15, koff=(l>>4)*8;
  f32x4 acc[16]={};
  const unsigned short* ar = Abuf + (size_t)(g*16+row16)*128 + koff;
  #pragma unroll
  for(int s=0;s<4;s++){
    bf16x8 af=*(const bf16x8*)(ar+s*32);
    #pragma unroll
    for(int t=0;t<16;t++){
      bf16x8 bf=*(const bf16x8*)(Bf+(((t*4)+s)*64+l)*8);
      acc[t]=__builtin_amdgcn_mfma_f32_16x16x32_bf16(af,bf,acc[t],0,0,0);
    }
  }
  int rbase=g*16+(l>>4)*4;
  #pragma unroll
  for(int t=0;t<4;t++){
    int d=t*16+(l&15);
    float br =bih[d]    +bhh[d];
    float bz =bih[64+d] +bhh[64+d];
    float bni=bih[128+d];
    float bnh=bhh[128+d];
    #pragma unroll
    for(int j=0;j<4;j++){
      int node=rbase+j;
      float r  = sigmoidf_(acc[t][j]   + br);
      float z  = sigmoidf_(acc[4+t][j] + bz);
      float nc = tanhf(acc[8+t][j] + bni + r*(acc[12+t][j] + bnh));
      float hold = h[(size_t)node*64+d];
      float hn = (1.f-z)*nc + z*hold;
      h[(size_t)node*64+d]=hn;
      Abuf[(size_t)node*128+64+d]=f2bf(hn);
    }
  }
}

// ======================= Set2Set =======================
__global__ __launch_bounds__(256) void k_lstm(float* __restrict__ qstar, float* __restrict__ hl, float* __restrict__ cl,
                   const float* __restrict__ wih, const float* __restrict__ whh,
                   const float* __restrict__ bih, const float* __restrict__ bhh){
  int b=blockIdx.x, j=threadIdx.x;
  __shared__ float qs[128];
  __shared__ float hsh[64];
  __shared__ float gates[256];
  if(j<128) qs[j]=qstar[b*128+j];
  else if(j<192) hsh[j-128]=hl[b*64+(j-128)];
  __syncthreads();
  float acc=bih[j]+bhh[j];
  const float* wi=wih+(size_t)j*128;
  #pragma unroll 8
  for(int k=0;k<128;k++) acc+=qs[k]*wi[k];
  const float* w2=whh+(size_t)j*64;
  #pragma unroll 8
  for(int k=0;k<64;k++) acc+=hsh[k]*w2[k];
  gates[j]=acc;
  __syncthreads();
  if(j<64){
    float i_=gates[j], f_=gates[64+j], g_=gates[128+j], o_=gates[192+j];
    float c=sigmoidf_(f_)*cl[b*64+j]+sigmoidf_(i_)*tanhf(g_);
    float hn=sigmoidf_(o_)*tanhf(c);
    cl[b*64+j]=c; hl[b*64+j]=hn;
    qstar[b*128+j]=hn;
  }
}

// attention reads the bf16 copy of h from Abuf[:,64:128]
__global__ __launch_bounds__(256) void k_attn_emax(const unsigned short* __restrict__ Abuf, const float* __restrict__ hl,
                        const int* __restrict__ batch, float* __restrict__ e, float* __restrict__ emax, int n){
  int b=blockIdx.x;
  __shared__ float qs[64];
  __shared__ float wmax[4];
  int tid=threadIdx.x, lane=tid&63, w=tid>>6;
  if(tid<64) qs[tid]=hl[b*64+tid];
  int lo=lower_bound_i(batch,n,b), hi=lower_bound_i(batch,n,b+1);
  __syncthreads();
  float mx=-1e30f;
  for(int i=lo+w;i<hi;i+=4){
    float v=bf2f(Abuf[(size_t)i*128+64+lane])*qs[lane];
    #pragma unroll
    for(int off=32;off;off>>=1) v+=__shfl_xor(v,off);
    if(lane==0) e[i]=v;
    mx=fmaxf(mx,v);
  }
  if(lane==0) wmax[w]=mx;
  __syncthreads();
  if(tid==0){
    float m2=fmaxf(fmaxf(wmax[0],wmax[1]),fmaxf(wmax[2],wmax[3]));
    emax[b]=(hi>lo)? m2:0.f;
  }
}

__global__ __launch_bounds__(256) void k_attn_read(const unsigned short* __restrict__ Abuf, const int* __restrict__ batch,
                        const float* __restrict__ e, const float* __restrict__ emax,
                        float* __restrict__ qstar, int n){
  int b=blockIdx.x, tid=threadIdx.x, lane=tid&63, w=tid>>6;
  int lo=lower_bound_i(batch,n,b), hi=lower_bound_i(batch,n,b+1);
  float em=emax[b];
  __shared__ float red[256];
  float s=0.f;
  for(int i=lo+tid;i<hi;i+=256) s+=__expf(e[i]-em);
  red[tid]=s; __syncthreads();
  for(int off=128;off;off>>=1){
    if(tid<off) red[tid]+=red[tid+off];
    __syncthreads();
  }
  float inv=(hi>lo && red[0]>0.f)? 1.f/red[0]:0.f;
  float acc=0.f;
  for(int i=lo+w;i<hi;i+=4){
    float a=__expf(e[i]-em)*inv;
    acc+=a*bf2f(Abuf[(size_t)i*128+64+lane]);
  }
  __shared__ float part[4][64];
  part[w][lane]=acc; __syncthreads();
  if(tid<64){
    qstar[b*128+64+tid]=part[0][tid]+part[1][tid]+part[2][tid]+part[3][tid];
  }
}

extern "C" void kernel_launch(void* const* d_in, const int* in_sizes, int n_in,
                              void* d_out, int out_size, void* d_ws, size_t ws_size,
                              hipStream_t stream){
  const float* x      =(const float*)d_in[0];
  const int*   ei     =(const int*)d_in[1];
  const int*   batch  =(const int*)d_in[2];
  const float* lin0_w =(const float*)d_in[3];
  const float* lin0_b =(const float*)d_in[4];
  const float* conv_w =(const float*)d_in[5];
  const float* conv_b =(const float*)d_in[6];
  const float* gwih   =(const float*)d_in[7];
  const float* gwhh   =(const float*)d_in[8];
  const float* gbih   =(const float*)d_in[9];
  const float* gbhh   =(const float*)d_in[10];
  const float* lwih   =(const float*)d_in[11];
  const float* lwhh   =(const float*)d_in[12];
  const float* lbih   =(const float*)d_in[13];
  const float* lbhh   =(const float*)d_in[14];

  int N = in_sizes[0]/FEATD;
  int E = in_sizes[1]/2;
  const int* row = ei;
  const int* col = ei + E;

  float* qstar = (float*)d_out;            // [256,128]
  float* h     = (float*)d_out + NB*2*DIM; // [N,64] 'feat' region = f32 h

  char* ws=(char*)d_ws;
  size_t off=0;
  auto alloc=[&](size_t bytes)->void*{ void* p=ws+off; off=(off+bytes+255)&~(size_t)255; return p; };
  int*   deg  =(int*)  alloc((size_t)N*4);
  float* dinv =(float*)alloc((size_t)N*4);
  int*   rp   =(int*)  alloc((size_t)(N+1)*4);
  int*   fill =(int*)  alloc((size_t)N*4);
  int*   csrc =(int*)  alloc((size_t)E*4);
  float* cnorm=(float*)alloc((size_t)E*4);
  unsigned short* Abuf =(unsigned short*)alloc((size_t)N*128*2); // [m(64) | h(64)] bf16 per node
  unsigned short* hwb  =(unsigned short*)alloc((size_t)N*64*2);  // hw bf16
  float* e    =(float*)alloc((size_t)N*4);
  float* emax =(float*)alloc((size_t)NB*4);
  float* hl   =(float*)alloc((size_t)NB*DIM*4);
  float* cl   =(float*)alloc((size_t)NB*DIM*4);
  unsigned short* Bgru =(unsigned short*)alloc(128*256*2);
  unsigned short* Blin =(unsigned short*)alloc(128*64*2);
  unsigned short* Bcnv =(unsigned short*)alloc(64*64*2);

  hipMemsetAsync(deg ,0,(size_t)N*4,stream);
  hipMemsetAsync(fill,0,(size_t)N*4,stream);
  hipMemsetAsync(hl  ,0,(size_t)NB*DIM*4,stream);
  hipMemsetAsync(cl  ,0,(size_t)NB*DIM*4,stream);
  hipMemsetAsync(qstar,0,(size_t)NB*2*DIM*4,stream);

  k_count<<<(E+255)/256,256,0,stream>>>(col,deg,E);
  k_dinv <<<(N+255)/256,256,0,stream>>>(deg,dinv,N);
  k_scan <<<1,1024,0,stream>>>(deg,rp,N);
  k_fill <<<(E+255)/256,256,0,stream>>>(row,col,dinv,rp,fill,csrc,cnorm,E);

  k_prep_plain<<<(128*64+255)/256,256,0,stream>>>(lin0_w,Blin,128,64);
  k_prep_plain<<<(64*64+255)/256,256,0,stream>>>(conv_w,Bcnv,64,64);
  k_prep_gru  <<<(128*256+255)/256,256,0,stream>>>(gwih,gwhh,Bgru);

  int ngrp=(N+15)/16;          // 12500 (N divisible by 16)
  int gb=(ngrp+3)/4;           // 3125 blocks, 4 waves each, 1 wave = 16 nodes

  k_lin0<<<gb,256,0,stream>>>(x,Blin,lin0_b,h,Abuf,ngrp);

  for(int it=0;it<3;it++){
    k_conv     <<<gb,256,0,stream>>>(Abuf,Bcnv,hwb,ngrp);
    k_aggregate<<<(N+3)/4,256,0,stream>>>(hwb,rp,csrc,cnorm,dinv,conv_b,Abuf,N);
    k_gru      <<<gb,256,0,stream>>>(Abuf,Bgru,gbih,gbhh,h,ngrp);
  }

  for(int st=0;st<3;st++){
    k_lstm     <<<NB,256,0,stream>>>(qstar,hl,cl,lwih,lwhh,lbih,lbhh);
    k_attn_emax<<<NB,256,0,stream>>>(Abuf,hl,batch,e,emax,N);
    k_attn_read<<<NB,256,0,stream>>>(Abuf,batch,e,emax,qstar,N);
  }
}

// Round 3
// 1245.542 us; speedup vs baseline: 2.7232x; 1.4185x over previous
//
#include <hip/hip_runtime.h>
#include <math.h>

#define FEATD 128
#define DIM 64
#define NB 256
#define SCB 256

typedef short bf16x8 __attribute__((ext_vector_type(8)));
typedef float f32x4 __attribute__((ext_vector_type(4)));

__device__ __forceinline__ float sigmoidf_(float x){ return 1.f/(1.f+__expf(-x)); }

__device__ __forceinline__ unsigned short f2bf(float f){
  unsigned u = __float_as_uint(f);
  unsigned r = (u + 0x7FFFu + ((u>>16)&1u)) >> 16;
  return (unsigned short)r;
}
__device__ __forceinline__ float bf2f(unsigned short s){
  return __uint_as_float(((unsigned)s)<<16);
}

__device__ __forceinline__ int lower_bound_i(const int* __restrict__ a, int n, int key){
  int lo=0, hi=n;
  while(lo<hi){ int mid=(lo+hi)>>1; if(a[mid]<key) lo=mid+1; else hi=mid; }
  return lo;
}

// ======================= CSR setup =======================
__global__ void k_count(const int* __restrict__ col, int* __restrict__ deg, int E){
  int i=blockIdx.x*blockDim.x+threadIdx.x;
  if(i<E) atomicAdd(&deg[col[i]],1);
}

__global__ void k_dinv(const int* __restrict__ deg, float* __restrict__ dinv, int n){
  int i=blockIdx.x*blockDim.x+threadIdx.x;
  if(i<n) dinv[i]=rsqrtf((float)(deg[i]+1)); // +1 self-loop
}

// --- multi-block exclusive scan: part sums -> scan parts -> per-block scan ---
__global__ __launch_bounds__(256) void k_scan_part(const int* __restrict__ deg, int* __restrict__ part, int n){
  __shared__ int s[256];
  int b=blockIdx.x;
  int chunk=(n+SCB-1)/SCB;
  int lo=b*chunk, hi=min(lo+chunk,n);
  int acc=0;
  for(int i=lo+threadIdx.x;i<hi;i+=256) acc+=deg[i];
  s[threadIdx.x]=acc; __syncthreads();
  for(int off=128;off;off>>=1){
    if(threadIdx.x<off) s[threadIdx.x]+=s[threadIdx.x+off];
    __syncthreads();
  }
  if(threadIdx.x==0) part[b]=s[0];
}

__global__ __launch_bounds__(256) void k_scan_mid(int* __restrict__ part){
  __shared__ int s[256];
  int t=threadIdx.x;
  s[t]=part[t]; __syncthreads();
  for(int off=1;off<256;off<<=1){
    int v=(t>=off)? s[t-off]:0;
    __syncthreads();
    s[t]+=v;
    __syncthreads();
  }
  part[t]=(t>0)? s[t-1]:0;  // exclusive
}

__global__ __launch_bounds__(256) void k_scan_out(const int* __restrict__ deg, const int* __restrict__ part,
                                                  int* __restrict__ rp, int n){
  __shared__ int s[256];
  int b=blockIdx.x, t=threadIdx.x;
  int chunk=(n+SCB-1)/SCB;
  int lo=b*chunk, hi=min(lo+chunk,n);
  int tchunk=(chunk+255)/256;
  int tlo=lo+t*tchunk, thi=min(tlo+tchunk,hi);
  int acc=0;
  for(int i=tlo;i<thi;i++) acc+=deg[i];
  s[t]=acc; __syncthreads();
  for(int off=1;off<256;off<<=1){
    int v=(t>=off)? s[t-off]:0;
    __syncthreads();
    s[t]+=v;
    __syncthreads();
  }
  int pre=part[b]+((t>0)? s[t-1]:0);
  for(int i=tlo;i<thi;i++){ rp[i]=pre; pre+=deg[i]; }
  if(b==SCB-1 && t==0) rp[n]=part[b]+s[255];
}

// CSR fill: packed (src, norm) per edge slot
__global__ void k_fill(const int* __restrict__ row, const int* __restrict__ col,
                       const float* __restrict__ dinv, const int* __restrict__ rp,
                       int* __restrict__ fill, int2* __restrict__ epack, int E){
  int i=blockIdx.x*blockDim.x+threadIdx.x;
  if(i>=E) return;
  int r=row[i], c=col[i];
  int pos=atomicAdd(&fill[c],1);
  int idx=rp[c]+pos;
  epack[idx]=make_int2(r,__float_as_int(dinv[r]*dinv[c]));
}

// ======================= MFMA B-fragment prep =======================
// mfma_f32_16x16x32_bf16 fragments:
//   A: lane l holds row (l&15), k = s*32 + (l>>4)*8 + r   (r=0..7)
//   B: lane l holds col (l&15), k = s*32 + (l>>4)*8 + r
//   D: lane l holds col (l&15), row = (l>>4)*4 + reg
// B frags flat: Bf[((t*S + s)*64 + lane)*8 + r] = W[k][c], t=c/16, S=K/32.
__global__ void k_prep_plain(const float* __restrict__ W, unsigned short* __restrict__ Bf, int K, int C){
  int i=blockIdx.x*blockDim.x+threadIdx.x;
  if(i>=K*C) return;
  int k=i/C, c=i%C;
  int t=c>>4, s=k>>5, lane=(c&15)|(((k>>3)&3)<<4), r=k&7;
  int S=K>>5;
  Bf[(((t*S)+s)*64+lane)*8+r]=f2bf(W[(size_t)k*C+c]);
}

// Assembled GRU weights: X=[m|h] (K=128), cols: [0,64)=r-preact, [64,128)=z-preact,
// [128,192)=in_ (m only), [192,256)=hn (h only).
__global__ void k_prep_gru(const float* __restrict__ wih, const float* __restrict__ whh,
                           unsigned short* __restrict__ Bf){
  int i=blockIdx.x*blockDim.x+threadIdx.x;
  if(i>=128*256) return;
  int k=i>>8, c=i&255;
  float v;
  if(c<128){          // r,z
    v = (k<64) ? wih[c*64+k] : whh[c*64+(k-64)];
  } else if(c<192){   // in_
    v = (k<64) ? wih[c*64+k] : 0.f;
  } else {            // hn
    v = (k<64) ? 0.f : whh[(c-64)*64+(k-64)];
  }
  int t=c>>4, s=k>>5, lane=(c&15)|(((k>>3)&3)<<4), r=k&7;
  Bf[(((t*4)+s)*64+lane)*8+r]=f2bf(v);
}

// ======================= lin0: h = relu(x @ W + b); writes f32 h + bf16 hb ===================
__global__ __launch_bounds__(256) void k_lin0(const float* __restrict__ x, const unsigned short* __restrict__ Bf,
                      const float* __restrict__ bias, float* __restrict__ h,
                      unsigned short* __restrict__ hb, int ngrp){
  int l=threadIdx.x&63;
  int g=blockIdx.x*4+(threadIdx.x>>6);
  if(g>=ngrp) return;
  int row16=l&15, koff=(l>>4)*8;
  f32x4 acc[4]={};
  const float* xr = x + (size_t)(g*16+row16)*128 + koff;
  #pragma unroll
  for(int s=0;s<4;s++){
    f32x4 a0=*(const f32x4*)(xr+s*32);
    f32x4 a1=*(const f32x4*)(xr+s*32+4);
    bf16x8 af;
    #pragma unroll
    for(int r=0;r<4;r++){ af[r]=(short)f2bf(a0[r]); af[4+r]=(short)f2bf(a1[r]); }
    #pragma unroll
    for(int t=0;t<4;t++){
      bf16x8 bf=*(const bf16x8*)(Bf+(((t*4)+s)*64+l)*8);
      acc[t]=__builtin_amdgcn_mfma_f32_16x16x32_bf16(af,bf,acc[t],0,0,0);
    }
  }
  int rbase=g*16+(l>>4)*4;
  #pragma unroll
  for(int t=0;t<4;t++){
    int c=t*16+(l&15);
    float b=bias[c];
    #pragma unroll
    for(int j=0;j<4;j++){
      int node=rbase+j;
      float v=fmaxf(acc[t][j]+b,0.f);
      h[(size_t)node*64+c]=v;
      hb[(size_t)node*64+c]=f2bf(v);
    }
  }
}

// ======================= aggregate: agg = Â h (no bias/relu; conv folded into GRU) =========
__global__ __launch_bounds__(256) void k_aggregate(const unsigned short* __restrict__ hb, const int* __restrict__ rp,
                        const int2* __restrict__ epack, const float* __restrict__ dinv,
                        unsigned short* __restrict__ aggb, int n){
  int node=blockIdx.x*4+(threadIdx.x>>6);
  int lane=threadIdx.x&63;
  if(node>=n) return;
  float dv=dinv[node];
  float acc=dv*dv*bf2f(hb[(size_t)node*64+lane]);
  int s=rp[node], e=rp[node+1];
  for(int j=s;j<e;j++){
    int2 ev=epack[j];
    acc += __int_as_float(ev.y)*bf2f(hb[(size_t)ev.x*64+lane]);
  }
  aggb[(size_t)node*64+lane]=f2bf(acc);
}

// ======================= fused conv+GRU: m = relu(agg@Wc+cb); h' = GRU(m,h) ===================
__global__ __launch_bounds__(256) void k_gru(const unsigned short* __restrict__ aggb, unsigned short* hb,
                     const unsigned short* __restrict__ Bcnv, const float* __restrict__ cb,
                     const unsigned short* __restrict__ Bgru,
                     const float* __restrict__ bih, const float* __restrict__ bhh,
                     float* h, int ngrp, int n){
  __shared__ __align__(16) unsigned short mt[4][16][72]; // padded: stride 72 ushorts
  int l=threadIdx.x&63, w=threadIdx.x>>6;
  int g=blockIdx.x*4+w;
  bool act = g<ngrp;
  int row16=l&15, koff=(l>>4)*8;
  if(act){
    // mini GEMM: m = relu(agg[16x64] @ conv_w[64x64] + cb)
    f32x4 accm[4]={};
    const unsigned short* ar = aggb + (size_t)(g*16+row16)*64 + koff;
    #pragma unroll
    for(int s=0;s<2;s++){
      bf16x8 af=*(const bf16x8*)(ar+s*32);
      #pragma unroll
      for(int t=0;t<4;t++){
        bf16x8 bf=*(const bf16x8*)(Bcnv+(((t*2)+s)*64+l)*8);
        accm[t]=__builtin_amdgcn_mfma_f32_16x16x32_bf16(af,bf,accm[t],0,0,0);
      }
    }
    // D-layout -> row-major LDS tile (per-wave)
    #pragma unroll
    for(int t=0;t<4;t++){
      int c=t*16+(l&15);
      float b=cb[c];
      #pragma unroll
      for(int j=0;j<4;j++){
        mt[w][(l>>4)*4+j][c]=f2bf(fmaxf(accm[t][j]+b,0.f));
      }
    }
  }
  __syncthreads();
  if(!act) return;
  // GRU GEMM: [m|h](16x128) @ Bgru(128x256)
  f32x4 acc[16]={};
  const unsigned short* hr = hb + (size_t)(g*16+row16)*64 + koff;
  #pragma unroll
  for(int s=0;s<4;s++){
    bf16x8 af;
    if(s<2) af=*(const bf16x8*)&mt[w][row16][koff+s*32];
    else    af=*(const bf16x8*)(hr+(s-2)*32);
    #pragma unroll
    for(int t=0;t<16;t++){
      bf16x8 bf=*(const bf16x8*)(Bgru+(((t*4)+s)*64+l)*8);
      acc[t]=__builtin_amdgcn_mfma_f32_16x16x32_bf16(af,bf,acc[t],0,0,0);
    }
  }
  int rbase=g*16+(l>>4)*4;
  #pragma unroll
  for(int t=0;t<4;t++){
    int d=t*16+(l&15);
    float br =bih[d]    +bhh[d];
    float bz =bih[64+d] +bhh[64+d];
    float bni=bih[128+d];
    float bnh=bhh[128+d];
    #pragma unroll
    for(int j=0;j<4;j++){
      int node=rbase+j;
      if(node<n){
        float r  = sigmoidf_(acc[t][j]   + br);
        float z  = sigmoidf_(acc[4+t][j] + bz);
        float nc = tanhf(acc[8+t][j] + bni + r*(acc[12+t][j] + bnh));
        float hold = h[(size_t)node*64+d];
        float hn = (1.f-z)*nc + z*hold;
        h[(size_t)node*64+d]=hn;
        hb[(size_t)node*64+d]=f2bf(hn);
      }
    }
  }
}

// ======================= Set2Set step: fused LSTM + online-softmax attention =======================
__global__ __launch_bounds__(256) void k_s2s(const unsigned short* __restrict__ hb, const int* __restrict__ batch,
                   float* __restrict__ qstar, float* __restrict__ hl, float* __restrict__ cl,
                   const float* __restrict__ wih, const float* __restrict__ whh,
                   const float* __restrict__ bih, const float* __restrict__ bhh, int n){
  int b=blockIdx.x, tid=threadIdx.x;
  __shared__ float qs[128];
  __shared__ float hsh[64];
  __shared__ float gates[256];
  __shared__ float wm[4], wsum[4];
  __shared__ float wacc[4][64];
  if(tid<128) qs[tid]=qstar[b*128+tid];
  else if(tid<192) hsh[tid-128]=hl[b*64+(tid-128)];
  __syncthreads();
  // LSTM gates (torch order i,f,g,o)
  float acc=bih[tid]+bhh[tid];
  const float* wi=wih+(size_t)tid*128;
  #pragma unroll 8
  for(int k=0;k<128;k++) acc+=qs[k]*wi[k];
  const float* w2=whh+(size_t)tid*64;
  #pragma unroll 8
  for(int k=0;k<64;k++) acc+=hsh[k]*w2[k];
  gates[tid]=acc;
  __syncthreads();
  if(tid<64){
    float i_=gates[tid], f_=gates[64+tid], g_=gates[128+tid], o_=gates[192+tid];
    float c=sigmoidf_(f_)*cl[b*64+tid]+sigmoidf_(i_)*tanhf(g_);
    float hn=sigmoidf_(o_)*tanhf(c);
    cl[b*64+tid]=c; hl[b*64+tid]=hn;
    qstar[b*128+tid]=hn;
    hsh[tid]=hn;
  }
  __syncthreads();
  // attention, online softmax; wave w strides rows of this graph's segment
  int lane=tid&63, w=tid>>6;
  int lo=lower_bound_i(batch,n,b), hi=lower_bound_i(batch,n,b+1);
  float q=hsh[lane];
  float mw=-3.0e38f, sw=0.f, aw=0.f;
  for(int i=lo+w;i<hi;i+=4){
    float f=bf2f(hb[(size_t)i*64+lane]);
    float v=f*q;
    #pragma unroll
    for(int off=32;off;off>>=1) v+=__shfl_xor(v,off);
    if(v>mw){
      float sc=__expf(mw-v);
      sw=sw*sc+1.f;
      aw=aw*sc+f;
      mw=v;
    } else {
      float p=__expf(v-mw);
      sw+=p;
      aw+=p*f;
    }
  }
  if(lane==0){ wm[w]=mw; wsum[w]=sw; }
  wacc[w][lane]=aw;
  __syncthreads();
  if(w==0){
    float M=fmaxf(fmaxf(wm[0],wm[1]),fmaxf(wm[2],wm[3]));
    float S=0.f, A=0.f;
    #pragma unroll
    for(int k=0;k<4;k++){
      float sc=__expf(wm[k]-M);
      S+=wsum[k]*sc;
      A+=wacc[k][lane]*sc;
    }
    float inv=(S>0.f)? 1.f/S:0.f;
    qstar[b*128+64+lane]=A*inv;
  }
}

extern "C" void kernel_launch(void* const* d_in, const int* in_sizes, int n_in,
                              void* d_out, int out_size, void* d_ws, size_t ws_size,
                              hipStream_t stream){
  const float* x      =(const float*)d_in[0];
  const int*   ei     =(const int*)d_in[1];
  const int*   batch  =(const int*)d_in[2];
  const float* lin0_w =(const float*)d_in[3];
  const float* lin0_b =(const float*)d_in[4];
  const float* conv_w =(const float*)d_in[5];
  const float* conv_b =(const float*)d_in[6];
  const float* gwih   =(const float*)d_in[7];
  const float* gwhh   =(const float*)d_in[8];
  const float* gbih   =(const float*)d_in[9];
  const float* gbhh   =(const float*)d_in[10];
  const float* lwih   =(const float*)d_in[11];
  const float* lwhh   =(const float*)d_in[12];
  const float* lbih   =(const float*)d_in[13];
  const float* lbhh   =(const float*)d_in[14];

  int N = in_sizes[0]/FEATD;
  int E = in_sizes[1]/2;
  const int* row = ei;
  const int* col = ei + E;

  float* qstar = (float*)d_out;            // [256,128]
  float* h     = (float*)d_out + NB*2*DIM; // [N,64] 'feat' = f32 h

  char* ws=(char*)d_ws;
  size_t off=0;
  auto alloc=[&](size_t bytes)->void*{ void* p=ws+off; off=(off+bytes+255)&~(size_t)255; return p; };
  int*   deg  =(int*)  alloc((size_t)N*4);
  float* dinv =(float*)alloc((size_t)N*4);
  int*   rp   =(int*)  alloc((size_t)(N+1)*4);
  int*   fill =(int*)  alloc((size_t)N*4);
  int*   part =(int*)  alloc((size_t)SCB*4);
  int2*  epack=(int2*) alloc((size_t)E*8);
  unsigned short* hb   =(unsigned short*)alloc((size_t)N*64*2);
  unsigned short* aggb =(unsigned short*)alloc((size_t)N*64*2);
  float* hl   =(float*)alloc((size_t)NB*DIM*4);
  float* cl   =(float*)alloc((size_t)NB*DIM*4);
  unsigned short* Bgru =(unsigned short*)alloc(128*256*2);
  unsigned short* Blin =(unsigned short*)alloc(128*64*2);
  unsigned short* Bcnv =(unsigned short*)alloc(64*64*2);

  hipMemsetAsync(deg ,0,(size_t)N*4,stream);
  hipMemsetAsync(fill,0,(size_t)N*4,stream);
  hipMemsetAsync(hl  ,0,(size_t)NB*DIM*4,stream);
  hipMemsetAsync(cl  ,0,(size_t)NB*DIM*4,stream);
  hipMemsetAsync(qstar,0,(size_t)NB*2*DIM*4,stream);

  k_count<<<(E+255)/256,256,0,stream>>>(col,deg,E);
  k_dinv <<<(N+255)/256,256,0,stream>>>(deg,dinv,N);
  k_scan_part<<<SCB,256,0,stream>>>(deg,part,N);
  k_scan_mid <<<1,256,0,stream>>>(part);
  k_scan_out <<<SCB,256,0,stream>>>(deg,part,rp,N);
  k_fill <<<(E+255)/256,256,0,stream>>>(row,col,dinv,rp,fill,epack,E);

  k_prep_plain<<<(128*64+255)/256,256,0,stream>>>(lin0_w,Blin,128,64);
  k_prep_plain<<<(64*64+255)/256,256,0,stream>>>(conv_w,Bcnv,64,64);
  k_prep_gru  <<<(128*256+255)/256,256,0,stream>>>(gwih,gwhh,Bgru);

  int ngrp=(N+15)/16;
  int gb=(ngrp+3)/4;

  k_lin0<<<gb,256,0,stream>>>(x,Blin,lin0_b,h,hb,ngrp);

  for(int it=0;it<3;it++){
    k_aggregate<<<(N+3)/4,256,0,stream>>>(hb,rp,epack,dinv,aggb,N);
    k_gru      <<<gb,256,0,stream>>>(aggb,hb,Bcnv,conv_b,Bgru,gbih,gbhh,h,ngrp,N);
  }

  for(int st=0;st<3;st++){
    k_s2s<<<NB,256,0,stream>>>(hb,batch,qstar,hl,cl,lwih,lwhh,lbih,lbhh,N);
  }
}

// Round 4
// 1025.105 us; speedup vs baseline: 3.3087x; 1.2150x over previous
//
#include <hip/hip_runtime.h>
#include <math.h>

#define FEATD 128
#define DIM 64
#define NB 256
#define SCB 256

typedef short bf16x8 __attribute__((ext_vector_type(8)));
typedef float f32x4 __attribute__((ext_vector_type(4)));

__device__ __forceinline__ float sigmoidf_(float x){ return 1.f/(1.f+__expf(-x)); }

__device__ __forceinline__ unsigned short f2bf(float f){
  unsigned u = __float_as_uint(f);
  unsigned r = (u + 0x7FFFu + ((u>>16)&1u)) >> 16;
  return (unsigned short)r;
}
__device__ __forceinline__ float bf2f(unsigned short s){
  return __uint_as_float(((unsigned)s)<<16);
}

__device__ __forceinline__ int lower_bound_i(const int* __restrict__ a, int n, int key){
  int lo=0, hi=n;
  while(lo<hi){ int mid=(lo+hi)>>1; if(a[mid]<key) lo=mid+1; else hi=mid; }
  return lo;
}

// ======================= CSR setup =======================
__global__ void k_count(const int* __restrict__ col, int* __restrict__ deg, int E){
  int i=blockIdx.x*blockDim.x+threadIdx.x;
  if(i<E) atomicAdd(&deg[col[i]],1);
}

__global__ void k_dinv(const int* __restrict__ deg, float* __restrict__ dinv, int n){
  int i=blockIdx.x*blockDim.x+threadIdx.x;
  if(i<n) dinv[i]=rsqrtf((float)(deg[i]+1)); // +1 self-loop
}

// --- multi-block exclusive scan ---
__global__ __launch_bounds__(256) void k_scan_part(const int* __restrict__ deg, int* __restrict__ part, int n){
  __shared__ int s[256];
  int b=blockIdx.x;
  int chunk=(n+SCB-1)/SCB;
  int lo=b*chunk, hi=min(lo+chunk,n);
  int acc=0;
  for(int i=lo+threadIdx.x;i<hi;i+=256) acc+=deg[i];
  s[threadIdx.x]=acc; __syncthreads();
  for(int off=128;off;off>>=1){
    if(threadIdx.x<off) s[threadIdx.x]+=s[threadIdx.x+off];
    __syncthreads();
  }
  if(threadIdx.x==0) part[b]=s[0];
}

__global__ __launch_bounds__(256) void k_scan_mid(int* __restrict__ part){
  __shared__ int s[256];
  int t=threadIdx.x;
  s[t]=part[t]; __syncthreads();
  for(int off=1;off<256;off<<=1){
    int v=(t>=off)? s[t-off]:0;
    __syncthreads();
    s[t]+=v;
    __syncthreads();
  }
  part[t]=(t>0)? s[t-1]:0;  // exclusive
}

__global__ __launch_bounds__(256) void k_scan_out(const int* __restrict__ deg, const int* __restrict__ part,
                                                  int* __restrict__ rp, int n){
  __shared__ int s[256];
  int b=blockIdx.x, t=threadIdx.x;
  int chunk=(n+SCB-1)/SCB;
  int lo=b*chunk, hi=min(lo+chunk,n);
  int tchunk=(chunk+255)/256;
  int tlo=lo+t*tchunk, thi=min(tlo+tchunk,hi);
  int acc=0;
  for(int i=tlo;i<thi;i++) acc+=deg[i];
  s[t]=acc; __syncthreads();
  for(int off=1;off<256;off<<=1){
    int v=(t>=off)? s[t-off]:0;
    __syncthreads();
    s[t]+=v;
    __syncthreads();
  }
  int pre=part[b]+((t>0)? s[t-1]:0);
  for(int i=tlo;i<thi;i++){ rp[i]=pre; pre+=deg[i]; }
  if(b==SCB-1 && t==0) rp[n]=part[b]+s[255];
}

// CSR fill: packed (src, norm) per edge slot
__global__ void k_fill(const int* __restrict__ row, const int* __restrict__ col,
                       const float* __restrict__ dinv, const int* __restrict__ rp,
                       int* __restrict__ fill, int2* __restrict__ epack, int E){
  int i=blockIdx.x*blockDim.x+threadIdx.x;
  if(i>=E) return;
  int r=row[i], c=col[i];
  int pos=atomicAdd(&fill[c],1);
  int idx=rp[c]+pos;
  epack[idx]=make_int2(r,__float_as_int(dinv[r]*dinv[c]));
}

// ======================= MFMA B-fragment prep =======================
// mfma_f32_16x16x32_bf16 fragments:
//   A: lane l holds row (l&15), k = s*32 + (l>>4)*8 + r   (r=0..7)
//   B: lane l holds col (l&15), k = s*32 + (l>>4)*8 + r
//   D: lane l holds col (l&15), row = (l>>4)*4 + reg
// B frags flat: Bf[((t*S + s)*64 + lane)*8 + r] = W[k][c], t=c/16, S=K/32.
__global__ void k_prep_plain(const float* __restrict__ W, unsigned short* __restrict__ Bf, int K, int C){
  int i=blockIdx.x*blockDim.x+threadIdx.x;
  if(i>=K*C) return;
  int k=i/C, c=i%C;
  int t=c>>4, s=k>>5, lane=(c&15)|(((k>>3)&3)<<4), r=k&7;
  int S=K>>5;
  Bf[(((t*S)+s)*64+lane)*8+r]=f2bf(W[(size_t)k*C+c]);
}

// Assembled GRU weights: X=[m|h] (K=128), cols: [0,64)=r, [64,128)=z, [128,192)=in_, [192,256)=hn.
__global__ void k_prep_gru(const float* __restrict__ wih, const float* __restrict__ whh,
                           unsigned short* __restrict__ Bf){
  int i=blockIdx.x*blockDim.x+threadIdx.x;
  if(i>=128*256) return;
  int k=i>>8, c=i&255;
  float v;
  if(c<128){          // r,z
    v = (k<64) ? wih[c*64+k] : whh[c*64+(k-64)];
  } else if(c<192){   // in_
    v = (k<64) ? wih[c*64+k] : 0.f;
  } else {            // hn
    v = (k<64) ? 0.f : whh[(c-64)*64+(k-64)];
  }
  int t=c>>4, s=k>>5, lane=(c&15)|(((k>>3)&3)<<4), r=k&7;
  Bf[(((t*4)+s)*64+lane)*8+r]=f2bf(v);
}

// ======================= lin0: h = relu(x @ W + b); writes f32 h + bf16 hb ===================
__global__ __launch_bounds__(256) void k_lin0(const float* __restrict__ x, const unsigned short* __restrict__ Bf,
                      const float* __restrict__ bias, float* __restrict__ h,
                      unsigned short* __restrict__ hb, int ngrp){
  int l=threadIdx.x&63;
  int g=blockIdx.x*4+(threadIdx.x>>6);
  if(g>=ngrp) return;
  int row16=l&15, koff=(l>>4)*8;
  f32x4 acc[4]={};
  const float* xr = x + (size_t)(g*16+row16)*128 + koff;
  #pragma unroll
  for(int s=0;s<4;s++){
    f32x4 a0=*(const f32x4*)(xr+s*32);
    f32x4 a1=*(const f32x4*)(xr+s*32+4);
    bf16x8 af;
    #pragma unroll
    for(int r=0;r<4;r++){ af[r]=(short)f2bf(a0[r]); af[4+r]=(short)f2bf(a1[r]); }
    #pragma unroll
    for(int t=0;t<4;t++){
      bf16x8 bf=*(const bf16x8*)(Bf+(((t*4)+s)*64+l)*8);
      acc[t]=__builtin_amdgcn_mfma_f32_16x16x32_bf16(af,bf,acc[t],0,0,0);
    }
  }
  int rbase=g*16+(l>>4)*4;
  #pragma unroll
  for(int t=0;t<4;t++){
    int c=t*16+(l&15);
    float b=bias[c];
    #pragma unroll
    for(int j=0;j<4;j++){
      int node=rbase+j;
      float v=fmaxf(acc[t][j]+b,0.f);
      h[(size_t)node*64+c]=v;
      hb[(size_t)node*64+c]=f2bf(v);
    }
  }
}

// ======================= aggregate: agg = Â h — half-wave edge parallel, 2 chains/half =========
__global__ __launch_bounds__(256) void k_aggregate(const unsigned short* __restrict__ hb, const int* __restrict__ rp,
                        const int2* __restrict__ epack, const float* __restrict__ dinv,
                        unsigned short* __restrict__ aggb, int n){
  int node=blockIdx.x*4+(threadIdx.x>>6);
  int lane=threadIdx.x&63;
  if(node>=n) return;
  int half=lane>>5, l32=lane&31;
  const unsigned* hb32=(const unsigned*)hb;   // one dword = 2 bf16 features
  float ax=0.f, ay=0.f, bx=0.f, by=0.f;
  int s=rp[node], e=rp[node+1];
  int j=s+half;
  // main loop: 4 edges/iter across the wave, 4 independent row-gathers in flight
  for(; j+2<e; j+=4){
    int2 e0=epack[j];
    int2 e1=epack[j+2];
    unsigned p0=hb32[(size_t)e0.x*32+l32];
    unsigned p1=hb32[(size_t)e1.x*32+l32];
    float n0=__int_as_float(e0.y), n1=__int_as_float(e1.y);
    ax+=n0*bf2f((unsigned short)p0);
    ay+=n0*bf2f((unsigned short)(p0>>16));
    bx+=n1*bf2f((unsigned short)p1);
    by+=n1*bf2f((unsigned short)(p1>>16));
  }
  for(; j<e; j+=2){
    int2 e0=epack[j];
    unsigned p0=hb32[(size_t)e0.x*32+l32];
    float n0=__int_as_float(e0.y);
    ax+=n0*bf2f((unsigned short)p0);
    ay+=n0*bf2f((unsigned short)(p0>>16));
  }
  ax+=bx; ay+=by;
  if(half==0){ // self-loop term once
    float dv=dinv[node];
    unsigned ps=hb32[(size_t)node*32+l32];
    ax+=dv*dv*bf2f((unsigned short)ps);
    ay+=dv*dv*bf2f((unsigned short)(ps>>16));
  }
  ax+=__shfl_xor(ax,32);
  ay+=__shfl_xor(ay,32);
  if(half==0){
    unsigned out=(unsigned)f2bf(ax) | (((unsigned)f2bf(ay))<<16);
    ((unsigned*)aggb)[(size_t)node*32+l32]=out;
  }
}

// ======================= fused conv+GRU: m = relu(agg@Wc+cb); h' = GRU(m,h) ===================
__global__ __launch_bounds__(256) void k_gru(const unsigned short* __restrict__ aggb, unsigned short* hb,
                     const unsigned short* __restrict__ Bcnv, const float* __restrict__ cb,
                     const unsigned short* __restrict__ Bgru,
                     const float* __restrict__ bih, const float* __restrict__ bhh,
                     float* h, int ngrp, int n){
  __shared__ __align__(16) unsigned short mt[4][16][72]; // padded: stride 72 ushorts
  int l=threadIdx.x&63, w=threadIdx.x>>6;
  int g=blockIdx.x*4+w;
  bool act = g<ngrp;
  int row16=l&15, koff=(l>>4)*8;
  if(act){
    // mini GEMM: m = relu(agg[16x64] @ conv_w[64x64] + cb)
    f32x4 accm[4]={};
    const unsigned short* ar = aggb + (size_t)(g*16+row16)*64 + koff;
    #pragma unroll
    for(int s=0;s<2;s++){
      bf16x8 af=*(const bf16x8*)(ar+s*32);
      #pragma unroll
      for(int t=0;t<4;t++){
        bf16x8 bf=*(const bf16x8*)(Bcnv+(((t*2)+s)*64+l)*8);
        accm[t]=__builtin_amdgcn_mfma_f32_16x16x32_bf16(af,bf,accm[t],0,0,0);
      }
    }
    // D-layout -> row-major LDS tile (per-wave)
    #pragma unroll
    for(int t=0;t<4;t++){
      int c=t*16+(l&15);
      float b=cb[c];
      #pragma unroll
      for(int j=0;j<4;j++){
        mt[w][(l>>4)*4+j][c]=f2bf(fmaxf(accm[t][j]+b,0.f));
      }
    }
  }
  __syncthreads();
  if(!act) return;
  // GRU GEMM: [m|h](16x128) @ Bgru(128x256)
  f32x4 acc[16]={};
  const unsigned short* hr = hb + (size_t)(g*16+row16)*64 + koff;
  #pragma unroll
  for(int s=0;s<4;s++){
    bf16x8 af;
    if(s<2) af=*(const bf16x8*)&mt[w][row16][koff+s*32];
    else    af=*(const bf16x8*)(hr+(s-2)*32);
    #pragma unroll
    for(int t=0;t<16;t++){
      bf16x8 bf=*(const bf16x8*)(Bgru+(((t*4)+s)*64+l)*8);
      acc[t]=__builtin_amdgcn_mfma_f32_16x16x32_bf16(af,bf,acc[t],0,0,0);
    }
  }
  int rbase=g*16+(l>>4)*4;
  #pragma unroll
  for(int t=0;t<4;t++){
    int d=t*16+(l&15);
    float br =bih[d]    +bhh[d];
    float bz =bih[64+d] +bhh[64+d];
    float bni=bih[128+d];
    float bnh=bhh[128+d];
    #pragma unroll
    for(int j=0;j<4;j++){
      int node=rbase+j;
      if(node<n){
        float r  = sigmoidf_(acc[t][j]   + br);
        float z  = sigmoidf_(acc[4+t][j] + bz);
        float nc = tanhf(acc[8+t][j] + bni + r*(acc[12+t][j] + bnh));
        float hold = h[(size_t)node*64+d];
        float hn = (1.f-z)*nc + z*hold;
        h[(size_t)node*64+d]=hn;
        hb[(size_t)node*64+d]=f2bf(hn);
      }
    }
  }
}

// ======================= Set2Set step: fused LSTM + online-softmax attention =======================
__global__ __launch_bounds__(256) void k_s2s(const unsigned short* __restrict__ hb, const int* __restrict__ batch,
                   float* __restrict__ qstar, float* __restrict__ hl, float* __restrict__ cl,
                   const float* __restrict__ wih, const float* __restrict__ whh,
                   const float* __restrict__ bih, const float* __restrict__ bhh, int n){
  int b=blockIdx.x, tid=threadIdx.x;
  __shared__ float qs[128];
  __shared__ float hsh[64];
  __shared__ float gates[256];
  __shared__ float wm[4], wsum[4];
  __shared__ float wacc[4][64];
  if(tid<128) qs[tid]=qstar[b*128+tid];
  else if(tid<192) hsh[tid-128]=hl[b*64+(tid-128)];
  __syncthreads();
  // LSTM gates (torch order i,f,g,o)
  float acc=bih[tid]+bhh[tid];
  const float* wi=wih+(size_t)tid*128;
  #pragma unroll 8
  for(int k=0;k<128;k++) acc+=qs[k]*wi[k];
  const float* w2=whh+(size_t)tid*64;
  #pragma unroll 8
  for(int k=0;k<64;k++) acc+=hsh[k]*w2[k];
  gates[tid]=acc;
  __syncthreads();
  if(tid<64){
    float i_=gates[tid], f_=gates[64+tid], g_=gates[128+tid], o_=gates[192+tid];
    float c=sigmoidf_(f_)*cl[b*64+tid]+sigmoidf_(i_)*tanhf(g_);
    float hn=sigmoidf_(o_)*tanhf(c);
    cl[b*64+tid]=c; hl[b*64+tid]=hn;
    qstar[b*128+tid]=hn;
    hsh[tid]=hn;
  }
  __syncthreads();
  // attention, online softmax
  int lane=tid&63, w=tid>>6;
  int lo=lower_bound_i(batch,n,b), hi=lower_bound_i(batch,n,b+1);
  float q=hsh[lane];
  float mw=-3.0e38f, sw=0.f, aw=0.f;
  for(int i=lo+w;i<hi;i+=4){
    float f=bf2f(hb[(size_t)i*64+lane]);
    float v=f*q;
    #pragma unroll
    for(int off=32;off;off>>=1) v+=__shfl_xor(v,off);
    if(v>mw){
      float sc=__expf(mw-v);
      sw=sw*sc+1.f;
      aw=aw*sc+f;
      mw=v;
    } else {
      float p=__expf(v-mw);
      sw+=p;
      aw+=p*f;
    }
  }
  if(lane==0){ wm[w]=mw; wsum[w]=sw; }
  wacc[w][lane]=aw;
  __syncthreads();
  if(w==0){
    float M=fmaxf(fmaxf(wm[0],wm[1]),fmaxf(wm[2],wm[3]));
    float S=0.f, A=0.f;
    #pragma unroll
    for(int k=0;k<4;k++){
      float sc=__expf(wm[k]-M);
      S+=wsum[k]*sc;
      A+=wacc[k][lane]*sc;
    }
    float inv=(S>0.f)? 1.f/S:0.f;
    qstar[b*128+64+lane]=A*inv;
  }
}

extern "C" void kernel_launch(void* const* d_in, const int* in_sizes, int n_in,
                              void* d_out, int out_size, void* d_ws, size_t ws_size,
                              hipStream_t stream){
  const float* x      =(const float*)d_in[0];
  const int*   ei     =(const int*)d_in[1];
  const int*   batch  =(const int*)d_in[2];
  const float* lin0_w =(const float*)d_in[3];
  const float* lin0_b =(const float*)d_in[4];
  const float* conv_w =(const float*)d_in[5];
  const float* conv_b =(const float*)d_in[6];
  const float* gwih   =(const float*)d_in[7];
  const float* gwhh   =(const float*)d_in[8];
  const float* gbih   =(const float*)d_in[9];
  const float* gbhh   =(const float*)d_in[10];
  const float* lwih   =(const float*)d_in[11];
  const float* lwhh   =(const float*)d_in[12];
  const float* lbih   =(const float*)d_in[13];
  const float* lbhh   =(const float*)d_in[14];

  int N = in_sizes[0]/FEATD;
  int E = in_sizes[1]/2;
  const int* row = ei;
  const int* col = ei + E;

  float* qstar = (float*)d_out;            // [256,128]
  float* h     = (float*)d_out + NB*2*DIM; // [N,64] 'feat' = f32 h

  char* ws=(char*)d_ws;
  size_t off=0;
  auto alloc=[&](size_t bytes)->void*{ void* p=ws+off; off=(off+bytes+255)&~(size_t)255; return p; };
  int*   deg  =(int*)  alloc((size_t)N*4);
  float* dinv =(float*)alloc((size_t)N*4);
  int*   rp   =(int*)  alloc((size_t)(N+1)*4);
  int*   fill =(int*)  alloc((size_t)N*4);
  int*   part =(int*)  alloc((size_t)SCB*4);
  int2*  epack=(int2*) alloc((size_t)E*8);
  unsigned short* hb   =(unsigned short*)alloc((size_t)N*64*2);
  unsigned short* aggb =(unsigned short*)alloc((size_t)N*64*2);
  float* hl   =(float*)alloc((size_t)NB*DIM*4);
  float* cl   =(float*)alloc((size_t)NB*DIM*4);
  unsigned short* Bgru =(unsigned short*)alloc(128*256*2);
  unsigned short* Blin =(unsigned short*)alloc(128*64*2);
  unsigned short* Bcnv =(unsigned short*)alloc(64*64*2);

  hipMemsetAsync(deg ,0,(size_t)N*4,stream);
  hipMemsetAsync(fill,0,(size_t)N*4,stream);
  hipMemsetAsync(hl  ,0,(size_t)NB*DIM*4,stream);
  hipMemsetAsync(cl  ,0,(size_t)NB*DIM*4,stream);
  hipMemsetAsync(qstar,0,(size_t)NB*2*DIM*4,stream);

  k_count<<<(E+255)/256,256,0,stream>>>(col,deg,E);
  k_dinv <<<(N+255)/256,256,0,stream>>>(deg,dinv,N);
  k_scan_part<<<SCB,256,0,stream>>>(deg,part,N);
  k_scan_mid <<<1,256,0,stream>>>(part);
  k_scan_out <<<SCB,256,0,stream>>>(deg,part,rp,N);
  k_fill <<<(E+255)/256,256,0,stream>>>(row,col,dinv,rp,fill,epack,E);

  k_prep_plain<<<(128*64+255)/256,256,0,stream>>>(lin0_w,Blin,128,64);
  k_prep_plain<<<(64*64+255)/256,256,0,stream>>>(conv_w,Bcnv,64,64);
  k_prep_gru  <<<(128*256+255)/256,256,0,stream>>>(gwih,gwhh,Bgru);

  int ngrp=(N+15)/16;
  int gb=(ngrp+3)/4;

  k_lin0<<<gb,256,0,stream>>>(x,Blin,lin0_b,h,hb,ngrp);

  for(int it=0;it<3;it++){
    k_aggregate<<<(N+3)/4,256,0,stream>>>(hb,rp,epack,dinv,aggb,N);
    k_gru      <<<gb,256,0,stream>>>(aggb,hb,Bcnv,conv_b,Bgru,gbih,gbhh,h,ngrp,N);
  }

  for(int st=0;st<3;st++){
    k_s2s<<<NB,256,0,stream>>>(hb,batch,qstar,hl,cl,lwih,lwhh,lbih,lbhh,N);
  }
}

// Round 5
// 845.141 us; speedup vs baseline: 4.0133x; 1.2129x over previous
//
#include <hip/hip_runtime.h>
#include <math.h>

#define FEATD 128
#define DIM 64
#define NB 256
#define SCB 256
#define KB 16   // attention partial blocks per graph

typedef short bf16x8 __attribute__((ext_vector_type(8)));
typedef float f32x4 __attribute__((ext_vector_type(4)));

__device__ __forceinline__ float sigmoidf_(float x){ return 1.f/(1.f+__expf(-x)); }

__device__ __forceinline__ unsigned short f2bf(float f){
  unsigned u = __float_as_uint(f);
  unsigned r = (u + 0x7FFFu + ((u>>16)&1u)) >> 16;
  return (unsigned short)r;
}
__device__ __forceinline__ float bf2f(unsigned short s){
  return __uint_as_float(((unsigned)s)<<16);
}

__device__ __forceinline__ int lower_bound_i(const int* __restrict__ a, int n, int key){
  int lo=0, hi=n;
  while(lo<hi){ int mid=(lo+hi)>>1; if(a[mid]<key) lo=mid+1; else hi=mid; }
  return lo;
}

// ======================= CSR setup =======================
__global__ void k_count(const int* __restrict__ col, int* __restrict__ deg, int E){
  int i=blockIdx.x*blockDim.x+threadIdx.x;
  if(i<E) atomicAdd(&deg[col[i]],1);
}

__global__ void k_dinv(const int* __restrict__ deg, float* __restrict__ dinv, int n){
  int i=blockIdx.x*blockDim.x+threadIdx.x;
  if(i<n) dinv[i]=rsqrtf((float)(deg[i]+1)); // +1 self-loop
}

// --- multi-block exclusive scan ---
__global__ __launch_bounds__(256) void k_scan_part(const int* __restrict__ deg, int* __restrict__ part, int n){
  __shared__ int s[256];
  int b=blockIdx.x;
  int chunk=(n+SCB-1)/SCB;
  int lo=b*chunk, hi=min(lo+chunk,n);
  int acc=0;
  for(int i=lo+threadIdx.x;i<hi;i+=256) acc+=deg[i];
  s[threadIdx.x]=acc; __syncthreads();
  for(int off=128;off;off>>=1){
    if(threadIdx.x<off) s[threadIdx.x]+=s[threadIdx.x+off];
    __syncthreads();
  }
  if(threadIdx.x==0) part[b]=s[0];
}

__global__ __launch_bounds__(256) void k_scan_mid(int* __restrict__ part){
  __shared__ int s[256];
  int t=threadIdx.x;
  s[t]=part[t]; __syncthreads();
  for(int off=1;off<256;off<<=1){
    int v=(t>=off)? s[t-off]:0;
    __syncthreads();
    s[t]+=v;
    __syncthreads();
  }
  part[t]=(t>0)? s[t-1]:0;  // exclusive
}

__global__ __launch_bounds__(256) void k_scan_out(const int* __restrict__ deg, const int* __restrict__ part,
                                                  int* __restrict__ rp, int n){
  __shared__ int s[256];
  int b=blockIdx.x, t=threadIdx.x;
  int chunk=(n+SCB-1)/SCB;
  int lo=b*chunk, hi=min(lo+chunk,n);
  int tchunk=(chunk+255)/256;
  int tlo=lo+t*tchunk, thi=min(tlo+tchunk,hi);
  int acc=0;
  for(int i=tlo;i<thi;i++) acc+=deg[i];
  s[t]=acc; __syncthreads();
  for(int off=1;off<256;off<<=1){
    int v=(t>=off)? s[t-off]:0;
    __syncthreads();
    s[t]+=v;
    __syncthreads();
  }
  int pre=part[b]+((t>0)? s[t-1]:0);
  for(int i=tlo;i<thi;i++){ rp[i]=pre; pre+=deg[i]; }
  if(b==SCB-1 && t==0) rp[n]=part[b]+s[255];
}

// CSR fill: packed (src, norm) per edge slot
__global__ void k_fill(const int* __restrict__ row, const int* __restrict__ col,
                       const float* __restrict__ dinv, const int* __restrict__ rp,
                       int* __restrict__ fill, int2* __restrict__ epack, int E){
  int i=blockIdx.x*blockDim.x+threadIdx.x;
  if(i>=E) return;
  int r=row[i], c=col[i];
  int pos=atomicAdd(&fill[c],1);
  int idx=rp[c]+pos;
  epack[idx]=make_int2(r,__float_as_int(dinv[r]*dinv[c]));
}

// ======================= MFMA B-fragment prep =======================
// mfma_f32_16x16x32_bf16 fragments:
//   A: lane l holds row (l&15), k = s*32 + (l>>4)*8 + r   (r=0..7)
//   B: lane l holds col (l&15), k = s*32 + (l>>4)*8 + r
//   D: lane l holds col (l&15), row = (l>>4)*4 + reg
// B frags flat: Bf[((t*S + s)*64 + lane)*8 + r] = W[k][c], t=c/16, S=K/32.
__global__ void k_prep_plain(const float* __restrict__ W, unsigned short* __restrict__ Bf, int K, int C){
  int i=blockIdx.x*blockDim.x+threadIdx.x;
  if(i>=K*C) return;
  int k=i/C, c=i%C;
  int t=c>>4, s=k>>5, lane=(c&15)|(((k>>3)&3)<<4), r=k&7;
  int S=K>>5;
  Bf[(((t*S)+s)*64+lane)*8+r]=f2bf(W[(size_t)k*C+c]);
}

// Assembled GRU weights: X=[m|h] (K=128), cols: [0,64)=r, [64,128)=z, [128,192)=in_, [192,256)=hn.
__global__ void k_prep_gru(const float* __restrict__ wih, const float* __restrict__ whh,
                           unsigned short* __restrict__ Bf){
  int i=blockIdx.x*blockDim.x+threadIdx.x;
  if(i>=128*256) return;
  int k=i>>8, c=i&255;
  float v;
  if(c<128){          // r,z
    v = (k<64) ? wih[c*64+k] : whh[c*64+(k-64)];
  } else if(c<192){   // in_
    v = (k<64) ? wih[c*64+k] : 0.f;
  } else {            // hn
    v = (k<64) ? 0.f : whh[(c-64)*64+(k-64)];
  }
  int t=c>>4, s=k>>5, lane=(c&15)|(((k>>3)&3)<<4), r=k&7;
  Bf[(((t*4)+s)*64+lane)*8+r]=f2bf(v);
}

// ======================= lin0: h = relu(x @ W + b); writes f32 h + bf16 hb ===================
__global__ __launch_bounds__(256) void k_lin0(const float* __restrict__ x, const unsigned short* __restrict__ Bf,
                      const float* __restrict__ bias, float* __restrict__ h,
                      unsigned short* __restrict__ hb, int ngrp){
  int l=threadIdx.x&63;
  int g=blockIdx.x*4+(threadIdx.x>>6);
  if(g>=ngrp) return;
  int row16=l&15, koff=(l>>4)*8;
  f32x4 acc[4]={};
  const float* xr = x + (size_t)(g*16+row16)*128 + koff;
  #pragma unroll
  for(int s=0;s<4;s++){
    f32x4 a0=*(const f32x4*)(xr+s*32);
    f32x4 a1=*(const f32x4*)(xr+s*32+4);
    bf16x8 af;
    #pragma unroll
    for(int r=0;r<4;r++){ af[r]=(short)f2bf(a0[r]); af[4+r]=(short)f2bf(a1[r]); }
    #pragma unroll
    for(int t=0;t<4;t++){
      bf16x8 bf=*(const bf16x8*)(Bf+(((t*4)+s)*64+l)*8);
      acc[t]=__builtin_amdgcn_mfma_f32_16x16x32_bf16(af,bf,acc[t],0,0,0);
    }
  }
  int rbase=g*16+(l>>4)*4;
  #pragma unroll
  for(int t=0;t<4;t++){
    int c=t*16+(l&15);
    float b=bias[c];
    #pragma unroll
    for(int j=0;j<4;j++){
      int node=rbase+j;
      float v=fmaxf(acc[t][j]+b,0.f);
      h[(size_t)node*64+c]=v;
      hb[(size_t)node*64+c]=f2bf(v);
    }
  }
}

// ======================= aggregate: agg = Â h — half-wave edge parallel, 2 chains/half =========
__global__ __launch_bounds__(256) void k_aggregate(const unsigned short* __restrict__ hb, const int* __restrict__ rp,
                        const int2* __restrict__ epack, const float* __restrict__ dinv,
                        unsigned short* __restrict__ aggb, int n){
  int node=blockIdx.x*4+(threadIdx.x>>6);
  int lane=threadIdx.x&63;
  if(node>=n) return;
  int half=lane>>5, l32=lane&31;
  const unsigned* hb32=(const unsigned*)hb;   // one dword = 2 bf16 features
  float ax=0.f, ay=0.f, bx=0.f, by=0.f;
  int s=rp[node], e=rp[node+1];
  int j=s+half;
  for(; j+2<e; j+=4){
    int2 e0=epack[j];
    int2 e1=epack[j+2];
    unsigned p0=hb32[(size_t)e0.x*32+l32];
    unsigned p1=hb32[(size_t)e1.x*32+l32];
    float n0=__int_as_float(e0.y), n1=__int_as_float(e1.y);
    ax+=n0*bf2f((unsigned short)p0);
    ay+=n0*bf2f((unsigned short)(p0>>16));
    bx+=n1*bf2f((unsigned short)p1);
    by+=n1*bf2f((unsigned short)(p1>>16));
  }
  for(; j<e; j+=2){
    int2 e0=epack[j];
    unsigned p0=hb32[(size_t)e0.x*32+l32];
    float n0=__int_as_float(e0.y);
    ax+=n0*bf2f((unsigned short)p0);
    ay+=n0*bf2f((unsigned short)(p0>>16));
  }
  ax+=bx; ay+=by;
  if(half==0){ // self-loop term once
    float dv=dinv[node];
    unsigned ps=hb32[(size_t)node*32+l32];
    ax+=dv*dv*bf2f((unsigned short)ps);
    ay+=dv*dv*bf2f((unsigned short)(ps>>16));
  }
  ax+=__shfl_xor(ax,32);
  ay+=__shfl_xor(ay,32);
  if(half==0){
    unsigned out=(unsigned)f2bf(ax) | (((unsigned)f2bf(ay))<<16);
    ((unsigned*)aggb)[(size_t)node*32+l32]=out;
  }
}

// ======================= fused conv+GRU: m = relu(agg@Wc+cb); h' = GRU(m,h) ===================
__global__ __launch_bounds__(256) void k_gru(const unsigned short* __restrict__ aggb, unsigned short* hb,
                     const unsigned short* __restrict__ Bcnv, const float* __restrict__ cb,
                     const unsigned short* __restrict__ Bgru,
                     const float* __restrict__ bih, const float* __restrict__ bhh,
                     float* h, int ngrp, int n){
  __shared__ __align__(16) unsigned short mt[4][16][72]; // padded: stride 72 ushorts
  int l=threadIdx.x&63, w=threadIdx.x>>6;
  int g=blockIdx.x*4+w;
  bool act = g<ngrp;
  int row16=l&15, koff=(l>>4)*8;
  if(act){
    f32x4 accm[4]={};
    const unsigned short* ar = aggb + (size_t)(g*16+row16)*64 + koff;
    #pragma unroll
    for(int s=0;s<2;s++){
      bf16x8 af=*(const bf16x8*)(ar+s*32);
      #pragma unroll
      for(int t=0;t<4;t++){
        bf16x8 bf=*(const bf16x8*)(Bcnv+(((t*2)+s)*64+l)*8);
        accm[t]=__builtin_amdgcn_mfma_f32_16x16x32_bf16(af,bf,accm[t],0,0,0);
      }
    }
    #pragma unroll
    for(int t=0;t<4;t++){
      int c=t*16+(l&15);
      float b=cb[c];
      #pragma unroll
      for(int j=0;j<4;j++){
        mt[w][(l>>4)*4+j][c]=f2bf(fmaxf(accm[t][j]+b,0.f));
      }
    }
  }
  __syncthreads();
  if(!act) return;
  f32x4 acc[16]={};
  const unsigned short* hr = hb + (size_t)(g*16+row16)*64 + koff;
  #pragma unroll
  for(int s=0;s<4;s++){
    bf16x8 af;
    if(s<2) af=*(const bf16x8*)&mt[w][row16][koff+s*32];
    else    af=*(const bf16x8*)(hr+(s-2)*32);
    #pragma unroll
    for(int t=0;t<16;t++){
      bf16x8 bf=*(const bf16x8*)(Bgru+(((t*4)+s)*64+l)*8);
      acc[t]=__builtin_amdgcn_mfma_f32_16x16x32_bf16(af,bf,acc[t],0,0,0);
    }
  }
  int rbase=g*16+(l>>4)*4;
  #pragma unroll
  for(int t=0;t<4;t++){
    int d=t*16+(l&15);
    float br =bih[d]    +bhh[d];
    float bz =bih[64+d] +bhh[64+d];
    float bni=bih[128+d];
    float bnh=bhh[128+d];
    #pragma unroll
    for(int j=0;j<4;j++){
      int node=rbase+j;
      if(node<n){
        float r  = sigmoidf_(acc[t][j]   + br);
        float z  = sigmoidf_(acc[4+t][j] + bz);
        float nc = tanhf(acc[8+t][j] + bni + r*(acc[12+t][j] + bnh));
        float hold = h[(size_t)node*64+d];
        float hn = (1.f-z)*nc + z*hold;
        h[(size_t)node*64+d]=hn;
        hb[(size_t)node*64+d]=f2bf(hn);
      }
    }
  }
}

// ======================= Set2Set: parallel attention partials =======================
// block (b, kb): online-softmax over slice kb of graph b's rows; writes (acc[64], m, s)
__global__ __launch_bounds__(256) void k_attn_part(const unsigned short* __restrict__ hb, const int* __restrict__ batch,
                        const float* __restrict__ hl, float* __restrict__ apart, int n){
  int b=blockIdx.x/KB, kb=blockIdx.x%KB;
  int tid=threadIdx.x, lane=tid&63, w=tid>>6;
  __shared__ float qs[64];
  __shared__ float wm[4], wsm[4];
  __shared__ float wacc[4][64];
  if(tid<64) qs[tid]=hl[b*64+tid];
  int lo=lower_bound_i(batch,n,b), hi=lower_bound_i(batch,n,b+1);
  int cnt=hi-lo;
  int chunk=(cnt+KB-1)/KB;
  int slo=lo+kb*chunk, shi=min(slo+chunk,hi);
  __syncthreads();
  float q=qs[lane];
  float mw=-3.0e38f, sw=0.f, aw=0.f;
  for(int i=slo+w;i<shi;i+=4){
    float f=bf2f(hb[(size_t)i*64+lane]);
    float v=f*q;
    #pragma unroll
    for(int off=32;off;off>>=1) v+=__shfl_xor(v,off);
    if(v>mw){
      float sc=__expf(mw-v);
      sw=sw*sc+1.f;
      aw=aw*sc+f;
      mw=v;
    } else {
      float p=__expf(v-mw);
      sw+=p;
      aw+=p*f;
    }
  }
  if(lane==0){ wm[w]=mw; wsm[w]=sw; }
  wacc[w][lane]=aw;
  __syncthreads();
  if(w==0){
    float M=fmaxf(fmaxf(wm[0],wm[1]),fmaxf(wm[2],wm[3]));
    float S=0.f, A=0.f;
    #pragma unroll
    for(int k=0;k<4;k++){
      float sc=__expf(wm[k]-M);
      S+=wsm[k]*sc;
      A+=wacc[k][lane]*sc;
    }
    float* p=apart+(size_t)blockIdx.x*68;
    p[lane]=A;
    if(lane==0){ p[64]=M; p[65]=S; }
  }
}

// merge partials -> r_read (qstar[64:128]); optionally run next LSTM cell -> q (qstar[0:64], hl)
__global__ __launch_bounds__(256) void k_merge_lstm(const float* __restrict__ apart,
                   float* __restrict__ qstar, float* __restrict__ hl, float* __restrict__ cl,
                   const float* __restrict__ wih, const float* __restrict__ whh,
                   const float* __restrict__ bih, const float* __restrict__ bhh,
                   int do_merge, int do_lstm){
  int b=blockIdx.x, tid=threadIdx.x;
  __shared__ float qs[128];
  __shared__ float gates[256];
  if(do_merge){
    if(tid<64){
      const float* p0=apart+(size_t)b*KB*68;
      float M=-3.0e38f;
      #pragma unroll
      for(int k=0;k<KB;k++) M=fmaxf(M,p0[k*68+64]);
      float S=0.f, A=0.f;
      #pragma unroll
      for(int k=0;k<KB;k++){
        float sc=__expf(p0[k*68+64]-M);
        S+=p0[k*68+65]*sc;
        A+=p0[k*68+tid]*sc;
      }
      float inv=(S>0.f)? 1.f/S:0.f;
      float r=A*inv;
      qs[64+tid]=r;
      qstar[b*128+64+tid]=r;
    }
  } else {
    if(tid<64) qs[64+tid]=qstar[b*128+64+tid];
  }
  if(tid<64) qs[tid]=hl[b*64+tid];   // q_t == previous LSTM hidden
  __syncthreads();
  if(!do_lstm) return;
  // LSTM gates (torch order i,f,g,o): gates = W_ih @ q_star + W_hh @ h + b
  float acc=bih[tid]+bhh[tid];
  const float* wi=wih+(size_t)tid*128;
  #pragma unroll 8
  for(int k=0;k<128;k++) acc+=qs[k]*wi[k];
  const float* w2=whh+(size_t)tid*64;
  #pragma unroll 8
  for(int k=0;k<64;k++) acc+=qs[k]*w2[k];
  gates[tid]=acc;
  __syncthreads();
  if(tid<64){
    float i_=gates[tid], f_=gates[64+tid], g_=gates[128+tid], o_=gates[192+tid];
    float c=sigmoidf_(f_)*cl[b*64+tid]+sigmoidf_(i_)*tanhf(g_);
    float hn=sigmoidf_(o_)*tanhf(c);
    cl[b*64+tid]=c; hl[b*64+tid]=hn;
    qstar[b*128+tid]=hn;
  }
}

extern "C" void kernel_launch(void* const* d_in, const int* in_sizes, int n_in,
                              void* d_out, int out_size, void* d_ws, size_t ws_size,
                              hipStream_t stream){
  const float* x      =(const float*)d_in[0];
  const int*   ei     =(const int*)d_in[1];
  const int*   batch  =(const int*)d_in[2];
  const float* lin0_w =(const float*)d_in[3];
  const float* lin0_b =(const float*)d_in[4];
  const float* conv_w =(const float*)d_in[5];
  const float* conv_b =(const float*)d_in[6];
  const float* gwih   =(const float*)d_in[7];
  const float* gwhh   =(const float*)d_in[8];
  const float* gbih   =(const float*)d_in[9];
  const float* gbhh   =(const float*)d_in[10];
  const float* lwih   =(const float*)d_in[11];
  const float* lwhh   =(const float*)d_in[12];
  const float* lbih   =(const float*)d_in[13];
  const float* lbhh   =(const float*)d_in[14];

  int N = in_sizes[0]/FEATD;
  int E = in_sizes[1]/2;
  const int* row = ei;
  const int* col = ei + E;

  float* qstar = (float*)d_out;            // [256,128]
  float* h     = (float*)d_out + NB*2*DIM; // [N,64] 'feat' = f32 h

  char* ws=(char*)d_ws;
  size_t off=0;
  auto alloc=[&](size_t bytes)->void*{ void* p=ws+off; off=(off+bytes+255)&~(size_t)255; return p; };
  int*   deg  =(int*)  alloc((size_t)N*4);
  float* dinv =(float*)alloc((size_t)N*4);
  int*   rp   =(int*)  alloc((size_t)(N+1)*4);
  int*   fill =(int*)  alloc((size_t)N*4);
  int*   part =(int*)  alloc((size_t)SCB*4);
  int2*  epack=(int2*) alloc((size_t)E*8);
  unsigned short* hb   =(unsigned short*)alloc((size_t)N*64*2);
  unsigned short* aggb =(unsigned short*)alloc((size_t)N*64*2);
  float* hl   =(float*)alloc((size_t)NB*DIM*4);
  float* cl   =(float*)alloc((size_t)NB*DIM*4);
  float* apart=(float*)alloc((size_t)NB*KB*68*4);
  unsigned short* Bgru =(unsigned short*)alloc(128*256*2);
  unsigned short* Blin =(unsigned short*)alloc(128*64*2);
  unsigned short* Bcnv =(unsigned short*)alloc(64*64*2);

  hipMemsetAsync(deg ,0,(size_t)N*4,stream);
  hipMemsetAsync(fill,0,(size_t)N*4,stream);
  hipMemsetAsync(hl  ,0,(size_t)NB*DIM*4,stream);
  hipMemsetAsync(cl  ,0,(size_t)NB*DIM*4,stream);
  hipMemsetAsync(qstar,0,(size_t)NB*2*DIM*4,stream);

  k_count<<<(E+255)/256,256,0,stream>>>(col,deg,E);
  k_dinv <<<(N+255)/256,256,0,stream>>>(deg,dinv,N);
  k_scan_part<<<SCB,256,0,stream>>>(deg,part,N);
  k_scan_mid <<<1,256,0,stream>>>(part);
  k_scan_out <<<SCB,256,0,stream>>>(deg,part,rp,N);
  k_fill <<<(E+255)/256,256,0,stream>>>(row,col,dinv,rp,fill,epack,E);

  k_prep_plain<<<(128*64+255)/256,256,0,stream>>>(lin0_w,Blin,128,64);
  k_prep_plain<<<(64*64+255)/256,256,0,stream>>>(conv_w,Bcnv,64,64);
  k_prep_gru  <<<(128*256+255)/256,256,0,stream>>>(gwih,gwhh,Bgru);

  int ngrp=(N+15)/16;
  int gb=(ngrp+3)/4;

  k_lin0<<<gb,256,0,stream>>>(x,Blin,lin0_b,h,hb,ngrp);

  for(int it=0;it<3;it++){
    k_aggregate<<<(N+3)/4,256,0,stream>>>(hb,rp,epack,dinv,aggb,N);
    k_gru      <<<gb,256,0,stream>>>(aggb,hb,Bcnv,conv_b,Bgru,gbih,gbhh,h,ngrp,N);
  }

  // Set2Set: lstm0; [attn, merge+lstm] x2; attn; merge(final)
  k_merge_lstm<<<NB,256,0,stream>>>(apart,qstar,hl,cl,lwih,lwhh,lbih,lbhh,0,1);
  for(int st=0;st<3;st++){
    k_attn_part<<<NB*KB,256,0,stream>>>(hb,batch,hl,apart,N);
    int do_lstm = (st<2)? 1:0;
    k_merge_lstm<<<NB,256,0,stream>>>(apart,qstar,hl,cl,lwih,lwhh,lbih,lbhh,1,do_lstm);
  }
}

// Round 6
// 736.740 us; speedup vs baseline: 4.6038x; 1.1471x over previous
//
#include <hip/hip_runtime.h>
#include <math.h>

#define FEATD 128
#define DIM 64
#define NB 256
#define SCB 256
#define KB 16   // attention partial blocks per graph

typedef short bf16x8 __attribute__((ext_vector_type(8)));
typedef float f32x4 __attribute__((ext_vector_type(4)));

__device__ __forceinline__ float frcp_(float x){ return __builtin_amdgcn_rcpf(x); }
__device__ __forceinline__ float sigmoidf_(float x){ return frcp_(1.f+__expf(-x)); }
__device__ __forceinline__ float tanhf_(float x){ float e=__expf(2.f*x); return 1.f-2.f*frcp_(e+1.f); }

__device__ __forceinline__ unsigned short f2bf(float f){
  unsigned u = __float_as_uint(f);
  unsigned r = (u + 0x7FFFu + ((u>>16)&1u)) >> 16;
  return (unsigned short)r;
}
__device__ __forceinline__ float bf2f(unsigned short s){
  return __uint_as_float(((unsigned)s)<<16);
}

__device__ __forceinline__ int lower_bound_i(const int* __restrict__ a, int n, int key){
  int lo=0, hi=n;
  while(lo<hi){ int mid=(lo+hi)>>1; if(a[mid]<key) lo=mid+1; else hi=mid; }
  return lo;
}

// ======================= CSR setup =======================
__global__ void k_count(const int* __restrict__ col, int* __restrict__ deg, int E){
  int i=blockIdx.x*blockDim.x+threadIdx.x;
  if(i<E) atomicAdd(&deg[col[i]],1);
}

__global__ void k_dinv(const int* __restrict__ deg, float* __restrict__ dinv, int n){
  int i=blockIdx.x*blockDim.x+threadIdx.x;
  if(i<n) dinv[i]=rsqrtf((float)(deg[i]+1)); // +1 self-loop
}

// --- multi-block exclusive scan ---
__global__ __launch_bounds__(256) void k_scan_part(const int* __restrict__ deg, int* __restrict__ part, int n){
  __shared__ int s[256];
  int b=blockIdx.x;
  int chunk=(n+SCB-1)/SCB;
  int lo=b*chunk, hi=min(lo+chunk,n);
  int acc=0;
  for(int i=lo+threadIdx.x;i<hi;i+=256) acc+=deg[i];
  s[threadIdx.x]=acc; __syncthreads();
  for(int off=128;off;off>>=1){
    if(threadIdx.x<off) s[threadIdx.x]+=s[threadIdx.x+off];
    __syncthreads();
  }
  if(threadIdx.x==0) part[b]=s[0];
}

__global__ __launch_bounds__(256) void k_scan_mid(int* __restrict__ part){
  __shared__ int s[256];
  int t=threadIdx.x;
  s[t]=part[t]; __syncthreads();
  for(int off=1;off<256;off<<=1){
    int v=(t>=off)? s[t-off]:0;
    __syncthreads();
    s[t]+=v;
    __syncthreads();
  }
  part[t]=(t>0)? s[t-1]:0;  // exclusive
}

__global__ __launch_bounds__(256) void k_scan_out(const int* __restrict__ deg, const int* __restrict__ part,
                                                  int* __restrict__ rp, int n){
  __shared__ int s[256];
  int b=blockIdx.x, t=threadIdx.x;
  int chunk=(n+SCB-1)/SCB;
  int lo=b*chunk, hi=min(lo+chunk,n);
  int tchunk=(chunk+255)/256;
  int tlo=lo+t*tchunk, thi=min(tlo+tchunk,hi);
  int acc=0;
  for(int i=tlo;i<thi;i++) acc+=deg[i];
  s[t]=acc; __syncthreads();
  for(int off=1;off<256;off<<=1){
    int v=(t>=off)? s[t-off]:0;
    __syncthreads();
    s[t]+=v;
    __syncthreads();
  }
  int pre=part[b]+((t>0)? s[t-1]:0);
  for(int i=tlo;i<thi;i++){ rp[i]=pre; pre+=deg[i]; }
  if(b==SCB-1 && t==0) rp[n]=part[b]+s[255];
}

// CSR fill: packed (src, norm) per edge slot
__global__ void k_fill(const int* __restrict__ row, const int* __restrict__ col,
                       const float* __restrict__ dinv, const int* __restrict__ rp,
                       int* __restrict__ fill, int2* __restrict__ epack, int E){
  int i=blockIdx.x*blockDim.x+threadIdx.x;
  if(i>=E) return;
  int r=row[i], c=col[i];
  int pos=atomicAdd(&fill[c],1);
  int idx=rp[c]+pos;
  epack[idx]=make_int2(r,__float_as_int(dinv[r]*dinv[c]));
}

// ======================= MFMA B-fragment prep =======================
// mfma_f32_16x16x32_bf16 fragments:
//   A: lane l holds row (l&15), k = s*32 + (l>>4)*8 + r   (r=0..7)
//   B: lane l holds col (l&15), k = s*32 + (l>>4)*8 + r
//   D: lane l holds col (l&15), row = (l>>4)*4 + reg
// Plain (t-major) frags: Bf[((t*S + s)*64 + lane)*8 + r] = W[k][c], t=c/16, S=K/32.
__global__ void k_prep_plain(const float* __restrict__ W, unsigned short* __restrict__ Bf, int K, int C){
  int i=blockIdx.x*blockDim.x+threadIdx.x;
  if(i>=K*C) return;
  int k=i/C, c=i%C;
  int t=c>>4, s=k>>5, lane=(c&15)|(((k>>3)&3)<<4), r=k&7;
  int S=K>>5;
  Bf[(((t*S)+s)*64+lane)*8+r]=f2bf(W[(size_t)k*C+c]);
}

// Assembled GRU weights, S-MAJOR frag order (f = s*16+t) so each 32KB half is contiguous.
// X=[m|h] (K=128), cols: [0,64)=r, [64,128)=z, [128,192)=in_, [192,256)=hn.
__global__ void k_prep_gru(const float* __restrict__ wih, const float* __restrict__ whh,
                           unsigned short* __restrict__ Bf){
  int i=blockIdx.x*blockDim.x+threadIdx.x;
  if(i>=128*256) return;
  int k=i>>8, c=i&255;
  float v;
  if(c<128){          // r,z
    v = (k<64) ? wih[c*64+k] : whh[c*64+(k-64)];
  } else if(c<192){   // in_
    v = (k<64) ? wih[c*64+k] : 0.f;
  } else {            // hn
    v = (k<64) ? 0.f : whh[(c-64)*64+(k-64)];
  }
  int t=c>>4, s=k>>5, lane=(c&15)|(((k>>3)&3)<<4), r=k&7;
  Bf[(((s*16)+t)*64+lane)*8+r]=f2bf(v);
}

// ======================= lin0: h = relu(x @ W + b); writes f32 h + bf16 hb ===================
__global__ __launch_bounds__(256) void k_lin0(const float* __restrict__ x, const unsigned short* __restrict__ Bf,
                      const float* __restrict__ bias, float* __restrict__ h,
                      unsigned short* __restrict__ hb, int ngrp){
  int l=threadIdx.x&63;
  int g=blockIdx.x*4+(threadIdx.x>>6);
  if(g>=ngrp) return;
  int row16=l&15, koff=(l>>4)*8;
  f32x4 acc[4]={};
  const float* xr = x + (size_t)(g*16+row16)*128 + koff;
  #pragma unroll
  for(int s=0;s<4;s++){
    f32x4 a0=*(const f32x4*)(xr+s*32);
    f32x4 a1=*(const f32x4*)(xr+s*32+4);
    bf16x8 af;
    #pragma unroll
    for(int r=0;r<4;r++){ af[r]=(short)f2bf(a0[r]); af[4+r]=(short)f2bf(a1[r]); }
    #pragma unroll
    for(int t=0;t<4;t++){
      bf16x8 bf=*(const bf16x8*)(Bf+(((t*4)+s)*64+l)*8);
      acc[t]=__builtin_amdgcn_mfma_f32_16x16x32_bf16(af,bf,acc[t],0,0,0);
    }
  }
  int rbase=g*16+(l>>4)*4;
  #pragma unroll
  for(int t=0;t<4;t++){
    int c=t*16+(l&15);
    float b=bias[c];
    #pragma unroll
    for(int j=0;j<4;j++){
      int node=rbase+j;
      float v=fmaxf(acc[t][j]+b,0.f);
      h[(size_t)node*64+c]=v;
      hb[(size_t)node*64+c]=f2bf(v);
    }
  }
}

// ======================= aggregate: agg = Â h — half-wave edge parallel, 2 chains/half =========
__global__ __launch_bounds__(256) void k_aggregate(const unsigned short* __restrict__ hb, const int* __restrict__ rp,
                        const int2* __restrict__ epack, const float* __restrict__ dinv,
                        unsigned short* __restrict__ aggb, int n){
  int node=blockIdx.x*4+(threadIdx.x>>6);
  int lane=threadIdx.x&63;
  if(node>=n) return;
  int half=lane>>5, l32=lane&31;
  const unsigned* hb32=(const unsigned*)hb;   // one dword = 2 bf16 features
  float ax=0.f, ay=0.f, bx=0.f, by=0.f;
  int s=rp[node], e=rp[node+1];
  int j=s+half;
  for(; j+2<e; j+=4){
    int2 e0=epack[j];
    int2 e1=epack[j+2];
    unsigned p0=hb32[(size_t)e0.x*32+l32];
    unsigned p1=hb32[(size_t)e1.x*32+l32];
    float n0=__int_as_float(e0.y), n1=__int_as_float(e1.y);
    ax+=n0*bf2f((unsigned short)p0);
    ay+=n0*bf2f((unsigned short)(p0>>16));
    bx+=n1*bf2f((unsigned short)p1);
    by+=n1*bf2f((unsigned short)(p1>>16));
  }
  for(; j<e; j+=2){
    int2 e0=epack[j];
    unsigned p0=hb32[(size_t)e0.x*32+l32];
    float n0=__int_as_float(e0.y);
    ax+=n0*bf2f((unsigned short)p0);
    ay+=n0*bf2f((unsigned short)(p0>>16));
  }
  ax+=bx; ay+=by;
  if(half==0){ // self-loop term once
    float dv=dinv[node];
    unsigned ps=hb32[(size_t)node*32+l32];
    ax+=dv*dv*bf2f((unsigned short)ps);
    ay+=dv*dv*bf2f((unsigned short)(ps>>16));
  }
  ax+=__shfl_xor(ax,32);
  ay+=__shfl_xor(ay,32);
  if(half==0){
    unsigned out=(unsigned)f2bf(ax) | (((unsigned)f2bf(ay))<<16);
    ((unsigned*)aggb)[(size_t)node*32+l32]=out;
  }
}

// ======================= fused conv+GRU, LDS-staged weights ===================
// m = relu(agg@Wc+cb); h' = GRU(m,h). Bgru staged in 2x32KB halves, Bcnv 8KB.
__global__ __launch_bounds__(256) void k_gru(const unsigned short* __restrict__ aggb, unsigned short* hb,
                     const unsigned short* __restrict__ Bcnv, const float* __restrict__ cb,
                     const unsigned short* __restrict__ Bgru,
                     const float* __restrict__ bih, const float* __restrict__ bhh,
                     float* h, int ngrp, int n){
  __shared__ __align__(16) unsigned short Bs[16384];      // 32 KB: one half = frags f=[s*16+t], s in {half*2, half*2+1}
  __shared__ __align__(16) unsigned short Bc[4096];       // 8 KB conv frags (t-major, S=2)
  __shared__ __align__(16) unsigned short mt[4][16][72];  // 9 KB per-wave m tiles (padded)
  int tid=threadIdx.x;
  int l=tid&63, w=tid>>6;
  int g=blockIdx.x*4+w;
  bool act = g<ngrp;
  int gc = act? g : (ngrp-1);
  int row16=l&15, koff=(l>>4)*8;
  int node_r=gc*16+row16;
  int rbase=gc*16+(l>>4)*4;

  // --- prefetch all per-thread global data up front ---
  const unsigned short* ar = aggb + (size_t)node_r*64 + koff;
  const unsigned short* hr = hb   + (size_t)node_r*64 + koff;
  bf16x8 a_agg0=*(const bf16x8*)(ar);
  bf16x8 a_agg1=*(const bf16x8*)(ar+32);
  bf16x8 a_h0=*(const bf16x8*)(hr);
  bf16x8 a_h1=*(const bf16x8*)(hr+32);
  float hold[16];
  #pragma unroll
  for(int t=0;t<4;t++)
    #pragma unroll
    for(int j=0;j<4;j++)
      hold[t*4+j]=h[(size_t)(rbase+j)*64 + t*16+(l&15)];

  // --- stage Bcnv (8KB) + Bgru half0 (32KB) ---
  {
    const f32x4* gs=(const f32x4*)Bcnv; f32x4* ls=(f32x4*)Bc;
    #pragma unroll
    for(int i=0;i<2;i++) ls[i*256+tid]=gs[i*256+tid];
    const f32x4* gh=(const f32x4*)Bgru; f32x4* lh=(f32x4*)Bs;
    #pragma unroll
    for(int i=0;i<8;i++) lh[i*256+tid]=gh[i*256+tid];
  }
  __syncthreads();

  // --- mini conv GEMM: m = relu(agg[16x64]@Wc[64x64]+cb) ---
  f32x4 accm[4]={};
  #pragma unroll
  for(int s=0;s<2;s++){
    bf16x8 af=(s==0)? a_agg0:a_agg1;
    #pragma unroll
    for(int t=0;t<4;t++){
      bf16x8 bf=*(const bf16x8*)(Bc+((t*2+s)*64+l)*8);
      accm[t]=__builtin_amdgcn_mfma_f32_16x16x32_bf16(af,bf,accm[t],0,0,0);
    }
  }
  #pragma unroll
  for(int t=0;t<4;t++){
    int c=t*16+(l&15);
    float b=cb[c];
    #pragma unroll
    for(int j=0;j<4;j++)
      mt[w][(l>>4)*4+j][c]=f2bf(fmaxf(accm[t][j]+b,0.f));
  }
  // (mt written+read by the same wave; compiler inserts lgkmcnt wait)

  // --- GRU GEMM, k-half 0 (s=0,1): A = m from mt ---
  f32x4 acc[16]={};
  #pragma unroll
  for(int s=0;s<2;s++){
    bf16x8 af=*(const bf16x8*)&mt[w][row16][koff+s*32];
    #pragma unroll
    for(int t=0;t<16;t++){
      bf16x8 bf=*(const bf16x8*)(Bs+((s*16+t)*64+l)*8);
      acc[t]=__builtin_amdgcn_mfma_f32_16x16x32_bf16(af,bf,acc[t],0,0,0);
    }
  }
  __syncthreads();   // everyone done reading half0
  {
    const f32x4* gh=(const f32x4*)(Bgru+16384); f32x4* lh=(f32x4*)Bs;
    #pragma unroll
    for(int i=0;i<8;i++) lh[i*256+tid]=gh[i*256+tid];
  }
  __syncthreads();   // half1 ready

  // --- GRU GEMM, k-half 1 (s=2,3): A = h from registers ---
  #pragma unroll
  for(int s=0;s<2;s++){
    bf16x8 af=(s==0)? a_h0:a_h1;
    #pragma unroll
    for(int t=0;t<16;t++){
      bf16x8 bf=*(const bf16x8*)(Bs+((s*16+t)*64+l)*8);
      acc[t]=__builtin_amdgcn_mfma_f32_16x16x32_bf16(af,bf,acc[t],0,0,0);
    }
  }

  if(!act) return;
  // --- epilogue: gates in-register ---
  #pragma unroll
  for(int t=0;t<4;t++){
    int d=t*16+(l&15);
    float br =bih[d]    +bhh[d];
    float bz =bih[64+d] +bhh[64+d];
    float bni=bih[128+d];
    float bnh=bhh[128+d];
    #pragma unroll
    for(int j=0;j<4;j++){
      int node=rbase+j;
      if(node<n){
        float r  = sigmoidf_(acc[t][j]   + br);
        float z  = sigmoidf_(acc[4+t][j] + bz);
        float nc = tanhf_(acc[8+t][j] + bni + r*(acc[12+t][j] + bnh));
        float hn = (1.f-z)*nc + z*hold[t*4+j];
        h[(size_t)node*64+d]=hn;
        hb[(size_t)node*64+d]=f2bf(hn);
      }
    }
  }
}

// ======================= Set2Set: parallel attention partials =======================
__global__ __launch_bounds__(256) void k_attn_part(const unsigned short* __restrict__ hb, const int* __restrict__ batch,
                        const float* __restrict__ hl, float* __restrict__ apart, int n){
  int b=blockIdx.x/KB, kb=blockIdx.x%KB;
  int tid=threadIdx.x, lane=tid&63, w=tid>>6;
  __shared__ float qs[64];
  __shared__ float wm[4], wsm[4];
  __shared__ float wacc[4][64];
  if(tid<64) qs[tid]=hl[b*64+tid];
  int lo=lower_bound_i(batch,n,b), hi=lower_bound_i(batch,n,b+1);
  int cnt=hi-lo;
  int chunk=(cnt+KB-1)/KB;
  int slo=lo+kb*chunk, shi=min(slo+chunk,hi);
  __syncthreads();
  float q=qs[lane];
  float mw=-3.0e38f, sw=0.f, aw=0.f;
  for(int i=slo+w;i<shi;i+=4){
    float f=bf2f(hb[(size_t)i*64+lane]);
    float v=f*q;
    #pragma unroll
    for(int off=32;off;off>>=1) v+=__shfl_xor(v,off);
    if(v>mw){
      float sc=__expf(mw-v);
      sw=sw*sc+1.f;
      aw=aw*sc+f;
      mw=v;
    } else {
      float p=__expf(v-mw);
      sw+=p;
      aw+=p*f;
    }
  }
  if(lane==0){ wm[w]=mw; wsm[w]=sw; }
  wacc[w][lane]=aw;
  __syncthreads();
  if(w==0){
    float M=fmaxf(fmaxf(wm[0],wm[1]),fmaxf(wm[2],wm[3]));
    float S=0.f, A=0.f;
    #pragma unroll
    for(int k=0;k<4;k++){
      float sc=__expf(wm[k]-M);
      S+=wsm[k]*sc;
      A+=wacc[k][lane]*sc;
    }
    float* p=apart+(size_t)blockIdx.x*68;
    p[lane]=A;
    if(lane==0){ p[64]=M; p[65]=S; }
  }
}

// merge partials -> r_read (qstar[64:128]); optionally run next LSTM cell -> q (qstar[0:64], hl)
__global__ __launch_bounds__(256) void k_merge_lstm(const float* __restrict__ apart,
                   float* __restrict__ qstar, float* __restrict__ hl, float* __restrict__ cl,
                   const float* __restrict__ wih, const float* __restrict__ whh,
                   const float* __restrict__ bih, const float* __restrict__ bhh,
                   int do_merge, int do_lstm){
  int b=blockIdx.x, tid=threadIdx.x;
  __shared__ float qs[128];
  __shared__ float gates[256];
  if(do_merge){
    if(tid<64){
      const float* p0=apart+(size_t)b*KB*68;
      float M=-3.0e38f;
      #pragma unroll
      for(int k=0;k<KB;k++) M=fmaxf(M,p0[k*68+64]);
      float S=0.f, A=0.f;
      #pragma unroll
      for(int k=0;k<KB;k++){
        float sc=__expf(p0[k*68+64]-M);
        S+=p0[k*68+65]*sc;
        A+=p0[k*68+tid]*sc;
      }
      float inv=(S>0.f)? 1.f/S:0.f;
      float r=A*inv;
      qs[64+tid]=r;
      qstar[b*128+64+tid]=r;
    }
  } else {
    if(tid<64) qs[64+tid]=qstar[b*128+64+tid];
  }
  if(tid<64) qs[tid]=hl[b*64+tid];   // q_t == previous LSTM hidden
  __syncthreads();
  if(!do_lstm) return;
  float acc=bih[tid]+bhh[tid];
  const float* wi=wih+(size_t)tid*128;
  #pragma unroll 8
  for(int k=0;k<128;k++) acc+=qs[k]*wi[k];
  const float* w2=whh+(size_t)tid*64;
  #pragma unroll 8
  for(int k=0;k<64;k++) acc+=qs[k]*w2[k];
  gates[tid]=acc;
  __syncthreads();
  if(tid<64){
    float i_=gates[tid], f_=gates[64+tid], g_=gates[128+tid], o_=gates[192+tid];
    float c=sigmoidf_(f_)*cl[b*64+tid]+sigmoidf_(i_)*tanhf(g_);
    float hn=sigmoidf_(o_)*tanhf(c);
    cl[b*64+tid]=c; hl[b*64+tid]=hn;
    qstar[b*128+tid]=hn;
  }
}

extern "C" void kernel_launch(void* const* d_in, const int* in_sizes, int n_in,
                              void* d_out, int out_size, void* d_ws, size_t ws_size,
                              hipStream_t stream){
  const float* x      =(const float*)d_in[0];
  const int*   ei     =(const int*)d_in[1];
  const int*   batch  =(const int*)d_in[2];
  const float* lin0_w =(const float*)d_in[3];
  const float* lin0_b =(const float*)d_in[4];
  const float* conv_w =(const float*)d_in[5];
  const float* conv_b =(const float*)d_in[6];
  const float* gwih   =(const float*)d_in[7];
  const float* gwhh   =(const float*)d_in[8];
  const float* gbih   =(const float*)d_in[9];
  const float* gbhh   =(const float*)d_in[10];
  const float* lwih   =(const float*)d_in[11];
  const float* lwhh   =(const float*)d_in[12];
  const float* lbih   =(const float*)d_in[13];
  const float* lbhh   =(const float*)d_in[14];

  int N = in_sizes[0]/FEATD;
  int E = in_sizes[1]/2;
  const int* row = ei;
  const int* col = ei + E;

  float* qstar = (float*)d_out;            // [256,128]
  float* h     = (float*)d_out + NB*2*DIM; // [N,64] 'feat' = f32 h

  char* ws=(char*)d_ws;
  size_t off=0;
  auto alloc=[&](size_t bytes)->void*{ void* p=ws+off; off=(off+bytes+255)&~(size_t)255; return p; };
  int*   deg  =(int*)  alloc((size_t)N*4);
  float* dinv =(float*)alloc((size_t)N*4);
  int*   rp   =(int*)  alloc((size_t)(N+1)*4);
  int*   fill =(int*)  alloc((size_t)N*4);
  int*   part =(int*)  alloc((size_t)SCB*4);
  int2*  epack=(int2*) alloc((size_t)E*8);
  unsigned short* hb   =(unsigned short*)alloc((size_t)N*64*2);
  unsigned short* aggb =(unsigned short*)alloc((size_t)N*64*2);
  float* hl   =(float*)alloc((size_t)NB*DIM*4);
  float* cl   =(float*)alloc((size_t)NB*DIM*4);
  float* apart=(float*)alloc((size_t)NB*KB*68*4);
  unsigned short* Bgru =(unsigned short*)alloc(128*256*2);
  unsigned short* Blin =(unsigned short*)alloc(128*64*2);
  unsigned short* Bcnv =(unsigned short*)alloc(64*64*2);

  hipMemsetAsync(deg ,0,(size_t)N*4,stream);
  hipMemsetAsync(fill,0,(size_t)N*4,stream);
  hipMemsetAsync(hl  ,0,(size_t)NB*DIM*4,stream);
  hipMemsetAsync(cl  ,0,(size_t)NB*DIM*4,stream);
  hipMemsetAsync(qstar,0,(size_t)NB*2*DIM*4,stream);

  k_count<<<(E+255)/256,256,0,stream>>>(col,deg,E);
  k_dinv <<<(N+255)/256,256,0,stream>>>(deg,dinv,N);
  k_scan_part<<<SCB,256,0,stream>>>(deg,part,N);
  k_scan_mid <<<1,256,0,stream>>>(part);
  k_scan_out <<<SCB,256,0,stream>>>(deg,part,rp,N);
  k_fill <<<(E+255)/256,256,0,stream>>>(row,col,dinv,rp,fill,epack,E);

  k_prep_plain<<<(128*64+255)/256,256,0,stream>>>(lin0_w,Blin,128,64);
  k_prep_plain<<<(64*64+255)/256,256,0,stream>>>(conv_w,Bcnv,64,64);
  k_prep_gru  <<<(128*256+255)/256,256,0,stream>>>(gwih,gwhh,Bgru);

  int ngrp=(N+15)/16;
  int gb=(ngrp+3)/4;

  k_lin0<<<gb,256,0,stream>>>(x,Blin,lin0_b,h,hb,ngrp);

  for(int it=0;it<3;it++){
    k_aggregate<<<(N+3)/4,256,0,stream>>>(hb,rp,epack,dinv,aggb,N);
    k_gru      <<<gb,256,0,stream>>>(aggb,hb,Bcnv,conv_b,Bgru,gbih,gbhh,h,ngrp,N);
  }

  // Set2Set: lstm0; [attn, merge+lstm] x2; attn; merge(final)
  k_merge_lstm<<<NB,256,0,stream>>>(apart,qstar,hl,cl,lwih,lwhh,lbih,lbhh,0,1);
  for(int st=0;st<3;st++){
    k_attn_part<<<NB*KB,256,0,stream>>>(hb,batch,hl,apart,N);
    int do_lstm = (st<2)? 1:0;
    k_merge_lstm<<<NB,256,0,stream>>>(apart,qstar,hl,cl,lwih,lwhh,lbih,lbhh,1,do_lstm);
  }
}

// Round 7
// 688.238 us; speedup vs baseline: 4.9282x; 1.0705x over previous
//
#include <hip/hip_runtime.h>
#include <math.h>

#define FEATD 128
#define DIM 64
#define NB 256
#define SCB 256
#define KB 16      // attention partial blocks per graph
#define RNG 128    // nodes per CSR-fill bucket
#define NBUCKMAX 2048
#define CH1 8192   // edges per block, bin-scatter phase

typedef short bf16x8 __attribute__((ext_vector_type(8)));
typedef float f32x4 __attribute__((ext_vector_type(4)));

__device__ __forceinline__ float frcp_(float x){ return __builtin_amdgcn_rcpf(x); }
__device__ __forceinline__ float sigmoidf_(float x){ return frcp_(1.f+__expf(-x)); }
__device__ __forceinline__ float tanhf_(float x){ float e=__expf(2.f*x); return 1.f-2.f*frcp_(e+1.f); }

__device__ __forceinline__ unsigned short f2bf(float f){
  unsigned u = __float_as_uint(f);
  unsigned r = (u + 0x7FFFu + ((u>>16)&1u)) >> 16;
  return (unsigned short)r;
}
__device__ __forceinline__ float bf2f(unsigned short s){
  return __uint_as_float(((unsigned)s)<<16);
}

__device__ __forceinline__ int lower_bound_i(const int* __restrict__ a, int n, int key){
  int lo=0, hi=n;
  while(lo<hi){ int mid=(lo+hi)>>1; if(a[mid]<key) lo=mid+1; else hi=mid; }
  return lo;
}

// ======================= CSR setup =======================
__global__ void k_count(const int* __restrict__ col, int* __restrict__ deg, int E){
  int i=blockIdx.x*blockDim.x+threadIdx.x;
  if(i<E) atomicAdd(&deg[col[i]],1);
}

__global__ void k_dinv(const int* __restrict__ deg, float* __restrict__ dinv, int n){
  int i=blockIdx.x*blockDim.x+threadIdx.x;
  if(i<n) dinv[i]=rsqrtf((float)(deg[i]+1)); // +1 self-loop
}

// --- multi-block exclusive scan ---
__global__ __launch_bounds__(256) void k_scan_part(const int* __restrict__ deg, int* __restrict__ part, int n){
  __shared__ int s[256];
  int b=blockIdx.x;
  int chunk=(n+SCB-1)/SCB;
  int lo=b*chunk, hi=min(lo+chunk,n);
  int acc=0;
  for(int i=lo+threadIdx.x;i<hi;i+=256) acc+=deg[i];
  s[threadIdx.x]=acc; __syncthreads();
  for(int off=128;off;off>>=1){
    if(threadIdx.x<off) s[threadIdx.x]+=s[threadIdx.x+off];
    __syncthreads();
  }
  if(threadIdx.x==0) part[b]=s[0];
}

__global__ __launch_bounds__(256) void k_scan_mid(int* __restrict__ part){
  __shared__ int s[256];
  int t=threadIdx.x;
  s[t]=part[t]; __syncthreads();
  for(int off=1;off<256;off<<=1){
    int v=(t>=off)? s[t-off]:0;
    __syncthreads();
    s[t]+=v;
    __syncthreads();
  }
  part[t]=(t>0)? s[t-1]:0;  // exclusive
}

__global__ __launch_bounds__(256) void k_scan_out(const int* __restrict__ deg, const int* __restrict__ part,
                                                  int* __restrict__ rp, int n){
  __shared__ int s[256];
  int b=blockIdx.x, t=threadIdx.x;
  int chunk=(n+SCB-1)/SCB;
  int lo=b*chunk, hi=min(lo+chunk,n);
  int tchunk=(chunk+255)/256;
  int tlo=lo+t*tchunk, thi=min(tlo+tchunk,hi);
  int acc=0;
  for(int i=tlo;i<thi;i++) acc+=deg[i];
  s[t]=acc; __syncthreads();
  for(int off=1;off<256;off<<=1){
    int v=(t>=off)? s[t-off]:0;
    __syncthreads();
    s[t]+=v;
    __syncthreads();
  }
  int pre=part[b]+((t>0)? s[t-1]:0);
  for(int i=tlo;i<thi;i++){ rp[i]=pre; pre+=deg[i]; }
  if(b==SCB-1 && t==0) rp[n]=part[b]+s[255];
}

// ======================= bucketed CSR fill =======================
// gcur[b*32] = running cursor for bucket b (padded to 128B to spread channels)
__global__ void k_binit(const int* __restrict__ rp, int* __restrict__ gcur, int nbuck, int n){
  int b=blockIdx.x*blockDim.x+threadIdx.x;
  if(b<nbuck) gcur[b*32]=rp[min(b*RNG,n)];
}

// phase 1: scatter edges into bucket-ordered tmp, packed (r<<7)|(c&127)
__global__ __launch_bounds__(256) void k_binscat(const int* __restrict__ row, const int* __restrict__ col,
                       int* __restrict__ gcur, unsigned* __restrict__ tmp, int E, int nbuck){
  __shared__ int lcnt[NBUCKMAX];
  __shared__ int lcur[NBUCKMAX];
  int t=threadIdx.x;
  for(int i=t;i<nbuck;i+=256) lcnt[i]=0;
  __syncthreads();
  int lo=blockIdx.x*CH1, hi=min(lo+CH1,E);
  for(int i=lo+t;i<hi;i+=256) atomicAdd(&lcnt[col[i]>>7],1);
  __syncthreads();
  for(int i=t;i<nbuck;i+=256){
    int cnt=lcnt[i];
    lcur[i]=(cnt>0)? atomicAdd(&gcur[i*32],cnt):0;
  }
  __syncthreads();
  for(int i=lo+t;i<hi;i+=256){
    int c=col[i], r=row[i];
    int pos=atomicAdd(&lcur[c>>7],1);
    tmp[pos]=((unsigned)r<<7)|(unsigned)(c&127);
  }
}

// phase 2: one block per bucket; LDS fill counters; write (src, norm) into node slots
__global__ __launch_bounds__(256) void k_place(const unsigned* __restrict__ tmp, const int* __restrict__ rp,
                      const float* __restrict__ dinv, int2* __restrict__ epack, int n, int nbuck){
  __shared__ int lfill[RNG];
  __shared__ int lrp[RNG];
  __shared__ float ldv[RNG];
  int b=blockIdx.x, t=threadIdx.x;
  int nbase=b*RNG;
  int nn=min(RNG,n-nbase);
  if(t<nn){ lfill[t]=0; lrp[t]=rp[nbase+t]; ldv[t]=dinv[nbase+t]; }
  __syncthreads();
  int lo=rp[nbase], hi=rp[min(nbase+RNG,n)];
  for(int j=lo+t;j<hi;j+=256){
    unsigned v=tmp[j];
    int cl=v&127;
    int r=(int)(v>>7);
    int pos=atomicAdd(&lfill[cl],1);
    epack[lrp[cl]+pos]=make_int2(r,__float_as_int(dinv[r]*ldv[cl]));
  }
}

// ======================= MFMA B-fragment prep =======================
// mfma_f32_16x16x32_bf16 fragments:
//   A: lane l holds row (l&15), k = s*32 + (l>>4)*8 + r   (r=0..7)
//   B: lane l holds col (l&15), k = s*32 + (l>>4)*8 + r
//   D: lane l holds col (l&15), row = (l>>4)*4 + reg
// Plain (t-major) frags: Bf[((t*S + s)*64 + lane)*8 + r] = W[k][c], t=c/16, S=K/32.
__global__ void k_prep_plain(const float* __restrict__ W, unsigned short* __restrict__ Bf, int K, int C){
  int i=blockIdx.x*blockDim.x+threadIdx.x;
  if(i>=K*C) return;
  int k=i/C, c=i%C;
  int t=c>>4, s=k>>5, lane=(c&15)|(((k>>3)&3)<<4), r=k&7;
  int S=K>>5;
  Bf[(((t*S)+s)*64+lane)*8+r]=f2bf(W[(size_t)k*C+c]);
}

// Assembled GRU weights, S-MAJOR frag order (f = s*16+t) so each 32KB half is contiguous.
// X=[m|h] (K=128), cols: [0,64)=r, [64,128)=z, [128,192)=in_, [192,256)=hn.
__global__ void k_prep_gru(const float* __restrict__ wih, const float* __restrict__ whh,
                           unsigned short* __restrict__ Bf){
  int i=blockIdx.x*blockDim.x+threadIdx.x;
  if(i>=128*256) return;
  int k=i>>8, c=i&255;
  float v;
  if(c<128){          // r,z
    v = (k<64) ? wih[c*64+k] : whh[c*64+(k-64)];
  } else if(c<192){   // in_
    v = (k<64) ? wih[c*64+k] : 0.f;
  } else {            // hn
    v = (k<64) ? 0.f : whh[(c-64)*64+(k-64)];
  }
  int t=c>>4, s=k>>5, lane=(c&15)|(((k>>3)&3)<<4), r=k&7;
  Bf[(((s*16)+t)*64+lane)*8+r]=f2bf(v);
}

// ======================= lin0: h = relu(x @ W + b); writes f32 h + bf16 hb ===================
__global__ __launch_bounds__(256) void k_lin0(const float* __restrict__ x, const unsigned short* __restrict__ Bf,
                      const float* __restrict__ bias, float* __restrict__ h,
                      unsigned short* __restrict__ hb, int ngrp){
  int l=threadIdx.x&63;
  int g=blockIdx.x*4+(threadIdx.x>>6);
  if(g>=ngrp) return;
  int row16=l&15, koff=(l>>4)*8;
  f32x4 acc[4]={};
  const float* xr = x + (size_t)(g*16+row16)*128 + koff;
  #pragma unroll
  for(int s=0;s<4;s++){
    f32x4 a0=*(const f32x4*)(xr+s*32);
    f32x4 a1=*(const f32x4*)(xr+s*32+4);
    bf16x8 af;
    #pragma unroll
    for(int r=0;r<4;r++){ af[r]=(short)f2bf(a0[r]); af[4+r]=(short)f2bf(a1[r]); }
    #pragma unroll
    for(int t=0;t<4;t++){
      bf16x8 bf=*(const bf16x8*)(Bf+(((t*4)+s)*64+l)*8);
      acc[t]=__builtin_amdgcn_mfma_f32_16x16x32_bf16(af,bf,acc[t],0,0,0);
    }
  }
  int rbase=g*16+(l>>4)*4;
  #pragma unroll
  for(int t=0;t<4;t++){
    int c=t*16+(l&15);
    float b=bias[c];
    #pragma unroll
    for(int j=0;j<4;j++){
      int node=rbase+j;
      float v=fmaxf(acc[t][j]+b,0.f);
      h[(size_t)node*64+c]=v;
      hb[(size_t)node*64+c]=f2bf(v);
    }
  }
}

// ======================= aggregate: agg = Â h — quarter-wave rows, 2 chains = 8 gathers in flight =========
__global__ __launch_bounds__(256) void k_aggregate(const unsigned short* __restrict__ hb, const int* __restrict__ rp,
                        const int2* __restrict__ epack, const float* __restrict__ dinv,
                        unsigned short* __restrict__ aggb, int n){
  int node=blockIdx.x*4+(threadIdx.x>>6);
  int lane=threadIdx.x&63;
  if(node>=n) return;
  int q=lane>>4, l16=lane&15;
  const uint2* hb64=(const uint2*)hb;   // one uint2 = 4 bf16 features
  float a0=0.f,a1=0.f,a2=0.f,a3=0.f, b0=0.f,b1=0.f,b2=0.f,b3=0.f;
  int s=rp[node], e=rp[node+1];
  int j=s+q;
  for(; j+4<e; j+=8){
    int2 e0=epack[j];
    int2 e1=epack[j+4];
    uint2 p0=hb64[(size_t)e0.x*16+l16];
    uint2 p1=hb64[(size_t)e1.x*16+l16];
    float n0=__int_as_float(e0.y), n1=__int_as_float(e1.y);
    a0+=n0*bf2f((unsigned short)p0.x);
    a1+=n0*bf2f((unsigned short)(p0.x>>16));
    a2+=n0*bf2f((unsigned short)p0.y);
    a3+=n0*bf2f((unsigned short)(p0.y>>16));
    b0+=n1*bf2f((unsigned short)p1.x);
    b1+=n1*bf2f((unsigned short)(p1.x>>16));
    b2+=n1*bf2f((unsigned short)p1.y);
    b3+=n1*bf2f((unsigned short)(p1.y>>16));
  }
  for(; j<e; j+=4){
    int2 e0=epack[j];
    uint2 p0=hb64[(size_t)e0.x*16+l16];
    float n0=__int_as_float(e0.y);
    a0+=n0*bf2f((unsigned short)p0.x);
    a1+=n0*bf2f((unsigned short)(p0.x>>16));
    a2+=n0*bf2f((unsigned short)p0.y);
    a3+=n0*bf2f((unsigned short)(p0.y>>16));
  }
  a0+=b0; a1+=b1; a2+=b2; a3+=b3;
  if(q==0){ // self-loop term once
    float dv=dinv[node]; dv*=dv;
    uint2 ps=hb64[(size_t)node*16+l16];
    a0+=dv*bf2f((unsigned short)ps.x);
    a1+=dv*bf2f((unsigned short)(ps.x>>16));
    a2+=dv*bf2f((unsigned short)ps.y);
    a3+=dv*bf2f((unsigned short)(ps.y>>16));
  }
  a0+=__shfl_xor(a0,16); a0+=__shfl_xor(a0,32);
  a1+=__shfl_xor(a1,16); a1+=__shfl_xor(a1,32);
  a2+=__shfl_xor(a2,16); a2+=__shfl_xor(a2,32);
  a3+=__shfl_xor(a3,16); a3+=__shfl_xor(a3,32);
  if(q==0){
    uint2 outp;
    outp.x=(unsigned)f2bf(a0)|(((unsigned)f2bf(a1))<<16);
    outp.y=(unsigned)f2bf(a2)|(((unsigned)f2bf(a3))<<16);
    ((uint2*)aggb)[(size_t)node*16+l16]=outp;
  }
}

// ======================= fused conv+GRU, LDS-staged weights ===================
__global__ __launch_bounds__(256) void k_gru(const unsigned short* __restrict__ aggb, unsigned short* hb,
                     const unsigned short* __restrict__ Bcnv, const float* __restrict__ cb,
                     const unsigned short* __restrict__ Bgru,
                     const float* __restrict__ bih, const float* __restrict__ bhh,
                     float* h, int ngrp, int n){
  __shared__ __align__(16) unsigned short Bs[16384];      // 32 KB half of Bgru
  __shared__ __align__(16) unsigned short Bc[4096];       // 8 KB conv frags
  __shared__ __align__(16) unsigned short mt[4][16][72];  // per-wave m tiles (padded)
  int tid=threadIdx.x;
  int l=tid&63, w=tid>>6;
  int g=blockIdx.x*4+w;
  bool act = g<ngrp;
  int gc = act? g : (ngrp-1);
  int row16=l&15, koff=(l>>4)*8;
  int node_r=gc*16+row16;
  int rbase=gc*16+(l>>4)*4;

  const unsigned short* ar = aggb + (size_t)node_r*64 + koff;
  const unsigned short* hr = hb   + (size_t)node_r*64 + koff;
  bf16x8 a_agg0=*(const bf16x8*)(ar);
  bf16x8 a_agg1=*(const bf16x8*)(ar+32);
  bf16x8 a_h0=*(const bf16x8*)(hr);
  bf16x8 a_h1=*(const bf16x8*)(hr+32);
  float hold[16];
  #pragma unroll
  for(int t=0;t<4;t++)
    #pragma unroll
    for(int j=0;j<4;j++)
      hold[t*4+j]=h[(size_t)(rbase+j)*64 + t*16+(l&15)];

  {
    const f32x4* gs=(const f32x4*)Bcnv; f32x4* ls=(f32x4*)Bc;
    #pragma unroll
    for(int i=0;i<2;i++) ls[i*256+tid]=gs[i*256+tid];
    const f32x4* gh=(const f32x4*)Bgru; f32x4* lh=(f32x4*)Bs;
    #pragma unroll
    for(int i=0;i<8;i++) lh[i*256+tid]=gh[i*256+tid];
  }
  __syncthreads();

  f32x4 accm[4]={};
  #pragma unroll
  for(int s=0;s<2;s++){
    bf16x8 af=(s==0)? a_agg0:a_agg1;
    #pragma unroll
    for(int t=0;t<4;t++){
      bf16x8 bf=*(const bf16x8*)(Bc+((t*2+s)*64+l)*8);
      accm[t]=__builtin_amdgcn_mfma_f32_16x16x32_bf16(af,bf,accm[t],0,0,0);
    }
  }
  #pragma unroll
  for(int t=0;t<4;t++){
    int c=t*16+(l&15);
    float b=cb[c];
    #pragma unroll
    for(int j=0;j<4;j++)
      mt[w][(l>>4)*4+j][c]=f2bf(fmaxf(accm[t][j]+b,0.f));
  }

  f32x4 acc[16]={};
  #pragma unroll
  for(int s=0;s<2;s++){
    bf16x8 af=*(const bf16x8*)&mt[w][row16][koff+s*32];
    #pragma unroll
    for(int t=0;t<16;t++){
      bf16x8 bf=*(const bf16x8*)(Bs+((s*16+t)*64+l)*8);
      acc[t]=__builtin_amdgcn_mfma_f32_16x16x32_bf16(af,bf,acc[t],0,0,0);
    }
  }
  __syncthreads();
  {
    const f32x4* gh=(const f32x4*)(Bgru+16384); f32x4* lh=(f32x4*)Bs;
    #pragma unroll
    for(int i=0;i<8;i++) lh[i*256+tid]=gh[i*256+tid];
  }
  __syncthreads();

  #pragma unroll
  for(int s=0;s<2;s++){
    bf16x8 af=(s==0)? a_h0:a_h1;
    #pragma unroll
    for(int t=0;t<16;t++){
      bf16x8 bf=*(const bf16x8*)(Bs+((s*16+t)*64+l)*8);
      acc[t]=__builtin_amdgcn_mfma_f32_16x16x32_bf16(af,bf,acc[t],0,0,0);
    }
  }

  if(!act) return;
  #pragma unroll
  for(int t=0;t<4;t++){
    int d=t*16+(l&15);
    float br =bih[d]    +bhh[d];
    float bz =bih[64+d] +bhh[64+d];
    float bni=bih[128+d];
    float bnh=bhh[128+d];
    #pragma unroll
    for(int j=0;j<4;j++){
      int node=rbase+j;
      if(node<n){
        float r  = sigmoidf_(acc[t][j]   + br);
        float z  = sigmoidf_(acc[4+t][j] + bz);
        float nc = tanhf_(acc[8+t][j] + bni + r*(acc[12+t][j] + bnh));
        float hn = (1.f-z)*nc + z*hold[t*4+j];
        h[(size_t)node*64+d]=hn;
        hb[(size_t)node*64+d]=f2bf(hn);
      }
    }
  }
}

// ======================= Set2Set: parallel attention partials =======================
__global__ __launch_bounds__(256) void k_attn_part(const unsigned short* __restrict__ hb, const int* __restrict__ batch,
                        const float* __restrict__ hl, float* __restrict__ apart, int n){
  int b=blockIdx.x/KB, kb=blockIdx.x%KB;
  int tid=threadIdx.x, lane=tid&63, w=tid>>6;
  __shared__ float qs[64];
  __shared__ float wm[4], wsm[4];
  __shared__ float wacc[4][64];
  if(tid<64) qs[tid]=hl[b*64+tid];
  int lo=lower_bound_i(batch,n,b), hi=lower_bound_i(batch,n,b+1);
  int cnt=hi-lo;
  int chunk=(cnt+KB-1)/KB;
  int slo=lo+kb*chunk, shi=min(slo+chunk,hi);
  __syncthreads();
  float q=qs[lane];
  float mw=-3.0e38f, sw=0.f, aw=0.f;
  for(int i=slo+w;i<shi;i+=4){
    float f=bf2f(hb[(size_t)i*64+lane]);
    float v=f*q;
    #pragma unroll
    for(int off=32;off;off>>=1) v+=__shfl_xor(v,off);
    if(v>mw){
      float sc=__expf(mw-v);
      sw=sw*sc+1.f;
      aw=aw*sc+f;
      mw=v;
    } else {
      float p=__expf(v-mw);
      sw+=p;
      aw+=p*f;
    }
  }
  if(lane==0){ wm[w]=mw; wsm[w]=sw; }
  wacc[w][lane]=aw;
  __syncthreads();
  if(w==0){
    float M=fmaxf(fmaxf(wm[0],wm[1]),fmaxf(wm[2],wm[3]));
    float S=0.f, A=0.f;
    #pragma unroll
    for(int k=0;k<4;k++){
      float sc=__expf(wm[k]-M);
      S+=wsm[k]*sc;
      A+=wacc[k][lane]*sc;
    }
    float* p=apart+(size_t)blockIdx.x*68;
    p[lane]=A;
    if(lane==0){ p[64]=M; p[65]=S; }
  }
}

// merge partials -> r_read (qstar[64:128]); optionally run next LSTM cell
__global__ __launch_bounds__(256) void k_merge_lstm(const float* __restrict__ apart,
                   float* __restrict__ qstar, float* __restrict__ hl, float* __restrict__ cl,
                   const float* __restrict__ wih, const float* __restrict__ whh,
                   const float* __restrict__ bih, const float* __restrict__ bhh,
                   int do_merge, int do_lstm){
  int b=blockIdx.x, tid=threadIdx.x;
  __shared__ float qs[128];
  __shared__ float gates[256];
  if(do_merge){
    if(tid<64){
      const float* p0=apart+(size_t)b*KB*68;
      float M=-3.0e38f;
      #pragma unroll
      for(int k=0;k<KB;k++) M=fmaxf(M,p0[k*68+64]);
      float S=0.f, A=0.f;
      #pragma unroll
      for(int k=0;k<KB;k++){
        float sc=__expf(p0[k*68+64]-M);
        S+=p0[k*68+65]*sc;
        A+=p0[k*68+tid]*sc;
      }
      float inv=(S>0.f)? 1.f/S:0.f;
      float r=A*inv;
      qs[64+tid]=r;
      qstar[b*128+64+tid]=r;
    }
  } else {
    if(tid<64) qs[64+tid]=qstar[b*128+64+tid];
  }
  if(tid<64) qs[tid]=hl[b*64+tid];   // q_t == previous LSTM hidden
  __syncthreads();
  if(!do_lstm) return;
  float acc=bih[tid]+bhh[tid];
  const float* wi=wih+(size_t)tid*128;
  #pragma unroll 8
  for(int k=0;k<128;k++) acc+=qs[k]*wi[k];
  const float* w2=whh+(size_t)tid*64;
  #pragma unroll 8
  for(int k=0;k<64;k++) acc+=qs[k]*w2[k];
  gates[tid]=acc;
  __syncthreads();
  if(tid<64){
    float i_=gates[tid], f_=gates[64+tid], g_=gates[128+tid], o_=gates[192+tid];
    float c=sigmoidf_(f_)*cl[b*64+tid]+sigmoidf_(i_)*tanhf(g_);
    float hn=sigmoidf_(o_)*tanhf(c);
    cl[b*64+tid]=c; hl[b*64+tid]=hn;
    qstar[b*128+tid]=hn;
  }
}

extern "C" void kernel_launch(void* const* d_in, const int* in_sizes, int n_in,
                              void* d_out, int out_size, void* d_ws, size_t ws_size,
                              hipStream_t stream){
  const float* x      =(const float*)d_in[0];
  const int*   ei     =(const int*)d_in[1];
  const int*   batch  =(const int*)d_in[2];
  const float* lin0_w =(const float*)d_in[3];
  const float* lin0_b =(const float*)d_in[4];
  const float* conv_w =(const float*)d_in[5];
  const float* conv_b =(const float*)d_in[6];
  const float* gwih   =(const float*)d_in[7];
  const float* gwhh   =(const float*)d_in[8];
  const float* gbih   =(const float*)d_in[9];
  const float* gbhh   =(const float*)d_in[10];
  const float* lwih   =(const float*)d_in[11];
  const float* lwhh   =(const float*)d_in[12];
  const float* lbih   =(const float*)d_in[13];
  const float* lbhh   =(const float*)d_in[14];

  int N = in_sizes[0]/FEATD;
  int E = in_sizes[1]/2;
  const int* row = ei;
  const int* col = ei + E;

  float* qstar = (float*)d_out;            // [256,128]
  float* h     = (float*)d_out + NB*2*DIM; // [N,64] 'feat' = f32 h

  char* ws=(char*)d_ws;
  size_t off=0;
  auto alloc=[&](size_t bytes)->void*{ void* p=ws+off; off=(off+bytes+255)&~(size_t)255; return p; };
  int*   deg  =(int*)  alloc((size_t)N*4);
  float* dinv =(float*)alloc((size_t)N*4);
  int*   rp   =(int*)  alloc((size_t)(N+1)*4);
  int*   part =(int*)  alloc((size_t)SCB*4);
  int*   gcur =(int*)  alloc((size_t)NBUCKMAX*32*4);
  unsigned* tmp=(unsigned*)alloc((size_t)E*4);
  int2*  epack=(int2*) alloc((size_t)E*8);
  unsigned short* hb   =(unsigned short*)alloc((size_t)N*64*2);
  unsigned short* aggb =(unsigned short*)alloc((size_t)N*64*2);
  float* hl   =(float*)alloc((size_t)NB*DIM*4);
  float* cl   =(float*)alloc((size_t)NB*DIM*4);
  float* apart=(float*)alloc((size_t)NB*KB*68*4);
  unsigned short* Bgru =(unsigned short*)alloc(128*256*2);
  unsigned short* Blin =(unsigned short*)alloc(128*64*2);
  unsigned short* Bcnv =(unsigned short*)alloc(64*64*2);

  hipMemsetAsync(deg ,0,(size_t)N*4,stream);
  hipMemsetAsync(hl  ,0,(size_t)NB*DIM*4,stream);
  hipMemsetAsync(cl  ,0,(size_t)NB*DIM*4,stream);
  hipMemsetAsync(qstar,0,(size_t)NB*2*DIM*4,stream);

  int nbuck=(N+RNG-1)/RNG;

  k_count<<<(E+255)/256,256,0,stream>>>(col,deg,E);
  k_dinv <<<(N+255)/256,256,0,stream>>>(deg,dinv,N);
  k_scan_part<<<SCB,256,0,stream>>>(deg,part,N);
  k_scan_mid <<<1,256,0,stream>>>(part);
  k_scan_out <<<SCB,256,0,stream>>>(deg,part,rp,N);
  k_binit<<<(nbuck+255)/256,256,0,stream>>>(rp,gcur,nbuck,N);
  k_binscat<<<(E+CH1-1)/CH1,256,0,stream>>>(row,col,gcur,tmp,E,nbuck);
  k_place<<<nbuck,256,0,stream>>>(tmp,rp,dinv,epack,N,nbuck);

  k_prep_plain<<<(128*64+255)/256,256,0,stream>>>(lin0_w,Blin,128,64);
  k_prep_plain<<<(64*64+255)/256,256,0,stream>>>(conv_w,Bcnv,64,64);
  k_prep_gru  <<<(128*256+255)/256,256,0,stream>>>(gwih,gwhh,Bgru);

  int ngrp=(N+15)/16;
  int gb=(ngrp+3)/4;

  k_lin0<<<gb,256,0,stream>>>(x,Blin,lin0_b,h,hb,ngrp);

  for(int it=0;it<3;it++){
    k_aggregate<<<(N+3)/4,256,0,stream>>>(hb,rp,epack,dinv,aggb,N);
    k_gru      <<<gb,256,0,stream>>>(aggb,hb,Bcnv,conv_b,Bgru,gbih,gbhh,h,ngrp,N);
  }

  // Set2Set: lstm0; [attn, merge+lstm] x2; attn; merge(final)
  k_merge_lstm<<<NB,256,0,stream>>>(apart,qstar,hl,cl,lwih,lwhh,lbih,lbhh,0,1);
  for(int st=0;st<3;st++){
    k_attn_part<<<NB*KB,256,0,stream>>>(hb,batch,hl,apart,N);
    int do_lstm = (st<2)? 1:0;
    k_merge_lstm<<<NB,256,0,stream>>>(apart,qstar,hl,cl,lwih,lwhh,lbih,lbhh,1,do_lstm);
  }
}

// Round 8
// 658.606 us; speedup vs baseline: 5.1500x; 1.0450x over previous
//
#include <hip/hip_runtime.h>
#include <math.h>

#define FEATD 128
#define DIM 64
#define NB 256
#define SCB 256
#define KB 16      // attention partial blocks per graph
#define RNG 128    // nodes per CSR-fill bucket
#define NBUCKMAX 2048
#define CH1 8192   // edges per block, bin-scatter phase

typedef short bf16x8 __attribute__((ext_vector_type(8)));
typedef float f32x4 __attribute__((ext_vector_type(4)));

__device__ __forceinline__ float frcp_(float x){ return __builtin_amdgcn_rcpf(x); }
__device__ __forceinline__ float sigmoidf_(float x){ return frcp_(1.f+__expf(-x)); }
__device__ __forceinline__ float tanhf_(float x){ float e=__expf(2.f*x); return 1.f-2.f*frcp_(e+1.f); }

__device__ __forceinline__ unsigned short f2bf(float f){
  unsigned u = __float_as_uint(f);
  unsigned r = (u + 0x7FFFu + ((u>>16)&1u)) >> 16;
  return (unsigned short)r;
}
__device__ __forceinline__ float bf2f(unsigned short s){
  return __uint_as_float(((unsigned)s)<<16);
}

__device__ __forceinline__ int lower_bound_i(const int* __restrict__ a, int n, int key){
  int lo=0, hi=n;
  while(lo<hi){ int mid=(lo+hi)>>1; if(a[mid]<key) lo=mid+1; else hi=mid; }
  return lo;
}

// ======================= CSR setup =======================
__global__ void k_count(const int* __restrict__ col, int* __restrict__ deg, int E){
  int i=blockIdx.x*blockDim.x+threadIdx.x;
  if(i<E) atomicAdd(&deg[col[i]],1);
}

__global__ void k_dinv(const int* __restrict__ deg, float* __restrict__ dinv, int n){
  int i=blockIdx.x*blockDim.x+threadIdx.x;
  if(i<n) dinv[i]=rsqrtf((float)(deg[i]+1)); // +1 self-loop
}

// --- multi-block exclusive scan ---
__global__ __launch_bounds__(256) void k_scan_part(const int* __restrict__ deg, int* __restrict__ part, int n){
  __shared__ int s[256];
  int b=blockIdx.x;
  int chunk=(n+SCB-1)/SCB;
  int lo=b*chunk, hi=min(lo+chunk,n);
  int acc=0;
  for(int i=lo+threadIdx.x;i<hi;i+=256) acc+=deg[i];
  s[threadIdx.x]=acc; __syncthreads();
  for(int off=128;off;off>>=1){
    if(threadIdx.x<off) s[threadIdx.x]+=s[threadIdx.x+off];
    __syncthreads();
  }
  if(threadIdx.x==0) part[b]=s[0];
}

__global__ __launch_bounds__(256) void k_scan_mid(int* __restrict__ part){
  __shared__ int s[256];
  int t=threadIdx.x;
  s[t]=part[t]; __syncthreads();
  for(int off=1;off<256;off<<=1){
    int v=(t>=off)? s[t-off]:0;
    __syncthreads();
    s[t]+=v;
    __syncthreads();
  }
  part[t]=(t>0)? s[t-1]:0;  // exclusive
}

// also fills gcur[b*32] = rp[b*RNG] (bucket cursors) on the fly
__global__ __launch_bounds__(256) void k_scan_out(const int* __restrict__ deg, const int* __restrict__ part,
                                                  int* __restrict__ rp, int* __restrict__ gcur, int n){
  __shared__ int s[256];
  int b=blockIdx.x, t=threadIdx.x;
  int chunk=(n+SCB-1)/SCB;
  int lo=b*chunk, hi=min(lo+chunk,n);
  int tchunk=(chunk+255)/256;
  int tlo=lo+t*tchunk, thi=min(tlo+tchunk,hi);
  int acc=0;
  for(int i=tlo;i<thi;i++) acc+=deg[i];
  s[t]=acc; __syncthreads();
  for(int off=1;off<256;off<<=1){
    int v=(t>=off)? s[t-off]:0;
    __syncthreads();
    s[t]+=v;
    __syncthreads();
  }
  int pre=part[b]+((t>0)? s[t-1]:0);
  for(int i=tlo;i<thi;i++){
    rp[i]=pre;
    if((i&(RNG-1))==0) gcur[(i>>7)*32]=pre;
    pre+=deg[i];
  }
  if(b==SCB-1 && t==0) rp[n]=part[b]+s[255];
}

// ======================= bucketed CSR fill =======================
// phase 1: scatter edges into bucket-ordered tmp, packed (r<<7)|(c&127)
__global__ __launch_bounds__(256) void k_binscat(const int* __restrict__ row, const int* __restrict__ col,
                       int* __restrict__ gcur, unsigned* __restrict__ tmp, int E, int nbuck){
  __shared__ int lcnt[NBUCKMAX];
  __shared__ int lcur[NBUCKMAX];
  int t=threadIdx.x;
  for(int i=t;i<nbuck;i+=256) lcnt[i]=0;
  __syncthreads();
  int lo=blockIdx.x*CH1, hi=min(lo+CH1,E);
  for(int i=lo+t;i<hi;i+=256) atomicAdd(&lcnt[col[i]>>7],1);
  __syncthreads();
  for(int i=t;i<nbuck;i+=256){
    int cnt=lcnt[i];
    lcur[i]=(cnt>0)? atomicAdd(&gcur[i*32],cnt):0;
  }
  __syncthreads();
  for(int i=lo+t;i<hi;i+=256){
    int c=col[i], r=row[i];
    int pos=atomicAdd(&lcur[c>>7],1);
    tmp[pos]=((unsigned)r<<7)|(unsigned)(c&127);
  }
}

// phase 2: one block per bucket; LDS fill counters; write (src, norm) into node slots
__global__ __launch_bounds__(256) void k_place(const unsigned* __restrict__ tmp, const int* __restrict__ rp,
                      const float* __restrict__ dinv, int2* __restrict__ epack, int n, int nbuck){
  __shared__ int lfill[RNG];
  __shared__ int lrp[RNG];
  __shared__ float ldv[RNG];
  int b=blockIdx.x, t=threadIdx.x;
  int nbase=b*RNG;
  int nn=min(RNG,n-nbase);
  if(t<nn){ lfill[t]=0; lrp[t]=rp[nbase+t]; ldv[t]=dinv[nbase+t]; }
  __syncthreads();
  int lo=rp[nbase], hi=rp[min(nbase+RNG,n)];
  for(int j=lo+t;j<hi;j+=256){
    unsigned v=tmp[j];
    int cl=v&127;
    int r=(int)(v>>7);
    int pos=atomicAdd(&lfill[cl],1);
    epack[lrp[cl]+pos]=make_int2(r,__float_as_int(dinv[r]*ldv[cl]));
  }
}

// ======================= MFMA B-fragment prep =======================
// mfma_f32_16x16x32_bf16 fragments:
//   A: lane l holds row (l&15), k = s*32 + (l>>4)*8 + r   (r=0..7)
//   B: lane l holds col (l&15), k = s*32 + (l>>4)*8 + r
//   D: lane l holds col (l&15), row = (l>>4)*4 + reg
// Plain (t-major) frags: Bf[((t*S + s)*64 + lane)*8 + r] = W[k][c], t=c/16, S=K/32.
__global__ void k_prep_plain(const float* __restrict__ W, unsigned short* __restrict__ Bf, int K, int C){
  int i=blockIdx.x*blockDim.x+threadIdx.x;
  if(i>=K*C) return;
  int k=i/C, c=i%C;
  int t=c>>4, s=k>>5, lane=(c&15)|(((k>>3)&3)<<4), r=k&7;
  int S=K>>5;
  Bf[(((t*S)+s)*64+lane)*8+r]=f2bf(W[(size_t)k*C+c]);
}

// Assembled GRU weights, S-MAJOR frag order (f = s*16+t) so each 32KB half is contiguous.
// X=[m|h] (K=128), cols: [0,64)=r, [64,128)=z, [128,192)=in_, [192,256)=hn.
__global__ void k_prep_gru(const float* __restrict__ wih, const float* __restrict__ whh,
                           unsigned short* __restrict__ Bf){
  int i=blockIdx.x*blockDim.x+threadIdx.x;
  if(i>=128*256) return;
  int k=i>>8, c=i&255;
  float v;
  if(c<128){          // r,z
    v = (k<64) ? wih[c*64+k] : whh[c*64+(k-64)];
  } else if(c<192){   // in_
    v = (k<64) ? wih[c*64+k] : 0.f;
  } else {            // hn
    v = (k<64) ? 0.f : whh[(c-64)*64+(k-64)];
  }
  int t=c>>4, s=k>>5, lane=(c&15)|(((k>>3)&3)<<4), r=k&7;
  Bf[(((s*16)+t)*64+lane)*8+r]=f2bf(v);
}

// ======================= lin0: hb = bf16(relu(x @ W + b)) ===================
__global__ __launch_bounds__(256) void k_lin0(const float* __restrict__ x, const unsigned short* __restrict__ Bf,
                      const float* __restrict__ bias,
                      unsigned short* __restrict__ hb, int ngrp){
  int l=threadIdx.x&63;
  int g=blockIdx.x*4+(threadIdx.x>>6);
  if(g>=ngrp) return;
  int row16=l&15, koff=(l>>4)*8;
  f32x4 acc[4]={};
  const float* xr = x + (size_t)(g*16+row16)*128 + koff;
  #pragma unroll
  for(int s=0;s<4;s++){
    f32x4 a0=*(const f32x4*)(xr+s*32);
    f32x4 a1=*(const f32x4*)(xr+s*32+4);
    bf16x8 af;
    #pragma unroll
    for(int r=0;r<4;r++){ af[r]=(short)f2bf(a0[r]); af[4+r]=(short)f2bf(a1[r]); }
    #pragma unroll
    for(int t=0;t<4;t++){
      bf16x8 bf=*(const bf16x8*)(Bf+(((t*4)+s)*64+l)*8);
      acc[t]=__builtin_amdgcn_mfma_f32_16x16x32_bf16(af,bf,acc[t],0,0,0);
    }
  }
  int rbase=g*16+(l>>4)*4;
  #pragma unroll
  for(int t=0;t<4;t++){
    int c=t*16+(l&15);
    float b=bias[c];
    #pragma unroll
    for(int j=0;j<4;j++){
      int node=rbase+j;
      float v=fmaxf(acc[t][j]+b,0.f);
      hb[(size_t)node*64+c]=f2bf(v);
    }
  }
}

// ======================= aggregate: agg = Â h — quarter-wave rows, 2 chains = 8 gathers in flight =========
__global__ __launch_bounds__(256) void k_aggregate(const unsigned short* __restrict__ hb, const int* __restrict__ rp,
                        const int2* __restrict__ epack, const float* __restrict__ dinv,
                        unsigned short* __restrict__ aggb, int n){
  int node=blockIdx.x*4+(threadIdx.x>>6);
  int lane=threadIdx.x&63;
  if(node>=n) return;
  int q=lane>>4, l16=lane&15;
  const uint2* hb64=(const uint2*)hb;   // one uint2 = 4 bf16 features
  float a0=0.f,a1=0.f,a2=0.f,a3=0.f, b0=0.f,b1=0.f,b2=0.f,b3=0.f;
  int s=rp[node], e=rp[node+1];
  int j=s+q;
  for(; j+4<e; j+=8){
    int2 e0=epack[j];
    int2 e1=epack[j+4];
    uint2 p0=hb64[((unsigned)e0.x<<4)+l16];
    uint2 p1=hb64[((unsigned)e1.x<<4)+l16];
    float n0=__int_as_float(e0.y), n1=__int_as_float(e1.y);
    a0+=n0*bf2f((unsigned short)p0.x);
    a1+=n0*bf2f((unsigned short)(p0.x>>16));
    a2+=n0*bf2f((unsigned short)p0.y);
    a3+=n0*bf2f((unsigned short)(p0.y>>16));
    b0+=n1*bf2f((unsigned short)p1.x);
    b1+=n1*bf2f((unsigned short)(p1.x>>16));
    b2+=n1*bf2f((unsigned short)p1.y);
    b3+=n1*bf2f((unsigned short)(p1.y>>16));
  }
  for(; j<e; j+=4){
    int2 e0=epack[j];
    uint2 p0=hb64[((unsigned)e0.x<<4)+l16];
    float n0=__int_as_float(e0.y);
    a0+=n0*bf2f((unsigned short)p0.x);
    a1+=n0*bf2f((unsigned short)(p0.x>>16));
    a2+=n0*bf2f((unsigned short)p0.y);
    a3+=n0*bf2f((unsigned short)(p0.y>>16));
  }
  a0+=b0; a1+=b1; a2+=b2; a3+=b3;
  if(q==0){ // self-loop term once
    float dv=dinv[node]; dv*=dv;
    uint2 ps=hb64[((unsigned)node<<4)+l16];
    a0+=dv*bf2f((unsigned short)ps.x);
    a1+=dv*bf2f((unsigned short)(ps.x>>16));
    a2+=dv*bf2f((unsigned short)ps.y);
    a3+=dv*bf2f((unsigned short)(ps.y>>16));
  }
  a0+=__shfl_xor(a0,16); a0+=__shfl_xor(a0,32);
  a1+=__shfl_xor(a1,16); a1+=__shfl_xor(a1,32);
  a2+=__shfl_xor(a2,16); a2+=__shfl_xor(a2,32);
  a3+=__shfl_xor(a3,16); a3+=__shfl_xor(a3,32);
  if(q==0){
    uint2 outp;
    outp.x=(unsigned)f2bf(a0)|(((unsigned)f2bf(a1))<<16);
    outp.y=(unsigned)f2bf(a2)|(((unsigned)f2bf(a3))<<16);
    ((uint2*)aggb)[((unsigned)node<<4)+l16]=outp;
  }
}

// ======================= fused conv+GRU, LDS-staged weights ===================
// hold comes from hb (bf16); f32 feat written only on the last iteration.
__global__ __launch_bounds__(256) void k_gru(const unsigned short* __restrict__ aggb, unsigned short* hb,
                     const unsigned short* __restrict__ Bcnv, const float* __restrict__ cb,
                     const unsigned short* __restrict__ Bgru,
                     const float* __restrict__ bih, const float* __restrict__ bhh,
                     float* h, int last, int ngrp, int n){
  __shared__ __align__(16) unsigned short Bs[16384];      // 32 KB half of Bgru
  __shared__ __align__(16) unsigned short Bc[4096];       // 8 KB conv frags
  __shared__ __align__(16) unsigned short mt[4][16][72];  // per-wave m tiles (padded)
  int tid=threadIdx.x;
  int l=tid&63, w=tid>>6;
  int g=blockIdx.x*4+w;
  bool act = g<ngrp;
  int gc = act? g : (ngrp-1);
  int row16=l&15, koff=(l>>4)*8;
  int node_r=gc*16+row16;
  int rbase=gc*16+(l>>4)*4;

  const unsigned short* ar = aggb + (size_t)node_r*64 + koff;
  const unsigned short* hr = hb   + (size_t)node_r*64 + koff;
  bf16x8 a_agg0=*(const bf16x8*)(ar);
  bf16x8 a_agg1=*(const bf16x8*)(ar+32);
  bf16x8 a_h0=*(const bf16x8*)(hr);
  bf16x8 a_h1=*(const bf16x8*)(hr+32);
  float hold[16];
  #pragma unroll
  for(int t=0;t<4;t++)
    #pragma unroll
    for(int j=0;j<4;j++)
      hold[t*4+j]=bf2f(hb[(size_t)(rbase+j)*64 + t*16+(l&15)]);

  {
    const f32x4* gs=(const f32x4*)Bcnv; f32x4* ls=(f32x4*)Bc;
    #pragma unroll
    for(int i=0;i<2;i++) ls[i*256+tid]=gs[i*256+tid];
    const f32x4* gh=(const f32x4*)Bgru; f32x4* lh=(f32x4*)Bs;
    #pragma unroll
    for(int i=0;i<8;i++) lh[i*256+tid]=gh[i*256+tid];
  }
  __syncthreads();

  f32x4 accm[4]={};
  #pragma unroll
  for(int s=0;s<2;s++){
    bf16x8 af=(s==0)? a_agg0:a_agg1;
    #pragma unroll
    for(int t=0;t<4;t++){
      bf16x8 bf=*(const bf16x8*)(Bc+((t*2+s)*64+l)*8);
      accm[t]=__builtin_amdgcn_mfma_f32_16x16x32_bf16(af,bf,accm[t],0,0,0);
    }
  }
  #pragma unroll
  for(int t=0;t<4;t++){
    int c=t*16+(l&15);
    float b=cb[c];
    #pragma unroll
    for(int j=0;j<4;j++)
      mt[w][(l>>4)*4+j][c]=f2bf(fmaxf(accm[t][j]+b,0.f));
  }

  f32x4 acc[16]={};
  #pragma unroll
  for(int s=0;s<2;s++){
    bf16x8 af=*(const bf16x8*)&mt[w][row16][koff+s*32];
    #pragma unroll
    for(int t=0;t<16;t++){
      bf16x8 bf=*(const bf16x8*)(Bs+((s*16+t)*64+l)*8);
      acc[t]=__builtin_amdgcn_mfma_f32_16x16x32_bf16(af,bf,acc[t],0,0,0);
    }
  }
  __syncthreads();
  {
    const f32x4* gh=(const f32x4*)(Bgru+16384); f32x4* lh=(f32x4*)Bs;
    #pragma unroll
    for(int i=0;i<8;i++) lh[i*256+tid]=gh[i*256+tid];
  }
  __syncthreads();

  #pragma unroll
  for(int s=0;s<2;s++){
    bf16x8 af=(s==0)? a_h0:a_h1;
    #pragma unroll
    for(int t=0;t<16;t++){
      bf16x8 bf=*(const bf16x8*)(Bs+((s*16+t)*64+l)*8);
      acc[t]=__builtin_amdgcn_mfma_f32_16x16x32_bf16(af,bf,acc[t],0,0,0);
    }
  }

  if(!act) return;
  #pragma unroll
  for(int t=0;t<4;t++){
    int d=t*16+(l&15);
    float br =bih[d]    +bhh[d];
    float bz =bih[64+d] +bhh[64+d];
    float bni=bih[128+d];
    float bnh=bhh[128+d];
    #pragma unroll
    for(int j=0;j<4;j++){
      int node=rbase+j;
      if(node<n){
        float r  = sigmoidf_(acc[t][j]   + br);
        float z  = sigmoidf_(acc[4+t][j] + bz);
        float nc = tanhf_(acc[8+t][j] + bni + r*(acc[12+t][j] + bnh));
        float hn = (1.f-z)*nc + z*hold[t*4+j];
        if(last) h[(size_t)node*64+d]=hn;
        hb[(size_t)node*64+d]=f2bf(hn);
      }
    }
  }
}

// ======================= Set2Set: parallel attention partials =======================
__global__ __launch_bounds__(256) void k_attn_part(const unsigned short* __restrict__ hb, const int* __restrict__ batch,
                        const float* __restrict__ hl, float* __restrict__ apart, int n){
  int b=blockIdx.x/KB, kb=blockIdx.x%KB;
  int tid=threadIdx.x, lane=tid&63, w=tid>>6;
  __shared__ float qs[64];
  __shared__ float wm[4], wsm[4];
  __shared__ float wacc[4][64];
  if(tid<64) qs[tid]=hl[b*64+tid];
  int lo=lower_bound_i(batch,n,b), hi=lower_bound_i(batch,n,b+1);
  int cnt=hi-lo;
  int chunk=(cnt+KB-1)/KB;
  int slo=lo+kb*chunk, shi=min(slo+chunk,hi);
  __syncthreads();
  float q=qs[lane];
  float mw=-3.0e38f, sw=0.f, aw=0.f;
  for(int i=slo+w;i<shi;i+=4){
    float f=bf2f(hb[(size_t)i*64+lane]);
    float v=f*q;
    #pragma unroll
    for(int off=32;off;off>>=1) v+=__shfl_xor(v,off);
    if(v>mw){
      float sc=__expf(mw-v);
      sw=sw*sc+1.f;
      aw=aw*sc+f;
      mw=v;
    } else {
      float p=__expf(v-mw);
      sw+=p;
      aw+=p*f;
    }
  }
  if(lane==0){ wm[w]=mw; wsm[w]=sw; }
  wacc[w][lane]=aw;
  __syncthreads();
  if(w==0){
    float M=fmaxf(fmaxf(wm[0],wm[1]),fmaxf(wm[2],wm[3]));
    float S=0.f, A=0.f;
    #pragma unroll
    for(int k=0;k<4;k++){
      float sc=__expf(wm[k]-M);
      S+=wsm[k]*sc;
      A+=wacc[k][lane]*sc;
    }
    float* p=apart+(size_t)blockIdx.x*68;
    p[lane]=A;
    if(lane==0){ p[64]=M; p[65]=S; }
  }
}

// merge partials -> r_read (qstar[64:128]); optionally run next LSTM cell
__global__ __launch_bounds__(256) void k_merge_lstm(const float* __restrict__ apart,
                   float* __restrict__ qstar, float* __restrict__ hl, float* __restrict__ cl,
                   const float* __restrict__ wih, const float* __restrict__ whh,
                   const float* __restrict__ bih, const float* __restrict__ bhh,
                   int do_merge, int do_lstm){
  int b=blockIdx.x, tid=threadIdx.x;
  __shared__ float qs[128];
  __shared__ float gates[256];
  if(do_merge){
    if(tid<64){
      const float* p0=apart+(size_t)b*KB*68;
      float M=-3.0e38f;
      #pragma unroll
      for(int k=0;k<KB;k++) M=fmaxf(M,p0[k*68+64]);
      float S=0.f, A=0.f;
      #pragma unroll
      for(int k=0;k<KB;k++){
        float sc=__expf(p0[k*68+64]-M);
        S+=p0[k*68+65]*sc;
        A+=p0[k*68+tid]*sc;
      }
      float inv=(S>0.f)? 1.f/S:0.f;
      float r=A*inv;
      qs[64+tid]=r;
      qstar[b*128+64+tid]=r;
    }
  } else {
    if(tid<64) qs[64+tid]=qstar[b*128+64+tid];
  }
  if(tid<64) qs[tid]=hl[b*64+tid];   // q_t == previous LSTM hidden
  __syncthreads();
  if(!do_lstm) return;
  float acc=bih[tid]+bhh[tid];
  const float* wi=wih+(size_t)tid*128;
  #pragma unroll 8
  for(int k=0;k<128;k++) acc+=qs[k]*wi[k];
  const float* w2=whh+(size_t)tid*64;
  #pragma unroll 8
  for(int k=0;k<64;k++) acc+=qs[k]*w2[k];
  gates[tid]=acc;
  __syncthreads();
  if(tid<64){
    float i_=gates[tid], f_=gates[64+tid], g_=gates[128+tid], o_=gates[192+tid];
    float c=sigmoidf_(f_)*cl[b*64+tid]+sigmoidf_(i_)*tanhf(g_);
    float hn=sigmoidf_(o_)*tanhf(c);
    cl[b*64+tid]=c; hl[b*64+tid]=hn;
    qstar[b*128+tid]=hn;
  }
}

extern "C" void kernel_launch(void* const* d_in, const int* in_sizes, int n_in,
                              void* d_out, int out_size, void* d_ws, size_t ws_size,
                              hipStream_t stream){
  const float* x      =(const float*)d_in[0];
  const int*   ei     =(const int*)d_in[1];
  const int*   batch  =(const int*)d_in[2];
  const float* lin0_w =(const float*)d_in[3];
  const float* lin0_b =(const float*)d_in[4];
  const float* conv_w =(const float*)d_in[5];
  const float* conv_b =(const float*)d_in[6];
  const float* gwih   =(const float*)d_in[7];
  const float* gwhh   =(const float*)d_in[8];
  const float* gbih   =(const float*)d_in[9];
  const float* gbhh   =(const float*)d_in[10];
  const float* lwih   =(const float*)d_in[11];
  const float* lwhh   =(const float*)d_in[12];
  const float* lbih   =(const float*)d_in[13];
  const float* lbhh   =(const float*)d_in[14];

  int N = in_sizes[0]/FEATD;
  int E = in_sizes[1]/2;
  const int* row = ei;
  const int* col = ei + E;

  float* qstar = (float*)d_out;            // [256,128]
  float* h     = (float*)d_out + NB*2*DIM; // [N,64] 'feat' = f32 h (written by last k_gru)

  char* ws=(char*)d_ws;
  size_t off=0;
  auto alloc=[&](size_t bytes)->void*{ void* p=ws+off; off=(off+bytes+255)&~(size_t)255; return p; };
  int*   deg  =(int*)  alloc((size_t)N*4);
  float* dinv =(float*)alloc((size_t)N*4);
  int*   rp   =(int*)  alloc((size_t)(N+1)*4);
  int*   part =(int*)  alloc((size_t)SCB*4);
  int*   gcur =(int*)  alloc((size_t)NBUCKMAX*32*4);
  unsigned* tmp=(unsigned*)alloc((size_t)E*4);
  int2*  epack=(int2*) alloc((size_t)E*8);
  unsigned short* hb   =(unsigned short*)alloc((size_t)N*64*2);
  unsigned short* aggb =(unsigned short*)alloc((size_t)N*64*2);
  float* hl   =(float*)alloc((size_t)NB*DIM*4);
  float* cl   =(float*)alloc((size_t)NB*DIM*4);
  float* apart=(float*)alloc((size_t)NB*KB*68*4);
  unsigned short* Bgru =(unsigned short*)alloc(128*256*2);
  unsigned short* Blin =(unsigned short*)alloc(128*64*2);
  unsigned short* Bcnv =(unsigned short*)alloc(64*64*2);

  hipMemsetAsync(deg ,0,(size_t)N*4,stream);
  hipMemsetAsync(hl  ,0,(size_t)NB*DIM*4,stream);
  hipMemsetAsync(cl  ,0,(size_t)NB*DIM*4,stream);
  hipMemsetAsync(qstar,0,(size_t)NB*2*DIM*4,stream);

  int nbuck=(N+RNG-1)/RNG;

  k_count<<<(E+255)/256,256,0,stream>>>(col,deg,E);
  k_dinv <<<(N+255)/256,256,0,stream>>>(deg,dinv,N);
  k_scan_part<<<SCB,256,0,stream>>>(deg,part,N);
  k_scan_mid <<<1,256,0,stream>>>(part);
  k_scan_out <<<SCB,256,0,stream>>>(deg,part,rp,gcur,N);
  k_binscat<<<(E+CH1-1)/CH1,256,0,stream>>>(row,col,gcur,tmp,E,nbuck);
  k_place<<<nbuck,256,0,stream>>>(tmp,rp,dinv,epack,N,nbuck);

  k_prep_plain<<<(128*64+255)/256,256,0,stream>>>(lin0_w,Blin,128,64);
  k_prep_plain<<<(64*64+255)/256,256,0,stream>>>(conv_w,Bcnv,64,64);
  k_prep_gru  <<<(128*256+255)/256,256,0,stream>>>(gwih,gwhh,Bgru);

  int ngrp=(N+15)/16;
  int gb=(ngrp+3)/4;

  k_lin0<<<gb,256,0,stream>>>(x,Blin,lin0_b,hb,ngrp);

  for(int it=0;it<3;it++){
    k_aggregate<<<(N+3)/4,256,0,stream>>>(hb,rp,epack,dinv,aggb,N);
    k_gru      <<<gb,256,0,stream>>>(aggb,hb,Bcnv,conv_b,Bgru,gbih,gbhh,h,(it==2)?1:0,ngrp,N);
  }

  // Set2Set: lstm0; [attn, merge+lstm] x2; attn; merge(final)
  k_merge_lstm<<<NB,256,0,stream>>>(apart,qstar,hl,cl,lwih,lwhh,lbih,lbhh,0,1);
  for(int st=0;st<3;st++){
    k_attn_part<<<NB*KB,256,0,stream>>>(hb,batch,hl,apart,N);
    int do_lstm = (st<2)? 1:0;
    k_merge_lstm<<<NB,256,0,stream>>>(apart,qstar,hl,cl,lwih,lwhh,lbih,lbhh,1,do_lstm);
  }
}

// Round 9
// 648.731 us; speedup vs baseline: 5.2284x; 1.0152x over previous
//
#include <hip/hip_runtime.h>
#include <math.h>

#define FEATD 128
#define DIM 64
#define NB 256
#define SCB 256
#define KB 16      // attention partial blocks per graph
#define RNG 128    // nodes per CSR-fill bucket
#define NBUCKMAX 2048
#define CH1 8192   // edges per block, bin-scatter phase

typedef short bf16x8 __attribute__((ext_vector_type(8)));
typedef float f32x4 __attribute__((ext_vector_type(4)));

__device__ __forceinline__ float frcp_(float x){ return __builtin_amdgcn_rcpf(x); }
__device__ __forceinline__ float sigmoidf_(float x){ return frcp_(1.f+__expf(-x)); }
__device__ __forceinline__ float tanhf_(float x){ float e=__expf(2.f*x); return 1.f-2.f*frcp_(e+1.f); }

__device__ __forceinline__ unsigned short f2bf(float f){
  unsigned u = __float_as_uint(f);
  unsigned r = (u + 0x7FFFu + ((u>>16)&1u)) >> 16;
  return (unsigned short)r;
}
__device__ __forceinline__ float bf2f(unsigned short s){
  return __uint_as_float(((unsigned)s)<<16);
}

__device__ __forceinline__ int lower_bound_i(const int* __restrict__ a, int n, int key){
  int lo=0, hi=n;
  while(lo<hi){ int mid=(lo+hi)>>1; if(a[mid]<key) lo=mid+1; else hi=mid; }
  return lo;
}

// ======================= CSR setup =======================
__global__ void k_count(const int* __restrict__ col, int* __restrict__ deg, int E){
  int i=blockIdx.x*blockDim.x+threadIdx.x;
  if(i<E) atomicAdd(&deg[col[i]],1);
}

__global__ void k_dinv(const int* __restrict__ deg, float* __restrict__ dinv, int n){
  int i=blockIdx.x*blockDim.x+threadIdx.x;
  if(i<n) dinv[i]=rsqrtf((float)(deg[i]+1)); // +1 self-loop
}

// --- multi-block exclusive scan ---
__global__ __launch_bounds__(256) void k_scan_part(const int* __restrict__ deg, int* __restrict__ part, int n){
  __shared__ int s[256];
  int b=blockIdx.x;
  int chunk=(n+SCB-1)/SCB;
  int lo=b*chunk, hi=min(lo+chunk,n);
  int acc=0;
  for(int i=lo+threadIdx.x;i<hi;i+=256) acc+=deg[i];
  s[threadIdx.x]=acc; __syncthreads();
  for(int off=128;off;off>>=1){
    if(threadIdx.x<off) s[threadIdx.x]+=s[threadIdx.x+off];
    __syncthreads();
  }
  if(threadIdx.x==0) part[b]=s[0];
}

__global__ __launch_bounds__(256) void k_scan_mid(int* __restrict__ part){
  __shared__ int s[256];
  int t=threadIdx.x;
  s[t]=part[t]; __syncthreads();
  for(int off=1;off<256;off<<=1){
    int v=(t>=off)? s[t-off]:0;
    __syncthreads();
    s[t]+=v;
    __syncthreads();
  }
  part[t]=(t>0)? s[t-1]:0;  // exclusive
}

// also fills gcur[b*32] = rp[b*RNG] (bucket cursors) on the fly
__global__ __launch_bounds__(256) void k_scan_out(const int* __restrict__ deg, const int* __restrict__ part,
                                                  int* __restrict__ rp, int* __restrict__ gcur, int n){
  __shared__ int s[256];
  int b=blockIdx.x, t=threadIdx.x;
  int chunk=(n+SCB-1)/SCB;
  int lo=b*chunk, hi=min(lo+chunk,n);
  int tchunk=(chunk+255)/256;
  int tlo=lo+t*tchunk, thi=min(tlo+tchunk,hi);
  int acc=0;
  for(int i=tlo;i<thi;i++) acc+=deg[i];
  s[t]=acc; __syncthreads();
  for(int off=1;off<256;off<<=1){
    int v=(t>=off)? s[t-off]:0;
    __syncthreads();
    s[t]+=v;
    __syncthreads();
  }
  int pre=part[b]+((t>0)? s[t-1]:0);
  for(int i=tlo;i<thi;i++){
    rp[i]=pre;
    if((i&(RNG-1))==0) gcur[(i>>7)*32]=pre;
    pre+=deg[i];
  }
  if(b==SCB-1 && t==0) rp[n]=part[b]+s[255];
}

// ======================= bucketed CSR fill =======================
__global__ __launch_bounds__(256) void k_binscat(const int* __restrict__ row, const int* __restrict__ col,
                       int* __restrict__ gcur, unsigned* __restrict__ tmp, int E, int nbuck){
  __shared__ int lcnt[NBUCKMAX];
  __shared__ int lcur[NBUCKMAX];
  int t=threadIdx.x;
  for(int i=t;i<nbuck;i+=256) lcnt[i]=0;
  __syncthreads();
  int lo=blockIdx.x*CH1, hi=min(lo+CH1,E);
  for(int i=lo+t;i<hi;i+=256) atomicAdd(&lcnt[col[i]>>7],1);
  __syncthreads();
  for(int i=t;i<nbuck;i+=256){
    int cnt=lcnt[i];
    lcur[i]=(cnt>0)? atomicAdd(&gcur[i*32],cnt):0;
  }
  __syncthreads();
  for(int i=lo+t;i<hi;i+=256){
    int c=col[i], r=row[i];
    int pos=atomicAdd(&lcur[c>>7],1);
    tmp[pos]=((unsigned)r<<7)|(unsigned)(c&127);
  }
}

__global__ __launch_bounds__(256) void k_place(const unsigned* __restrict__ tmp, const int* __restrict__ rp,
                      const float* __restrict__ dinv, int2* __restrict__ epack, int n, int nbuck){
  __shared__ int lfill[RNG];
  __shared__ int lrp[RNG];
  __shared__ float ldv[RNG];
  int b=blockIdx.x, t=threadIdx.x;
  int nbase=b*RNG;
  int nn=min(RNG,n-nbase);
  if(t<nn){ lfill[t]=0; lrp[t]=rp[nbase+t]; ldv[t]=dinv[nbase+t]; }
  __syncthreads();
  int lo=rp[nbase], hi=rp[min(nbase+RNG,n)];
  for(int j=lo+t;j<hi;j+=256){
    unsigned v=tmp[j];
    int cl=v&127;
    int r=(int)(v>>7);
    int pos=atomicAdd(&lfill[cl],1);
    epack[lrp[cl]+pos]=make_int2(r,__float_as_int(dinv[r]*ldv[cl]));
  }
}

// ======================= MFMA B-fragment prep =======================
// mfma_f32_16x16x32_bf16 fragments:
//   A: lane l holds row (l&15), k = s*32 + (l>>4)*8 + r   (r=0..7)
//   B: lane l holds col (l&15), k = s*32 + (l>>4)*8 + r
//   D: lane l holds col (l&15), row = (l>>4)*4 + reg
// Plain (t-major) frags: Bf[((t*S + s)*64 + lane)*8 + r] = W[k][c], t=c/16, S=K/32.
__global__ void k_prep_plain(const float* __restrict__ W, unsigned short* __restrict__ Bf, int K, int C){
  int i=blockIdx.x*blockDim.x+threadIdx.x;
  if(i>=K*C) return;
  int k=i/C, c=i%C;
  int t=c>>4, s=k>>5, lane=(c&15)|(((k>>3)&3)<<4), r=k&7;
  int S=K>>5;
  Bf[(((t*S)+s)*64+lane)*8+r]=f2bf(W[(size_t)k*C+c]);
}

// Assembled GRU weights, S-MAJOR frag order (f = s*16+t) so each 16KB quarter (one s) is contiguous.
// X=[m|h] (K=128), cols: [0,64)=r, [64,128)=z, [128,192)=in_, [192,256)=hn.
__global__ void k_prep_gru(const float* __restrict__ wih, const float* __restrict__ whh,
                           unsigned short* __restrict__ Bf){
  int i=blockIdx.x*blockDim.x+threadIdx.x;
  if(i>=128*256) return;
  int k=i>>8, c=i&255;
  float v;
  if(c<128){          // r,z
    v = (k<64) ? wih[c*64+k] : whh[c*64+(k-64)];
  } else if(c<192){   // in_
    v = (k<64) ? wih[c*64+k] : 0.f;
  } else {            // hn
    v = (k<64) ? 0.f : whh[(c-64)*64+(k-64)];
  }
  int t=c>>4, s=k>>5, lane=(c&15)|(((k>>3)&3)<<4), r=k&7;
  Bf[(((s*16)+t)*64+lane)*8+r]=f2bf(v);
}

// ======================= lin0: hb = bf16(relu(x @ W + b)) ===================
__global__ __launch_bounds__(256) void k_lin0(const float* __restrict__ x, const unsigned short* __restrict__ Bf,
                      const float* __restrict__ bias,
                      unsigned short* __restrict__ hb, int ngrp){
  int l=threadIdx.x&63;
  int g=blockIdx.x*4+(threadIdx.x>>6);
  if(g>=ngrp) return;
  int row16=l&15, koff=(l>>4)*8;
  f32x4 acc[4]={};
  const float* xr = x + (size_t)(g*16+row16)*128 + koff;
  #pragma unroll
  for(int s=0;s<4;s++){
    f32x4 a0=*(const f32x4*)(xr+s*32);
    f32x4 a1=*(const f32x4*)(xr+s*32+4);
    bf16x8 af;
    #pragma unroll
    for(int r=0;r<4;r++){ af[r]=(short)f2bf(a0[r]); af[4+r]=(short)f2bf(a1[r]); }
    #pragma unroll
    for(int t=0;t<4;t++){
      bf16x8 bf=*(const bf16x8*)(Bf+(((t*4)+s)*64+l)*8);
      acc[t]=__builtin_amdgcn_mfma_f32_16x16x32_bf16(af,bf,acc[t],0,0,0);
    }
  }
  int rbase=g*16+(l>>4)*4;
  #pragma unroll
  for(int t=0;t<4;t++){
    int c=t*16+(l&15);
    float b=bias[c];
    #pragma unroll
    for(int j=0;j<4;j++){
      int node=rbase+j;
      float v=fmaxf(acc[t][j]+b,0.f);
      hb[(size_t)node*64+c]=f2bf(v);
    }
  }
}

// ======================= fused aggregate + conv + GRU ===================
// Per wave: 16 nodes. Gather agg = Â h_in (4 rounds, quarter-wave per node, 4 chains),
// stage agg + self h row in per-wave LDS tiles, then m = relu(agg@Wc+cb) and
// h_out = GRU(m, h) with Bgru staged in 16KB LDS quarters (4 blocks/CU).
__global__ __launch_bounds__(256) void k_gruagg(
                     const unsigned short* __restrict__ hin, unsigned short* __restrict__ hout,
                     const int* __restrict__ rp, const int2* __restrict__ epack,
                     const float* __restrict__ dinv,
                     const unsigned short* __restrict__ Bcnv, const float* __restrict__ cb,
                     const unsigned short* __restrict__ Bgru,
                     const float* __restrict__ bih, const float* __restrict__ bhh,
                     float* __restrict__ h, int last, int ngrp, int n){
  __shared__ __align__(16) unsigned short Bs[8192];        // 16 KB: one s-quarter of Bgru
  __shared__ __align__(16) unsigned short tA[4][16][72];   // per-wave agg tile -> later m tile
  __shared__ __align__(16) unsigned short tH[4][16][72];   // per-wave h tile
  int tid=threadIdx.x;
  int l=tid&63, w=tid>>6;
  int g=blockIdx.x*4+w;
  bool act = g<ngrp;
  int gc = act? g : (ngrp-1);
  int q=l>>4, l16=l&15;
  int row16=l&15, koff=(l>>4)*8;
  int rbase=gc*16+(l>>4)*4;

  // conv B-frags into registers (issued early, resolve under gather)
  bf16x8 bc[8];
  #pragma unroll
  for(int f=0;f<8;f++) bc[f]=*(const bf16x8*)(Bcnv+((size_t)f*64+l)*8);

  // stage Bgru quarter s=0
  {
    const f32x4* gh=(const f32x4*)Bgru; f32x4* lh=(f32x4*)Bs;
    #pragma unroll
    for(int i=0;i<4;i++) lh[i*256+tid]=gh[i*256+tid];
  }

  // ---- gather: 4 rounds; quarter q owns node gc*16+rr*4+q; 4 chains ----
  const uint2* h64=(const uint2*)hin;
  #pragma unroll
  for(int rr=0;rr<4;rr++){
    int node=min(gc*16+rr*4+q, n-1);
    float a0=0.f,a1=0.f,a2=0.f,a3=0.f, b0=0.f,b1=0.f,b2=0.f,b3=0.f;
    int s=rp[node], e=rp[node+1];
    uint2 selfp=h64[((unsigned)node<<4)+l16];
    int j=s;
    for(; j+3<e; j+=4){
      int2 e0=epack[j];
      int2 e1=epack[j+1];
      int2 e2=epack[j+2];
      int2 e3=epack[j+3];
      uint2 p0=h64[((unsigned)e0.x<<4)+l16];
      uint2 p1=h64[((unsigned)e1.x<<4)+l16];
      uint2 p2=h64[((unsigned)e2.x<<4)+l16];
      uint2 p3=h64[((unsigned)e3.x<<4)+l16];
      float n0=__int_as_float(e0.y), n1=__int_as_float(e1.y);
      float n2=__int_as_float(e2.y), n3=__int_as_float(e3.y);
      a0+=n0*bf2f((unsigned short)p0.x); a1+=n0*bf2f((unsigned short)(p0.x>>16));
      a2+=n0*bf2f((unsigned short)p0.y); a3+=n0*bf2f((unsigned short)(p0.y>>16));
      b0+=n1*bf2f((unsigned short)p1.x); b1+=n1*bf2f((unsigned short)(p1.x>>16));
      b2+=n1*bf2f((unsigned short)p1.y); b3+=n1*bf2f((unsigned short)(p1.y>>16));
      a0+=n2*bf2f((unsigned short)p2.x); a1+=n2*bf2f((unsigned short)(p2.x>>16));
      a2+=n2*bf2f((unsigned short)p2.y); a3+=n2*bf2f((unsigned short)(p2.y>>16));
      b0+=n3*bf2f((unsigned short)p3.x); b1+=n3*bf2f((unsigned short)(p3.x>>16));
      b2+=n3*bf2f((unsigned short)p3.y); b3+=n3*bf2f((unsigned short)(p3.y>>16));
    }
    for(; j<e; j++){
      int2 e0=epack[j];
      uint2 p0=h64[((unsigned)e0.x<<4)+l16];
      float n0=__int_as_float(e0.y);
      a0+=n0*bf2f((unsigned short)p0.x); a1+=n0*bf2f((unsigned short)(p0.x>>16));
      a2+=n0*bf2f((unsigned short)p0.y); a3+=n0*bf2f((unsigned short)(p0.y>>16));
    }
    float dv=dinv[node]; dv*=dv;
    a0+=b0+dv*bf2f((unsigned short)selfp.x);
    a1+=b1+dv*bf2f((unsigned short)(selfp.x>>16));
    a2+=b2+dv*bf2f((unsigned short)selfp.y);
    a3+=b3+dv*bf2f((unsigned short)(selfp.y>>16));
    int ri=rr*4+q;
    unsigned* tAp=(unsigned*)&tA[w][ri][l16*4];
    tAp[0]=(unsigned)f2bf(a0)|(((unsigned)f2bf(a1))<<16);
    tAp[1]=(unsigned)f2bf(a2)|(((unsigned)f2bf(a3))<<16);
    unsigned* tHp=(unsigned*)&tH[w][ri][l16*4];
    tHp[0]=selfp.x; tHp[1]=selfp.y;
  }

  // ---- conv mini-GEMM: m = relu(agg[16x64] @ Wc + cb); A-frags from tA (same wave) ----
  f32x4 accm[4]={};
  #pragma unroll
  for(int s=0;s<2;s++){
    bf16x8 af=*(const bf16x8*)&tA[w][row16][s*32+koff];
    #pragma unroll
    for(int t=0;t<4;t++)
      accm[t]=__builtin_amdgcn_mfma_f32_16x16x32_bf16(af,bc[t*2+s],accm[t],0,0,0);
  }
  // m -> tA (overwrite; write data depends on reads via MFMA chain, same-wave safe)
  #pragma unroll
  for(int t=0;t<4;t++){
    int c=t*16+(l&15);
    float b=cb[c];
    #pragma unroll
    for(int j=0;j<4;j++)
      tA[w][(l>>4)*4+j][c]=f2bf(fmaxf(accm[t][j]+b,0.f));
  }

  // ---- GRU GEMM over 4 K-slices, Bs restaged per slice ----
  f32x4 acc[16]={};
  __syncthreads();   // Bs quarter 0 visible
  #pragma unroll
  for(int s=0;s<4;s++){
    if(s>0){
      __syncthreads();  // prior quarter reads done
      const f32x4* gh=(const f32x4*)(Bgru+(size_t)s*8192); f32x4* lh=(f32x4*)Bs;
      #pragma unroll
      for(int i=0;i<4;i++) lh[i*256+tid]=gh[i*256+tid];
      __syncthreads();  // quarter s visible
    }
    bf16x8 af;
    if(s<2) af=*(const bf16x8*)&tA[w][row16][s*32+koff];
    else    af=*(const bf16x8*)&tH[w][row16][(s-2)*32+koff];
    #pragma unroll
    for(int t=0;t<16;t++){
      bf16x8 bf=*(const bf16x8*)(Bs+((size_t)t*64+l)*8);
      acc[t]=__builtin_amdgcn_mfma_f32_16x16x32_bf16(af,bf,acc[t],0,0,0);
    }
  }

  if(!act) return;
  // ---- epilogue: gates in-register; hold from tH ----
  #pragma unroll
  for(int t=0;t<4;t++){
    int d=t*16+(l&15);
    float br =bih[d]    +bhh[d];
    float bz =bih[64+d] +bhh[64+d];
    float bni=bih[128+d];
    float bnh=bhh[128+d];
    #pragma unroll
    for(int j=0;j<4;j++){
      int node=rbase+j;
      if(node<n){
        float r  = sigmoidf_(acc[t][j]   + br);
        float z  = sigmoidf_(acc[4+t][j] + bz);
        float nc = tanhf_(acc[8+t][j] + bni + r*(acc[12+t][j] + bnh));
        float hold=bf2f(tH[w][(l>>4)*4+j][d]);
        float hn = (1.f-z)*nc + z*hold;
        if(last) h[(size_t)node*64+d]=hn;
        hout[(size_t)node*64+d]=f2bf(hn);
      }
    }
  }
}

// ======================= Set2Set: parallel attention partials =======================
__global__ __launch_bounds__(256) void k_attn_part(const unsigned short* __restrict__ hb, const int* __restrict__ batch,
                        const float* __restrict__ hl, float* __restrict__ apart, int n){
  int b=blockIdx.x/KB, kb=blockIdx.x%KB;
  int tid=threadIdx.x, lane=tid&63, w=tid>>6;
  __shared__ float qs[64];
  __shared__ float wm[4], wsm[4];
  __shared__ float wacc[4][64];
  if(tid<64) qs[tid]=hl[b*64+tid];
  int lo=lower_bound_i(batch,n,b), hi=lower_bound_i(batch,n,b+1);
  int cnt=hi-lo;
  int chunk=(cnt+KB-1)/KB;
  int slo=lo+kb*chunk, shi=min(slo+chunk,hi);
  __syncthreads();
  float q=qs[lane];
  float mw=-3.0e38f, sw=0.f, aw=0.f;
  for(int i=slo+w;i<shi;i+=4){
    float f=bf2f(hb[(size_t)i*64+lane]);
    float v=f*q;
    #pragma unroll
    for(int off=32;off;off>>=1) v+=__shfl_xor(v,off);
    if(v>mw){
      float sc=__expf(mw-v);
      sw=sw*sc+1.f;
      aw=aw*sc+f;
      mw=v;
    } else {
      float p=__expf(v-mw);
      sw+=p;
      aw+=p*f;
    }
  }
  if(lane==0){ wm[w]=mw; wsm[w]=sw; }
  wacc[w][lane]=aw;
  __syncthreads();
  if(w==0){
    float M=fmaxf(fmaxf(wm[0],wm[1]),fmaxf(wm[2],wm[3]));
    float S=0.f, A=0.f;
    #pragma unroll
    for(int k=0;k<4;k++){
      float sc=__expf(wm[k]-M);
      S+=wsm[k]*sc;
      A+=wacc[k][lane]*sc;
    }
    float* p=apart+(size_t)blockIdx.x*68;
    p[lane]=A;
    if(lane==0){ p[64]=M; p[65]=S; }
  }
}

// merge partials -> r_read (qstar[64:128]); optionally run next LSTM cell
__global__ __launch_bounds__(256) void k_merge_lstm(const float* __restrict__ apart,
                   float* __restrict__ qstar, float* __restrict__ hl, float* __restrict__ cl,
                   const float* __restrict__ wih, const float* __restrict__ whh,
                   const float* __restrict__ bih, const float* __restrict__ bhh,
                   int do_merge, int do_lstm){
  int b=blockIdx.x, tid=threadIdx.x;
  __shared__ float qs[128];
  __shared__ float gates[256];
  if(do_merge){
    if(tid<64){
      const float* p0=apart+(size_t)b*KB*68;
      float M=-3.0e38f;
      #pragma unroll
      for(int k=0;k<KB;k++) M=fmaxf(M,p0[k*68+64]);
      float S=0.f, A=0.f;
      #pragma unroll
      for(int k=0;k<KB;k++){
        float sc=__expf(p0[k*68+64]-M);
        S+=p0[k*68+65]*sc;
        A+=p0[k*68+tid]*sc;
      }
      float inv=(S>0.f)? 1.f/S:0.f;
      float r=A*inv;
      qs[64+tid]=r;
      qstar[b*128+64+tid]=r;
    }
  } else {
    if(tid<64) qs[64+tid]=qstar[b*128+64+tid];
  }
  if(tid<64) qs[tid]=hl[b*64+tid];   // q_t == previous LSTM hidden
  __syncthreads();
  if(!do_lstm) return;
  float acc=bih[tid]+bhh[tid];
  const float* wi=wih+(size_t)tid*128;
  #pragma unroll 8
  for(int k=0;k<128;k++) acc+=qs[k]*wi[k];
  const float* w2=whh+(size_t)tid*64;
  #pragma unroll 8
  for(int k=0;k<64;k++) acc+=qs[k]*w2[k];
  gates[tid]=acc;
  __syncthreads();
  if(tid<64){
    float i_=gates[tid], f_=gates[64+tid], g_=gates[128+tid], o_=gates[192+tid];
    float c=sigmoidf_(f_)*cl[b*64+tid]+sigmoidf_(i_)*tanhf(g_);
    float hn=sigmoidf_(o_)*tanhf(c);
    cl[b*64+tid]=c; hl[b*64+tid]=hn;
    qstar[b*128+tid]=hn;
  }
}

extern "C" void kernel_launch(void* const* d_in, const int* in_sizes, int n_in,
                              void* d_out, int out_size, void* d_ws, size_t ws_size,
                              hipStream_t stream){
  const float* x      =(const float*)d_in[0];
  const int*   ei     =(const int*)d_in[1];
  const int*   batch  =(const int*)d_in[2];
  const float* lin0_w =(const float*)d_in[3];
  const float* lin0_b =(const float*)d_in[4];
  const float* conv_w =(const float*)d_in[5];
  const float* conv_b =(const float*)d_in[6];
  const float* gwih   =(const float*)d_in[7];
  const float* gwhh   =(const float*)d_in[8];
  const float* gbih   =(const float*)d_in[9];
  const float* gbhh   =(const float*)d_in[10];
  const float* lwih   =(const float*)d_in[11];
  const float* lwhh   =(const float*)d_in[12];
  const float* lbih   =(const float*)d_in[13];
  const float* lbhh   =(const float*)d_in[14];

  int N = in_sizes[0]/FEATD;
  int E = in_sizes[1]/2;
  const int* row = ei;
  const int* col = ei + E;

  float* qstar = (float*)d_out;            // [256,128]
  float* h     = (float*)d_out + NB*2*DIM; // [N,64] 'feat' = f32 h (written by last k_gruagg)

  char* ws=(char*)d_ws;
  size_t off=0;
  auto alloc=[&](size_t bytes)->void*{ void* p=ws+off; off=(off+bytes+255)&~(size_t)255; return p; };
  int*   deg  =(int*)  alloc((size_t)N*4);
  float* dinv =(float*)alloc((size_t)N*4);
  int*   rp   =(int*)  alloc((size_t)(N+1)*4);
  int*   part =(int*)  alloc((size_t)SCB*4);
  int*   gcur =(int*)  alloc((size_t)NBUCKMAX*32*4);
  unsigned* tmp=(unsigned*)alloc((size_t)E*4);
  int2*  epack=(int2*) alloc((size_t)E*8);
  unsigned short* hb0  =(unsigned short*)alloc((size_t)N*64*2);
  unsigned short* hb1  =(unsigned short*)alloc((size_t)N*64*2);
  float* hl   =(float*)alloc((size_t)NB*DIM*4);
  float* cl   =(float*)alloc((size_t)NB*DIM*4);
  float* apart=(float*)alloc((size_t)NB*KB*68*4);
  unsigned short* Bgru =(unsigned short*)alloc(128*256*2);
  unsigned short* Blin =(unsigned short*)alloc(128*64*2);
  unsigned short* Bcnv =(unsigned short*)alloc(64*64*2);

  hipMemsetAsync(deg ,0,(size_t)N*4,stream);
  hipMemsetAsync(hl  ,0,(size_t)NB*DIM*4,stream);
  hipMemsetAsync(cl  ,0,(size_t)NB*DIM*4,stream);
  hipMemsetAsync(qstar,0,(size_t)NB*2*DIM*4,stream);

  int nbuck=(N+RNG-1)/RNG;

  k_count<<<(E+255)/256,256,0,stream>>>(col,deg,E);
  k_dinv <<<(N+255)/256,256,0,stream>>>(deg,dinv,N);
  k_scan_part<<<SCB,256,0,stream>>>(deg,part,N);
  k_scan_mid <<<1,256,0,stream>>>(part);
  k_scan_out <<<SCB,256,0,stream>>>(deg,part,rp,gcur,N);
  k_binscat<<<(E+CH1-1)/CH1,256,0,stream>>>(row,col,gcur,tmp,E,nbuck);
  k_place<<<nbuck,256,0,stream>>>(tmp,rp,dinv,epack,N,nbuck);

  k_prep_plain<<<(128*64+255)/256,256,0,stream>>>(lin0_w,Blin,128,64);
  k_prep_plain<<<(64*64+255)/256,256,0,stream>>>(conv_w,Bcnv,64,64);
  k_prep_gru  <<<(128*256+255)/256,256,0,stream>>>(gwih,gwhh,Bgru);

  int ngrp=(N+15)/16;
  int gb=(ngrp+3)/4;

  k_lin0<<<gb,256,0,stream>>>(x,Blin,lin0_b,hb0,ngrp);

  // h double-buffer: it0 hb0->hb1, it1 hb1->hb0, it2 hb0->hb1 (final in hb1)
  k_gruagg<<<gb,256,0,stream>>>(hb0,hb1,rp,epack,dinv,Bcnv,conv_b,Bgru,gbih,gbhh,h,0,ngrp,N);
  k_gruagg<<<gb,256,0,stream>>>(hb1,hb0,rp,epack,dinv,Bcnv,conv_b,Bgru,gbih,gbhh,h,0,ngrp,N);
  k_gruagg<<<gb,256,0,stream>>>(hb0,hb1,rp,epack,dinv,Bcnv,conv_b,Bgru,gbih,gbhh,h,1,ngrp,N);

  // Set2Set: lstm0; [attn, merge+lstm] x2; attn; merge(final)
  k_merge_lstm<<<NB,256,0,stream>>>(apart,qstar,hl,cl,lwih,lwhh,lbih,lbhh,0,1);
  for(int st=0;st<3;st++){
    k_attn_part<<<NB*KB,256,0,stream>>>(hb1,batch,hl,apart,N);
    int do_lstm = (st<2)? 1:0;
    k_merge_lstm<<<NB,256,0,stream>>>(apart,qstar,hl,cl,lwih,lwhh,lbih,lbhh,1,do_lstm);
  }
}

// Round 10
// 636.172 us; speedup vs baseline: 5.3316x; 1.0197x over previous
//
#include <hip/hip_runtime.h>
#include <math.h>

#define FEATD 128
#define DIM 64
#define NB 256
#define SCB 256
#define KB 16      // attention partial blocks per graph
#define RNG 128    // nodes per CSR-fill bucket
#define NBUCKMAX 2048
#define CH1 8192   // edges per block, bin-scatter phase

typedef short bf16x8 __attribute__((ext_vector_type(8)));
typedef float f32x4 __attribute__((ext_vector_type(4)));

__device__ __forceinline__ float frcp_(float x){ return __builtin_amdgcn_rcpf(x); }
__device__ __forceinline__ float sigmoidf_(float x){ return frcp_(1.f+__expf(-x)); }
__device__ __forceinline__ float tanhf_(float x){ float e=__expf(2.f*x); return 1.f-2.f*frcp_(e+1.f); }

__device__ __forceinline__ unsigned short f2bf(float f){
  unsigned u = __float_as_uint(f);
  unsigned r = (u + 0x7FFFu + ((u>>16)&1u)) >> 16;
  return (unsigned short)r;
}
__device__ __forceinline__ float bf2f(unsigned short s){
  return __uint_as_float(((unsigned)s)<<16);
}

__device__ __forceinline__ int lower_bound_i(const int* __restrict__ a, int n, int key){
  int lo=0, hi=n;
  while(lo<hi){ int mid=(lo+hi)>>1; if(a[mid]<key) lo=mid+1; else hi=mid; }
  return lo;
}

// ======================= CSR setup =======================
__global__ void k_count(const int* __restrict__ col, int* __restrict__ deg, int E){
  int i=blockIdx.x*blockDim.x+threadIdx.x;
  if(i<E) atomicAdd(&deg[col[i]],1);
}

__global__ void k_dinv(const int* __restrict__ deg, float* __restrict__ dinv, int n){
  int i=blockIdx.x*blockDim.x+threadIdx.x;
  if(i<n) dinv[i]=rsqrtf((float)(deg[i]+1)); // +1 self-loop
}

// --- multi-block exclusive scan ---
__global__ __launch_bounds__(256) void k_scan_part(const int* __restrict__ deg, int* __restrict__ part, int n){
  __shared__ int s[256];
  int b=blockIdx.x;
  int chunk=(n+SCB-1)/SCB;
  int lo=b*chunk, hi=min(lo+chunk,n);
  int acc=0;
  for(int i=lo+threadIdx.x;i<hi;i+=256) acc+=deg[i];
  s[threadIdx.x]=acc; __syncthreads();
  for(int off=128;off;off>>=1){
    if(threadIdx.x<off) s[threadIdx.x]+=s[threadIdx.x+off];
    __syncthreads();
  }
  if(threadIdx.x==0) part[b]=s[0];
}

__global__ __launch_bounds__(256) void k_scan_mid(int* __restrict__ part){
  __shared__ int s[256];
  int t=threadIdx.x;
  s[t]=part[t]; __syncthreads();
  for(int off=1;off<256;off<<=1){
    int v=(t>=off)? s[t-off]:0;
    __syncthreads();
    s[t]+=v;
    __syncthreads();
  }
  part[t]=(t>0)? s[t-1]:0;  // exclusive
}

// also fills gcur[b*32] = rp[b*RNG] (bucket cursors) on the fly
__global__ __launch_bounds__(256) void k_scan_out(const int* __restrict__ deg, const int* __restrict__ part,
                                                  int* __restrict__ rp, int* __restrict__ gcur, int n){
  __shared__ int s[256];
  int b=blockIdx.x, t=threadIdx.x;
  int chunk=(n+SCB-1)/SCB;
  int lo=b*chunk, hi=min(lo+chunk,n);
  int tchunk=(chunk+255)/256;
  int tlo=lo+t*tchunk, thi=min(tlo+tchunk,hi);
  int acc=0;
  for(int i=tlo;i<thi;i++) acc+=deg[i];
  s[t]=acc; __syncthreads();
  for(int off=1;off<256;off<<=1){
    int v=(t>=off)? s[t-off]:0;
    __syncthreads();
    s[t]+=v;
    __syncthreads();
  }
  int pre=part[b]+((t>0)? s[t-1]:0);
  for(int i=tlo;i<thi;i++){
    rp[i]=pre;
    if((i&(RNG-1))==0) gcur[(i>>7)*32]=pre;
    pre+=deg[i];
  }
  if(b==SCB-1 && t==0) rp[n]=part[b]+s[255];
}

// ======================= bucketed CSR fill =======================
__global__ __launch_bounds__(256) void k_binscat(const int* __restrict__ row, const int* __restrict__ col,
                       int* __restrict__ gcur, unsigned* __restrict__ tmp, int E, int nbuck){
  __shared__ int lcnt[NBUCKMAX];
  __shared__ int lcur[NBUCKMAX];
  int t=threadIdx.x;
  for(int i=t;i<nbuck;i+=256) lcnt[i]=0;
  __syncthreads();
  int lo=blockIdx.x*CH1, hi=min(lo+CH1,E);
  for(int i=lo+t;i<hi;i+=256) atomicAdd(&lcnt[col[i]>>7],1);
  __syncthreads();
  for(int i=t;i<nbuck;i+=256){
    int cnt=lcnt[i];
    lcur[i]=(cnt>0)? atomicAdd(&gcur[i*32],cnt):0;
  }
  __syncthreads();
  for(int i=lo+t;i<hi;i+=256){
    int c=col[i], r=row[i];
    int pos=atomicAdd(&lcur[c>>7],1);
    tmp[pos]=((unsigned)r<<7)|(unsigned)(c&127);
  }
}

__global__ __launch_bounds__(256) void k_place(const unsigned* __restrict__ tmp, const int* __restrict__ rp,
                      const float* __restrict__ dinv, int2* __restrict__ epack, int n, int nbuck){
  __shared__ int lfill[RNG];
  __shared__ int lrp[RNG];
  __shared__ float ldv[RNG];
  int b=blockIdx.x, t=threadIdx.x;
  int nbase=b*RNG;
  int nn=min(RNG,n-nbase);
  if(t<nn){ lfill[t]=0; lrp[t]=rp[nbase+t]; ldv[t]=dinv[nbase+t]; }
  __syncthreads();
  int lo=rp[nbase], hi=rp[min(nbase+RNG,n)];
  for(int j=lo+t;j<hi;j+=256){
    unsigned v=tmp[j];
    int cl=v&127;
    int r=(int)(v>>7);
    int pos=atomicAdd(&lfill[cl],1);
    epack[lrp[cl]+pos]=make_int2(r,__float_as_int(dinv[r]*ldv[cl]));
  }
}

// ======================= MFMA B-fragment prep =======================
// mfma_f32_16x16x32_bf16 fragments:
//   A: lane l holds row (l&15), k = s*32 + (l>>4)*8 + r   (r=0..7)
//   B: lane l holds col (l&15), k = s*32 + (l>>4)*8 + r
//   D: lane l holds col (l&15), row = (l>>4)*4 + reg
// Plain (t-major) frags: Bf[((t*S + s)*64 + lane)*8 + r] = W[k][c], t=c/16, S=K/32.
__global__ void k_prep_plain(const float* __restrict__ W, unsigned short* __restrict__ Bf, int K, int C){
  int i=blockIdx.x*blockDim.x+threadIdx.x;
  if(i>=K*C) return;
  int k=i/C, c=i%C;
  int t=c>>4, s=k>>5, lane=(c&15)|(((k>>3)&3)<<4), r=k&7;
  int S=K>>5;
  Bf[(((t*S)+s)*64+lane)*8+r]=f2bf(W[(size_t)k*C+c]);
}

// Assembled GRU weights, S-MAJOR frag order (f = s*16+t) so each 16KB quarter (one s) is contiguous.
// X=[m|h] (K=128), cols: [0,64)=r, [64,128)=z, [128,192)=in_, [192,256)=hn.
__global__ void k_prep_gru(const float* __restrict__ wih, const float* __restrict__ whh,
                           unsigned short* __restrict__ Bf){
  int i=blockIdx.x*blockDim.x+threadIdx.x;
  if(i>=128*256) return;
  int k=i>>8, c=i&255;
  float v;
  if(c<128){          // r,z
    v = (k<64) ? wih[c*64+k] : whh[c*64+(k-64)];
  } else if(c<192){   // in_
    v = (k<64) ? wih[c*64+k] : 0.f;
  } else {            // hn
    v = (k<64) ? 0.f : whh[(c-64)*64+(k-64)];
  }
  int t=c>>4, s=k>>5, lane=(c&15)|(((k>>3)&3)<<4), r=k&7;
  Bf[(((s*16)+t)*64+lane)*8+r]=f2bf(v);
}

// ======================= lin0: hb = bf16(relu(x @ W + b)), LDS-staged coalesced store ===================
__global__ __launch_bounds__(256) void k_lin0(const float* __restrict__ x, const unsigned short* __restrict__ Bf,
                      const float* __restrict__ bias,
                      unsigned short* __restrict__ hb, int ngrp){
  __shared__ __align__(16) unsigned short lt[4][16][72];
  int l=threadIdx.x&63, w=threadIdx.x>>6;
  int g=blockIdx.x*4+w;
  if(g>=ngrp) return;
  int row16=l&15, koff=(l>>4)*8, l16=l&15;
  f32x4 acc[4]={};
  const float* xr = x + (size_t)(g*16+row16)*128 + koff;
  #pragma unroll
  for(int s=0;s<4;s++){
    f32x4 a0=*(const f32x4*)(xr+s*32);
    f32x4 a1=*(const f32x4*)(xr+s*32+4);
    bf16x8 af;
    #pragma unroll
    for(int r=0;r<4;r++){ af[r]=(short)f2bf(a0[r]); af[4+r]=(short)f2bf(a1[r]); }
    #pragma unroll
    for(int t=0;t<4;t++){
      bf16x8 bf=*(const bf16x8*)(Bf+(((t*4)+s)*64+l)*8);
      acc[t]=__builtin_amdgcn_mfma_f32_16x16x32_bf16(af,bf,acc[t],0,0,0);
    }
  }
  #pragma unroll
  for(int t=0;t<4;t++){
    int c=t*16+l16;
    float b=bias[c];
    #pragma unroll
    for(int j=0;j<4;j++)
      lt[w][(l>>4)*4+j][c]=f2bf(fmaxf(acc[t][j]+b,0.f));
  }
  #pragma unroll
  for(int i=0;i<4;i++){
    int rl=i*4+(l>>4);
    uint2 v=*(const uint2*)&lt[w][rl][l16*4];
    ((uint2*)hb)[(((unsigned)(g*16+rl))<<4)+l16]=v;
  }
}

// ======================= fused aggregate + conv + GRU ===================
// Per wave: 16 nodes. Gather agg = Â h_in, stage agg + self h row in per-wave LDS tiles,
// then m = relu(agg@Wc+cb) and h_out = GRU(m, h) with Bgru staged in 16KB LDS quarters.
// Epilogue stages hn through LDS -> coalesced uint2 (bf16) / f32x4 (last iter) stores.
__global__ __launch_bounds__(256) void k_gruagg(
                     const unsigned short* __restrict__ hin, unsigned short* __restrict__ hout,
                     const int* __restrict__ rp, const int2* __restrict__ epack,
                     const float* __restrict__ dinv,
                     const unsigned short* __restrict__ Bcnv, const float* __restrict__ cb,
                     const unsigned short* __restrict__ Bgru,
                     const float* __restrict__ bih, const float* __restrict__ bhh,
                     float* __restrict__ h, int last, int ngrp, int n){
  __shared__ __align__(16) unsigned short Bs[8192];          // 16 KB: one s-quarter of Bgru
  __shared__ __align__(16) unsigned short tAH[4][2][16][72]; // [w][0]=agg/m tile, [w][1]=h tile
  int tid=threadIdx.x;
  int l=tid&63, w=tid>>6;
  int g=blockIdx.x*4+w;
  bool act = g<ngrp;
  int gc = act? g : (ngrp-1);
  int q=l>>4, l16=l&15;
  int row16=l&15, koff=(l>>4)*8;

  unsigned short (*tA)[72] = tAH[w][0];
  unsigned short (*tH)[72] = tAH[w][1];

  // conv B-frags into registers (issued early, resolve under gather)
  bf16x8 bc[8];
  #pragma unroll
  for(int f=0;f<8;f++) bc[f]=*(const bf16x8*)(Bcnv+((size_t)f*64+l)*8);

  // stage Bgru quarter s=0
  {
    const f32x4* gh=(const f32x4*)Bgru; f32x4* lh=(f32x4*)Bs;
    #pragma unroll
    for(int i=0;i<4;i++) lh[i*256+tid]=gh[i*256+tid];
  }

  // ---- gather: 4 rounds; quarter q owns node gc*16+rr*4+q; 4 chains ----
  const uint2* h64=(const uint2*)hin;
  #pragma unroll
  for(int rr=0;rr<4;rr++){
    int node=min(gc*16+rr*4+q, n-1);
    float a0=0.f,a1=0.f,a2=0.f,a3=0.f, b0=0.f,b1=0.f,b2=0.f,b3=0.f;
    int s=rp[node], e=rp[node+1];
    uint2 selfp=h64[((unsigned)node<<4)+l16];
    int j=s;
    for(; j+3<e; j+=4){
      int2 e0=epack[j];
      int2 e1=epack[j+1];
      int2 e2=epack[j+2];
      int2 e3=epack[j+3];
      uint2 p0=h64[((unsigned)e0.x<<4)+l16];
      uint2 p1=h64[((unsigned)e1.x<<4)+l16];
      uint2 p2=h64[((unsigned)e2.x<<4)+l16];
      uint2 p3=h64[((unsigned)e3.x<<4)+l16];
      float n0=__int_as_float(e0.y), n1=__int_as_float(e1.y);
      float n2=__int_as_float(e2.y), n3=__int_as_float(e3.y);
      a0+=n0*bf2f((unsigned short)p0.x); a1+=n0*bf2f((unsigned short)(p0.x>>16));
      a2+=n0*bf2f((unsigned short)p0.y); a3+=n0*bf2f((unsigned short)(p0.y>>16));
      b0+=n1*bf2f((unsigned short)p1.x); b1+=n1*bf2f((unsigned short)(p1.x>>16));
      b2+=n1*bf2f((unsigned short)p1.y); b3+=n1*bf2f((unsigned short)(p1.y>>16));
      a0+=n2*bf2f((unsigned short)p2.x); a1+=n2*bf2f((unsigned short)(p2.x>>16));
      a2+=n2*bf2f((unsigned short)p2.y); a3+=n2*bf2f((unsigned short)(p2.y>>16));
      b0+=n3*bf2f((unsigned short)p3.x); b1+=n3*bf2f((unsigned short)(p3.x>>16));
      b2+=n3*bf2f((unsigned short)p3.y); b3+=n3*bf2f((unsigned short)(p3.y>>16));
    }
    for(; j<e; j++){
      int2 e0=epack[j];
      uint2 p0=h64[((unsigned)e0.x<<4)+l16];
      float n0=__int_as_float(e0.y);
      a0+=n0*bf2f((unsigned short)p0.x); a1+=n0*bf2f((unsigned short)(p0.x>>16));
      a2+=n0*bf2f((unsigned short)p0.y); a3+=n0*bf2f((unsigned short)(p0.y>>16));
    }
    float dv=dinv[node]; dv*=dv;
    a0+=b0+dv*bf2f((unsigned short)selfp.x);
    a1+=b1+dv*bf2f((unsigned short)(selfp.x>>16));
    a2+=b2+dv*bf2f((unsigned short)selfp.y);
    a3+=b3+dv*bf2f((unsigned short)(selfp.y>>16));
    int ri=rr*4+q;
    unsigned* tAp=(unsigned*)&tA[ri][l16*4];
    tAp[0]=(unsigned)f2bf(a0)|(((unsigned)f2bf(a1))<<16);
    tAp[1]=(unsigned)f2bf(a2)|(((unsigned)f2bf(a3))<<16);
    unsigned* tHp=(unsigned*)&tH[ri][l16*4];
    tHp[0]=selfp.x; tHp[1]=selfp.y;
  }

  // ---- conv mini-GEMM: m = relu(agg[16x64] @ Wc + cb); A-frags from tA (same wave) ----
  f32x4 accm[4]={};
  #pragma unroll
  for(int s=0;s<2;s++){
    bf16x8 af=*(const bf16x8*)&tA[row16][s*32+koff];
    #pragma unroll
    for(int t=0;t<4;t++)
      accm[t]=__builtin_amdgcn_mfma_f32_16x16x32_bf16(af,bc[t*2+s],accm[t],0,0,0);
  }
  // m -> tA (overwrite; same-wave lockstep safe)
  #pragma unroll
  for(int t=0;t<4;t++){
    int c=t*16+l16;
    float b=cb[c];
    #pragma unroll
    for(int j=0;j<4;j++)
      tA[(l>>4)*4+j][c]=f2bf(fmaxf(accm[t][j]+b,0.f));
  }

  // ---- GRU GEMM over 4 K-slices, Bs restaged per slice ----
  f32x4 acc[16]={};
  __syncthreads();   // Bs quarter 0 visible
  #pragma unroll
  for(int s=0;s<4;s++){
    if(s>0){
      __syncthreads();  // prior quarter reads done
      const f32x4* gh=(const f32x4*)(Bgru+(size_t)s*8192); f32x4* lh=(f32x4*)Bs;
      #pragma unroll
      for(int i=0;i<4;i++) lh[i*256+tid]=gh[i*256+tid];
      __syncthreads();  // quarter s visible
    }
    bf16x8 af;
    if(s<2) af=*(const bf16x8*)&tA[row16][s*32+koff];
    else    af=*(const bf16x8*)&tH[row16][(s-2)*32+koff];
    #pragma unroll
    for(int t=0;t<16;t++){
      bf16x8 bf=*(const bf16x8*)(Bs+((size_t)t*64+l)*8);
      acc[t]=__builtin_amdgcn_mfma_f32_16x16x32_bf16(af,bf,acc[t],0,0,0);
    }
  }

  if(!act) return;
  // ---- epilogue: gates in-register; hold from tH (read before overwrite) ----
  float hn[16];
  #pragma unroll
  for(int t=0;t<4;t++){
    int d=t*16+l16;
    float br =bih[d]    +bhh[d];
    float bz =bih[64+d] +bhh[64+d];
    float bni=bih[128+d];
    float bnh=bhh[128+d];
    #pragma unroll
    for(int j=0;j<4;j++){
      float r  = sigmoidf_(acc[t][j]   + br);
      float z  = sigmoidf_(acc[4+t][j] + bz);
      float nc = tanhf_(acc[8+t][j] + bni + r*(acc[12+t][j] + bnh));
      float hold=bf2f(tH[(l>>4)*4+j][d]);
      hn[t*4+j]=(1.f-z)*nc + z*hold;
    }
  }
  // stage hn (bf16) into tH, then coalesced uint2 writeback (wave-lockstep: all hold reads precede)
  #pragma unroll
  for(int t=0;t<4;t++){
    int d=t*16+l16;
    #pragma unroll
    for(int j=0;j<4;j++)
      tH[(l>>4)*4+j][d]=f2bf(hn[t*4+j]);
  }
  #pragma unroll
  for(int i=0;i<4;i++){
    int rl=i*4+(l>>4);
    uint2 v=*(const uint2*)&tH[rl][l16*4];
    ((uint2*)hout)[(((unsigned)(gc*16+rl))<<4)+l16]=v;
  }
  if(last){
    // f32 feat via LDS transpose over the (now-free) tA+tH storage: float[16][68], 4352B <= 4608B
    float* ft=(float*)&tAH[w][0][0][0];
    #pragma unroll
    for(int t=0;t<4;t++){
      int d=t*16+l16;
      #pragma unroll
      for(int j=0;j<4;j++)
        ft[((l>>4)*4+j)*68+d]=hn[t*4+j];
    }
    #pragma unroll
    for(int i=0;i<4;i++){
      int rl=i*4+(l>>4);
      f32x4 v=*(const f32x4*)&ft[rl*68+l16*4];
      *(f32x4*)&h[(size_t)(gc*16+rl)*64+l16*4]=v;
    }
  }
}

// ======================= Set2Set: parallel attention partials =======================
__global__ __launch_bounds__(256) void k_attn_part(const unsigned short* __restrict__ hb, const int* __restrict__ batch,
                        const float* __restrict__ hl, float* __restrict__ apart, int n){
  int b=blockIdx.x/KB, kb=blockIdx.x%KB;
  int tid=threadIdx.x, lane=tid&63, w=tid>>6;
  __shared__ float qs[64];
  __shared__ float wm[4], wsm[4];
  __shared__ float wacc[4][64];
  if(tid<64) qs[tid]=hl[b*64+tid];
  int lo=lower_bound_i(batch,n,b), hi=lower_bound_i(batch,n,b+1);
  int cnt=hi-lo;
  int chunk=(cnt+KB-1)/KB;
  int slo=lo+kb*chunk, shi=min(slo+chunk,hi);
  __syncthreads();
  float q=qs[lane];
  float mw=-3.0e38f, sw=0.f, aw=0.f;
  for(int i=slo+w;i<shi;i+=4){
    float f=bf2f(hb[(size_t)i*64+lane]);
    float v=f*q;
    #pragma unroll
    for(int off=32;off;off>>=1) v+=__shfl_xor(v,off);
    if(v>mw){
      float sc=__expf(mw-v);
      sw=sw*sc+1.f;
      aw=aw*sc+f;
      mw=v;
    } else {
      float p=__expf(v-mw);
      sw+=p;
      aw+=p*f;
    }
  }
  if(lane==0){ wm[w]=mw; wsm[w]=sw; }
  wacc[w][lane]=aw;
  __syncthreads();
  if(w==0){
    float M=fmaxf(fmaxf(wm[0],wm[1]),fmaxf(wm[2],wm[3]));
    float S=0.f, A=0.f;
    #pragma unroll
    for(int k=0;k<4;k++){
      float sc=__expf(wm[k]-M);
      S+=wsm[k]*sc;
      A+=wacc[k][lane]*sc;
    }
    float* p=apart+(size_t)blockIdx.x*68;
    p[lane]=A;
    if(lane==0){ p[64]=M; p[65]=S; }
  }
}

// merge partials -> r_read (qstar[64:128]); optionally run next LSTM cell
__global__ __launch_bounds__(256) void k_merge_lstm(const float* __restrict__ apart,
                   float* __restrict__ qstar, float* __restrict__ hl, float* __restrict__ cl,
                   const float* __restrict__ wih, const float* __restrict__ whh,
                   const float* __restrict__ bih, const float* __restrict__ bhh,
                   int do_merge, int do_lstm){
  int b=blockIdx.x, tid=threadIdx.x;
  __shared__ float qs[128];
  __shared__ float gates[256];
  if(do_merge){
    if(tid<64){
      const float* p0=apart+(size_t)b*KB*68;
      float M=-3.0e38f;
      #pragma unroll
      for(int k=0;k<KB;k++) M=fmaxf(M,p0[k*68+64]);
      float S=0.f, A=0.f;
      #pragma unroll
      for(int k=0;k<KB;k++){
        float sc=__expf(p0[k*68+64]-M);
        S+=p0[k*68+65]*sc;
        A+=p0[k*68+tid]*sc;
      }
      float inv=(S>0.f)? 1.f/S:0.f;
      float r=A*inv;
      qs[64+tid]=r;
      qstar[b*128+64+tid]=r;
    }
  } else {
    if(tid<64) qs[64+tid]=qstar[b*128+64+tid];
  }
  if(tid<64) qs[tid]=hl[b*64+tid];   // q_t == previous LSTM hidden
  __syncthreads();
  if(!do_lstm) return;
  float acc=bih[tid]+bhh[tid];
  const float* wi=wih+(size_t)tid*128;
  #pragma unroll 8
  for(int k=0;k<128;k++) acc+=qs[k]*wi[k];
  const float* w2=whh+(size_t)tid*64;
  #pragma unroll 8
  for(int k=0;k<64;k++) acc+=qs[k]*w2[k];
  gates[tid]=acc;
  __syncthreads();
  if(tid<64){
    float i_=gates[tid], f_=gates[64+tid], g_=gates[128+tid], o_=gates[192+tid];
    float c=sigmoidf_(f_)*cl[b*64+tid]+sigmoidf_(i_)*tanhf(g_);
    float hn=sigmoidf_(o_)*tanhf(c);
    cl[b*64+tid]=c; hl[b*64+tid]=hn;
    qstar[b*128+tid]=hn;
  }
}

extern "C" void kernel_launch(void* const* d_in, const int* in_sizes, int n_in,
                              void* d_out, int out_size, void* d_ws, size_t ws_size,
                              hipStream_t stream){
  const float* x      =(const float*)d_in[0];
  const int*   ei     =(const int*)d_in[1];
  const int*   batch  =(const int*)d_in[2];
  const float* lin0_w =(const float*)d_in[3];
  const float* lin0_b =(const float*)d_in[4];
  const float* conv_w =(const float*)d_in[5];
  const float* conv_b =(const float*)d_in[6];
  const float* gwih   =(const float*)d_in[7];
  const float* gwhh   =(const float*)d_in[8];
  const float* gbih   =(const float*)d_in[9];
  const float* gbhh   =(const float*)d_in[10];
  const float* lwih   =(const float*)d_in[11];
  const float* lwhh   =(const float*)d_in[12];
  const float* lbih   =(const float*)d_in[13];
  const float* lbhh   =(const float*)d_in[14];

  int N = in_sizes[0]/FEATD;
  int E = in_sizes[1]/2;
  const int* row = ei;
  const int* col = ei + E;

  float* qstar = (float*)d_out;            // [256,128]
  float* h     = (float*)d_out + NB*2*DIM; // [N,64] 'feat' = f32 h (written by last k_gruagg)

  char* ws=(char*)d_ws;
  size_t off=0;
  auto alloc=[&](size_t bytes)->void*{ void* p=ws+off; off=(off+bytes+255)&~(size_t)255; return p; };
  int*   deg  =(int*)  alloc((size_t)N*4);
  float* dinv =(float*)alloc((size_t)N*4);
  int*   rp   =(int*)  alloc((size_t)(N+1)*4);
  int*   part =(int*)  alloc((size_t)SCB*4);
  int*   gcur =(int*)  alloc((size_t)NBUCKMAX*32*4);
  unsigned* tmp=(unsigned*)alloc((size_t)E*4);
  int2*  epack=(int2*) alloc((size_t)E*8);
  unsigned short* hb0  =(unsigned short*)alloc((size_t)N*64*2);
  unsigned short* hb1  =(unsigned short*)alloc((size_t)N*64*2);
  float* hl   =(float*)alloc((size_t)NB*DIM*4);
  float* cl   =(float*)alloc((size_t)NB*DIM*4);
  float* apart=(float*)alloc((size_t)NB*KB*68*4);
  unsigned short* Bgru =(unsigned short*)alloc(128*256*2);
  unsigned short* Blin =(unsigned short*)alloc(128*64*2);
  unsigned short* Bcnv =(unsigned short*)alloc(64*64*2);

  hipMemsetAsync(deg ,0,(size_t)N*4,stream);
  hipMemsetAsync(hl  ,0,(size_t)NB*DIM*4,stream);
  hipMemsetAsync(cl  ,0,(size_t)NB*DIM*4,stream);
  hipMemsetAsync(qstar,0,(size_t)NB*2*DIM*4,stream);

  int nbuck=(N+RNG-1)/RNG;

  k_count<<<(E+255)/256,256,0,stream>>>(col,deg,E);
  k_dinv <<<(N+255)/256,256,0,stream>>>(deg,dinv,N);
  k_scan_part<<<SCB,256,0,stream>>>(deg,part,N);
  k_scan_mid <<<1,256,0,stream>>>(part);
  k_scan_out <<<SCB,256,0,stream>>>(deg,part,rp,gcur,N);
  k_binscat<<<(E+CH1-1)/CH1,256,0,stream>>>(row,col,gcur,tmp,E,nbuck);
  k_place<<<nbuck,256,0,stream>>>(tmp,rp,dinv,epack,N,nbuck);

  k_prep_plain<<<(128*64+255)/256,256,0,stream>>>(lin0_w,Blin,128,64);
  k_prep_plain<<<(64*64+255)/256,256,0,stream>>>(conv_w,Bcnv,64,64);
  k_prep_gru  <<<(128*256+255)/256,256,0,stream>>>(gwih,gwhh,Bgru);

  int ngrp=(N+15)/16;
  int gb=(ngrp+3)/4;

  k_lin0<<<gb,256,0,stream>>>(x,Blin,lin0_b,hb0,ngrp);

  // h double-buffer: it0 hb0->hb1, it1 hb1->hb0, it2 hb0->hb1 (final in hb1)
  k_gruagg<<<gb,256,0,stream>>>(hb0,hb1,rp,epack,dinv,Bcnv,conv_b,Bgru,gbih,gbhh,h,0,ngrp,N);
  k_gruagg<<<gb,256,0,stream>>>(hb1,hb0,rp,epack,dinv,Bcnv,conv_b,Bgru,gbih,gbhh,h,0,ngrp,N);
  k_gruagg<<<gb,256,0,stream>>>(hb0,hb1,rp,epack,dinv,Bcnv,conv_b,Bgru,gbih,gbhh,h,1,ngrp,N);

  // Set2Set: lstm0; [attn, merge+lstm] x2; attn; merge(final)
  k_merge_lstm<<<NB,256,0,stream>>>(apart,qstar,hl,cl,lwih,lwhh,lbih,lbhh,0,1);
  for(int st=0;st<3;st++){
    k_attn_part<<<NB*KB,256,0,stream>>>(hb1,batch,hl,apart,N);
    int do_lstm = (st<2)? 1:0;
    k_merge_lstm<<<NB,256,0,stream>>>(apart,qstar,hl,cl,lwih,lwhh,lbih,lbhh,1,do_lstm);
  }
}

// Round 11
// 550.677 us; speedup vs baseline: 6.1593x; 1.1553x over previous
//
#include <hip/hip_runtime.h>
#include <math.h>

#define FEATD 128
#define DIM 64
#define NB 256
#define SCB 256
#define KB 16      // attention partial blocks per graph
#define RNG 128    // nodes per CSR-fill bucket
#define NBUCKMAX 2048
#define CH1 8192   // edges per block, bin-scatter phase

typedef short bf16x8 __attribute__((ext_vector_type(8)));
typedef float f32x4 __attribute__((ext_vector_type(4)));

__device__ __forceinline__ float frcp_(float x){ return __builtin_amdgcn_rcpf(x); }
__device__ __forceinline__ float sigmoidf_(float x){ return frcp_(1.f+__expf(-x)); }
__device__ __forceinline__ float tanhf_(float x){ float e=__expf(2.f*x); return 1.f-2.f*frcp_(e+1.f); }

__device__ __forceinline__ unsigned short f2bf(float f){
  unsigned u = __float_as_uint(f);
  unsigned r = (u + 0x7FFFu + ((u>>16)&1u)) >> 16;
  return (unsigned short)r;
}
__device__ __forceinline__ float bf2f(unsigned short s){
  return __uint_as_float(((unsigned)s)<<16);
}

__device__ __forceinline__ int lower_bound_i(const int* __restrict__ a, int n, int key){
  int lo=0, hi=n;
  while(lo<hi){ int mid=(lo+hi)>>1; if(a[mid]<key) lo=mid+1; else hi=mid; }
  return lo;
}

// ======================= CSR setup =======================
__global__ void k_count(const int* __restrict__ col, int* __restrict__ deg, int E){
  int i=blockIdx.x*blockDim.x+threadIdx.x;
  if(i<E) atomicAdd(&deg[col[i]],1);
}

__global__ void k_dinv(const int* __restrict__ deg, float* __restrict__ dinv, int n){
  int i=blockIdx.x*blockDim.x+threadIdx.x;
  if(i<n) dinv[i]=rsqrtf((float)(deg[i]+1)); // +1 self-loop
}

// --- multi-block exclusive scan ---
__global__ __launch_bounds__(256) void k_scan_part(const int* __restrict__ deg, int* __restrict__ part, int n){
  __shared__ int s[256];
  int b=blockIdx.x;
  int chunk=(n+SCB-1)/SCB;
  int lo=b*chunk, hi=min(lo+chunk,n);
  int acc=0;
  for(int i=lo+threadIdx.x;i<hi;i+=256) acc+=deg[i];
  s[threadIdx.x]=acc; __syncthreads();
  for(int off=128;off;off>>=1){
    if(threadIdx.x<off) s[threadIdx.x]+=s[threadIdx.x+off];
    __syncthreads();
  }
  if(threadIdx.x==0) part[b]=s[0];
}

__global__ __launch_bounds__(256) void k_scan_mid(int* __restrict__ part){
  __shared__ int s[256];
  int t=threadIdx.x;
  s[t]=part[t]; __syncthreads();
  for(int off=1;off<256;off<<=1){
    int v=(t>=off)? s[t-off]:0;
    __syncthreads();
    s[t]+=v;
    __syncthreads();
  }
  part[t]=(t>0)? s[t-1]:0;  // exclusive
}

// also fills gcur[b*32] = rp[b*RNG] (bucket cursors) on the fly
__global__ __launch_bounds__(256) void k_scan_out(const int* __restrict__ deg, const int* __restrict__ part,
                                                  int* __restrict__ rp, int* __restrict__ gcur, int n){
  __shared__ int s[256];
  int b=blockIdx.x, t=threadIdx.x;
  int chunk=(n+SCB-1)/SCB;
  int lo=b*chunk, hi=min(lo+chunk,n);
  int tchunk=(chunk+255)/256;
  int tlo=lo+t*tchunk, thi=min(tlo+tchunk,hi);
  int acc=0;
  for(int i=tlo;i<thi;i++) acc+=deg[i];
  s[t]=acc; __syncthreads();
  for(int off=1;off<256;off<<=1){
    int v=(t>=off)? s[t-off]:0;
    __syncthreads();
    s[t]+=v;
    __syncthreads();
  }
  int pre=part[b]+((t>0)? s[t-1]:0);
  for(int i=tlo;i<thi;i++){
    rp[i]=pre;
    if((i&(RNG-1))==0) gcur[(i>>7)*32]=pre;
    pre+=deg[i];
  }
  if(b==SCB-1 && t==0) rp[n]=part[b]+s[255];
}

// ======================= bucketed CSR fill =======================
__global__ __launch_bounds__(256) void k_binscat(const int* __restrict__ row, const int* __restrict__ col,
                       int* __restrict__ gcur, unsigned* __restrict__ tmp, int E, int nbuck){
  __shared__ int lcnt[NBUCKMAX];
  __shared__ int lcur[NBUCKMAX];
  int t=threadIdx.x;
  for(int i=t;i<nbuck;i+=256) lcnt[i]=0;
  __syncthreads();
  int lo=blockIdx.x*CH1, hi=min(lo+CH1,E);
  for(int i=lo+t;i<hi;i+=256) atomicAdd(&lcnt[col[i]>>7],1);
  __syncthreads();
  for(int i=t;i<nbuck;i+=256){
    int cnt=lcnt[i];
    lcur[i]=(cnt>0)? atomicAdd(&gcur[i*32],cnt):0;
  }
  __syncthreads();
  for(int i=lo+t;i<hi;i+=256){
    int c=col[i], r=row[i];
    int pos=atomicAdd(&lcur[c>>7],1);
    tmp[pos]=((unsigned)r<<7)|(unsigned)(c&127);
  }
}

__global__ __launch_bounds__(256) void k_place(const unsigned* __restrict__ tmp, const int* __restrict__ rp,
                      const float* __restrict__ dinv, int2* __restrict__ epack, int n, int nbuck){
  __shared__ int lfill[RNG];
  __shared__ int lrp[RNG];
  __shared__ float ldv[RNG];
  int b=blockIdx.x, t=threadIdx.x;
  int nbase=b*RNG;
  int nn=min(RNG,n-nbase);
  if(t<nn){ lfill[t]=0; lrp[t]=rp[nbase+t]; ldv[t]=dinv[nbase+t]; }
  __syncthreads();
  int lo=rp[nbase], hi=rp[min(nbase+RNG,n)];
  for(int j=lo+t;j<hi;j+=256){
    unsigned v=tmp[j];
    int cl=v&127;
    int r=(int)(v>>7);
    int pos=atomicAdd(&lfill[cl],1);
    epack[lrp[cl]+pos]=make_int2(r,__float_as_int(dinv[r]*ldv[cl]));
  }
}

// ======================= MFMA B-fragment prep =======================
// mfma_f32_16x16x32_bf16 fragments:
//   A: lane l holds row (l&15), k = s*32 + (l>>4)*8 + r   (r=0..7)
//   B: lane l holds col (l&15), k = s*32 + (l>>4)*8 + r
//   D: lane l holds col (l&15), row = (l>>4)*4 + reg
// Plain (t-major) frags: Bf[((t*S + s)*64 + lane)*8 + r] = W[k][c], t=c/16, S=K/32.
__global__ void k_prep_plain(const float* __restrict__ W, unsigned short* __restrict__ Bf, int K, int C){
  int i=blockIdx.x*blockDim.x+threadIdx.x;
  if(i>=K*C) return;
  int k=i/C, c=i%C;
  int t=c>>4, s=k>>5, lane=(c&15)|(((k>>3)&3)<<4), r=k&7;
  int S=K>>5;
  Bf[(((t*S)+s)*64+lane)*8+r]=f2bf(W[(size_t)k*C+c]);
}

// Assembled GRU weights, S-MAJOR frag order (f = s*16+t) so each 16KB quarter (one s) is contiguous.
// X=[m|h] (K=128), cols: [0,64)=r, [64,128)=z, [128,192)=in_, [192,256)=hn.
__global__ void k_prep_gru(const float* __restrict__ wih, const float* __restrict__ whh,
                           unsigned short* __restrict__ Bf){
  int i=blockIdx.x*blockDim.x+threadIdx.x;
  if(i>=128*256) return;
  int k=i>>8, c=i&255;
  float v;
  if(c<128){          // r,z
    v = (k<64) ? wih[c*64+k] : whh[c*64+(k-64)];
  } else if(c<192){   // in_
    v = (k<64) ? wih[c*64+k] : 0.f;
  } else {            // hn
    v = (k<64) ? 0.f : whh[(c-64)*64+(k-64)];
  }
  int t=c>>4, s=k>>5, lane=(c&15)|(((k>>3)&3)<<4), r=k&7;
  Bf[(((s*16)+t)*64+lane)*8+r]=f2bf(v);
}

// ======================= lin0: hb = bf16(relu(x @ W + b)), LDS-staged coalesced store ===================
__global__ __launch_bounds__(256) void k_lin0(const float* __restrict__ x, const unsigned short* __restrict__ Bf,
                      const float* __restrict__ bias,
                      unsigned short* __restrict__ hb, int ngrp){
  __shared__ __align__(16) unsigned short lt[4][16][72];
  int l=threadIdx.x&63, w=threadIdx.x>>6;
  int g=blockIdx.x*4+w;
  if(g>=ngrp) return;
  int row16=l&15, koff=(l>>4)*8, l16=l&15;
  f32x4 acc[4]={};
  const float* xr = x + (size_t)(g*16+row16)*128 + koff;
  #pragma unroll
  for(int s=0;s<4;s++){
    f32x4 a0=*(const f32x4*)(xr+s*32);
    f32x4 a1=*(const f32x4*)(xr+s*32+4);
    bf16x8 af;
    #pragma unroll
    for(int r=0;r<4;r++){ af[r]=(short)f2bf(a0[r]); af[4+r]=(short)f2bf(a1[r]); }
    #pragma unroll
    for(int t=0;t<4;t++){
      bf16x8 bf=*(const bf16x8*)(Bf+(((t*4)+s)*64+l)*8);
      acc[t]=__builtin_amdgcn_mfma_f32_16x16x32_bf16(af,bf,acc[t],0,0,0);
    }
  }
  #pragma unroll
  for(int t=0;t<4;t++){
    int c=t*16+l16;
    float b=bias[c];
    #pragma unroll
    for(int j=0;j<4;j++)
      lt[w][(l>>4)*4+j][c]=f2bf(fmaxf(acc[t][j]+b,0.f));
  }
  #pragma unroll
  for(int i=0;i<4;i++){
    int rl=i*4+(l>>4);
    uint2 v=*(const uint2*)&lt[w][rl][l16*4];
    ((uint2*)hb)[(((unsigned)(g*16+rl))<<4)+l16]=v;
  }
}

// ======================= fused aggregate + conv + GRU ===================
// __launch_bounds__(256,4): 4 waves/EU target -> VGPR cap 128 (acc[16] f32x4 needs ~90 live;
// at the default the compiler allocated 76 and spilled accumulators -> ~50MB/dispatch scratch writeback).
__global__ __launch_bounds__(256,4) void k_gruagg(
                     const unsigned short* __restrict__ hin, unsigned short* __restrict__ hout,
                     const int* __restrict__ rp, const int2* __restrict__ epack,
                     const float* __restrict__ dinv,
                     const unsigned short* __restrict__ Bcnv, const float* __restrict__ cb,
                     const unsigned short* __restrict__ Bgru,
                     const float* __restrict__ bih, const float* __restrict__ bhh,
                     float* __restrict__ h, int last, int ngrp, int n){
  __shared__ __align__(16) unsigned short Bs[8192];          // 16 KB: one s-quarter of Bgru
  __shared__ __align__(16) unsigned short tAH[4][2][16][72]; // [w][0]=agg/m tile, [w][1]=h tile
  int tid=threadIdx.x;
  int l=tid&63, w=tid>>6;
  int g=blockIdx.x*4+w;
  bool act = g<ngrp;
  int gc = act? g : (ngrp-1);
  int q=l>>4, l16=l&15;
  int row16=l&15, koff=(l>>4)*8;

  unsigned short (*tA)[72] = tAH[w][0];
  unsigned short (*tH)[72] = tAH[w][1];

  // conv B-frags into registers (issued early, resolve under gather)
  bf16x8 bc[8];
  #pragma unroll
  for(int f=0;f<8;f++) bc[f]=*(const bf16x8*)(Bcnv+((size_t)f*64+l)*8);

  // stage Bgru quarter s=0
  {
    const f32x4* gh=(const f32x4*)Bgru; f32x4* lh=(f32x4*)Bs;
    #pragma unroll
    for(int i=0;i<4;i++) lh[i*256+tid]=gh[i*256+tid];
  }

  // ---- gather: 4 rounds; quarter q owns node gc*16+rr*4+q; 4 chains ----
  const uint2* h64=(const uint2*)hin;
  #pragma unroll
  for(int rr=0;rr<4;rr++){
    int node=min(gc*16+rr*4+q, n-1);
    float a0=0.f,a1=0.f,a2=0.f,a3=0.f, b0=0.f,b1=0.f,b2=0.f,b3=0.f;
    int s=rp[node], e=rp[node+1];
    uint2 selfp=h64[((unsigned)node<<4)+l16];
    int j=s;
    for(; j+3<e; j+=4){
      int2 e0=epack[j];
      int2 e1=epack[j+1];
      int2 e2=epack[j+2];
      int2 e3=epack[j+3];
      uint2 p0=h64[((unsigned)e0.x<<4)+l16];
      uint2 p1=h64[((unsigned)e1.x<<4)+l16];
      uint2 p2=h64[((unsigned)e2.x<<4)+l16];
      uint2 p3=h64[((unsigned)e3.x<<4)+l16];
      float n0=__int_as_float(e0.y), n1=__int_as_float(e1.y);
      float n2=__int_as_float(e2.y), n3=__int_as_float(e3.y);
      a0+=n0*bf2f((unsigned short)p0.x); a1+=n0*bf2f((unsigned short)(p0.x>>16));
      a2+=n0*bf2f((unsigned short)p0.y); a3+=n0*bf2f((unsigned short)(p0.y>>16));
      b0+=n1*bf2f((unsigned short)p1.x); b1+=n1*bf2f((unsigned short)(p1.x>>16));
      b2+=n1*bf2f((unsigned short)p1.y); b3+=n1*bf2f((unsigned short)(p1.y>>16));
      a0+=n2*bf2f((unsigned short)p2.x); a1+=n2*bf2f((unsigned short)(p2.x>>16));
      a2+=n2*bf2f((unsigned short)p2.y); a3+=n2*bf2f((unsigned short)(p2.y>>16));
      b0+=n3*bf2f((unsigned short)p3.x); b1+=n3*bf2f((unsigned short)(p3.x>>16));
      b2+=n3*bf2f((unsigned short)p3.y); b3+=n3*bf2f((unsigned short)(p3.y>>16));
    }
    for(; j+1<e; j+=2){   // 2-wide remainder (avg deg 8: tail was serial before)
      int2 e0=epack[j];
      int2 e1=epack[j+1];
      uint2 p0=h64[((unsigned)e0.x<<4)+l16];
      uint2 p1=h64[((unsigned)e1.x<<4)+l16];
      float n0=__int_as_float(e0.y), n1=__int_as_float(e1.y);
      a0+=n0*bf2f((unsigned short)p0.x); a1+=n0*bf2f((unsigned short)(p0.x>>16));
      a2+=n0*bf2f((unsigned short)p0.y); a3+=n0*bf2f((unsigned short)(p0.y>>16));
      b0+=n1*bf2f((unsigned short)p1.x); b1+=n1*bf2f((unsigned short)(p1.x>>16));
      b2+=n1*bf2f((unsigned short)p1.y); b3+=n1*bf2f((unsigned short)(p1.y>>16));
    }
    if(j<e){
      int2 e0=epack[j];
      uint2 p0=h64[((unsigned)e0.x<<4)+l16];
      float n0=__int_as_float(e0.y);
      a0+=n0*bf2f((unsigned short)p0.x); a1+=n0*bf2f((unsigned short)(p0.x>>16));
      a2+=n0*bf2f((unsigned short)p0.y); a3+=n0*bf2f((unsigned short)(p0.y>>16));
    }
    float dv=dinv[node]; dv*=dv;
    a0+=b0+dv*bf2f((unsigned short)selfp.x);
    a1+=b1+dv*bf2f((unsigned short)(selfp.x>>16));
    a2+=b2+dv*bf2f((unsigned short)selfp.y);
    a3+=b3+dv*bf2f((unsigned short)(selfp.y>>16));
    int ri=rr*4+q;
    unsigned* tAp=(unsigned*)&tA[ri][l16*4];
    tAp[0]=(unsigned)f2bf(a0)|(((unsigned)f2bf(a1))<<16);
    tAp[1]=(unsigned)f2bf(a2)|(((unsigned)f2bf(a3))<<16);
    unsigned* tHp=(unsigned*)&tH[ri][l16*4];
    tHp[0]=selfp.x; tHp[1]=selfp.y;
  }

  // ---- conv mini-GEMM: m = relu(agg[16x64] @ Wc + cb); A-frags from tA (same wave) ----
  f32x4 accm[4]={};
  #pragma unroll
  for(int s=0;s<2;s++){
    bf16x8 af=*(const bf16x8*)&tA[row16][s*32+koff];
    #pragma unroll
    for(int t=0;t<4;t++)
      accm[t]=__builtin_amdgcn_mfma_f32_16x16x32_bf16(af,bc[t*2+s],accm[t],0,0,0);
  }
  // m -> tA (overwrite; same-wave lockstep safe)
  #pragma unroll
  for(int t=0;t<4;t++){
    int c=t*16+l16;
    float b=cb[c];
    #pragma unroll
    for(int j=0;j<4;j++)
      tA[(l>>4)*4+j][c]=f2bf(fmaxf(accm[t][j]+b,0.f));
  }

  // ---- GRU GEMM over 4 K-slices, Bs restaged per slice ----
  f32x4 acc[16]={};
  __syncthreads();   // Bs quarter 0 visible
  #pragma unroll
  for(int s=0;s<4;s++){
    if(s>0){
      __syncthreads();  // prior quarter reads done
      const f32x4* gh=(const f32x4*)(Bgru+(size_t)s*8192); f32x4* lh=(f32x4*)Bs;
      #pragma unroll
      for(int i=0;i<4;i++) lh[i*256+tid]=gh[i*256+tid];
      __syncthreads();  // quarter s visible
    }
    bf16x8 af;
    if(s<2) af=*(const bf16x8*)&tA[row16][s*32+koff];
    else    af=*(const bf16x8*)&tH[row16][(s-2)*32+koff];
    #pragma unroll
    for(int t=0;t<16;t++){
      bf16x8 bf=*(const bf16x8*)(Bs+((size_t)t*64+l)*8);
      acc[t]=__builtin_amdgcn_mfma_f32_16x16x32_bf16(af,bf,acc[t],0,0,0);
    }
  }

  if(!act) return;
  // ---- epilogue: gates in-register; hold from tH (read before overwrite) ----
  float hn[16];
  #pragma unroll
  for(int t=0;t<4;t++){
    int d=t*16+l16;
    float br =bih[d]    +bhh[d];
    float bz =bih[64+d] +bhh[64+d];
    float bni=bih[128+d];
    float bnh=bhh[128+d];
    #pragma unroll
    for(int j=0;j<4;j++){
      float r  = sigmoidf_(acc[t][j]   + br);
      float z  = sigmoidf_(acc[4+t][j] + bz);
      float nc = tanhf_(acc[8+t][j] + bni + r*(acc[12+t][j] + bnh));
      float hold=bf2f(tH[(l>>4)*4+j][d]);
      hn[t*4+j]=(1.f-z)*nc + z*hold;
    }
  }
  // stage hn (bf16) into tH, then coalesced uint2 writeback (wave-lockstep: all hold reads precede)
  #pragma unroll
  for(int t=0;t<4;t++){
    int d=t*16+l16;
    #pragma unroll
    for(int j=0;j<4;j++)
      tH[(l>>4)*4+j][d]=f2bf(hn[t*4+j]);
  }
  #pragma unroll
  for(int i=0;i<4;i++){
    int rl=i*4+(l>>4);
    uint2 v=*(const uint2*)&tH[rl][l16*4];
    ((uint2*)hout)[(((unsigned)(gc*16+rl))<<4)+l16]=v;
  }
  if(last){
    // f32 feat via LDS transpose over the (now-free) tA+tH storage: float[16][68], 4352B <= 4608B
    float* ft=(float*)&tAH[w][0][0][0];
    #pragma unroll
    for(int t=0;t<4;t++){
      int d=t*16+l16;
      #pragma unroll
      for(int j=0;j<4;j++)
        ft[((l>>4)*4+j)*68+d]=hn[t*4+j];
    }
    #pragma unroll
    for(int i=0;i<4;i++){
      int rl=i*4+(l>>4);
      f32x4 v=*(const f32x4*)&ft[rl*68+l16*4];
      *(f32x4*)&h[(size_t)(gc*16+rl)*64+l16*4]=v;
    }
  }
}

// ======================= Set2Set: parallel attention partials =======================
__global__ __launch_bounds__(256) void k_attn_part(const unsigned short* __restrict__ hb, const int* __restrict__ batch,
                        const float* __restrict__ hl, float* __restrict__ apart, int n){
  int b=blockIdx.x/KB, kb=blockIdx.x%KB;
  int tid=threadIdx.x, lane=tid&63, w=tid>>6;
  __shared__ float qs[64];
  __shared__ float wm[4], wsm[4];
  __shared__ float wacc[4][64];
  if(tid<64) qs[tid]=hl[b*64+tid];
  int lo=lower_bound_i(batch,n,b), hi=lower_bound_i(batch,n,b+1);
  int cnt=hi-lo;
  int chunk=(cnt+KB-1)/KB;
  int slo=lo+kb*chunk, shi=min(slo+chunk,hi);
  __syncthreads();
  float q=qs[lane];
  float mw=-3.0e38f, sw=0.f, aw=0.f;
  for(int i=slo+w;i<shi;i+=4){
    float f=bf2f(hb[(size_t)i*64+lane]);
    float v=f*q;
    #pragma unroll
    for(int off=32;off;off>>=1) v+=__shfl_xor(v,off);
    if(v>mw){
      float sc=__expf(mw-v);
      sw=sw*sc+1.f;
      aw=aw*sc+f;
      mw=v;
    } else {
      float p=__expf(v-mw);
      sw+=p;
      aw+=p*f;
    }
  }
  if(lane==0){ wm[w]=mw; wsm[w]=sw; }
  wacc[w][lane]=aw;
  __syncthreads();
  if(w==0){
    float M=fmaxf(fmaxf(wm[0],wm[1]),fmaxf(wm[2],wm[3]));
    float S=0.f, A=0.f;
    #pragma unroll
    for(int k=0;k<4;k++){
      float sc=__expf(wm[k]-M);
      S+=wsm[k]*sc;
      A+=wacc[k][lane]*sc;
    }
    float* p=apart+(size_t)blockIdx.x*68;
    p[lane]=A;
    if(lane==0){ p[64]=M; p[65]=S; }
  }
}

// merge partials -> r_read (qstar[64:128]); optionally run next LSTM cell
__global__ __launch_bounds__(256) void k_merge_lstm(const float* __restrict__ apart,
                   float* __restrict__ qstar, float* __restrict__ hl, float* __restrict__ cl,
                   const float* __restrict__ wih, const float* __restrict__ whh,
                   const float* __restrict__ bih, const float* __restrict__ bhh,
                   int do_merge, int do_lstm){
  int b=blockIdx.x, tid=threadIdx.x;
  __shared__ float qs[128];
  __shared__ float gates[256];
  if(do_merge){
    if(tid<64){
      const float* p0=apart+(size_t)b*KB*68;
      float M=-3.0e38f;
      #pragma unroll
      for(int k=0;k<KB;k++) M=fmaxf(M,p0[k*68+64]);
      float S=0.f, A=0.f;
      #pragma unroll
      for(int k=0;k<KB;k++){
        float sc=__expf(p0[k*68+64]-M);
        S+=p0[k*68+65]*sc;
        A+=p0[k*68+tid]*sc;
      }
      float inv=(S>0.f)? 1.f/S:0.f;
      float r=A*inv;
      qs[64+tid]=r;
      qstar[b*128+64+tid]=r;
    }
  } else {
    if(tid<64) qs[64+tid]=qstar[b*128+64+tid];
  }
  if(tid<64) qs[tid]=hl[b*64+tid];   // q_t == previous LSTM hidden
  __syncthreads();
  if(!do_lstm) return;
  float acc=bih[tid]+bhh[tid];
  const float* wi=wih+(size_t)tid*128;
  #pragma unroll 8
  for(int k=0;k<128;k++) acc+=qs[k]*wi[k];
  const float* w2=whh+(size_t)tid*64;
  #pragma unroll 8
  for(int k=0;k<64;k++) acc+=qs[k]*w2[k];
  gates[tid]=acc;
  __syncthreads();
  if(tid<64){
    float i_=gates[tid], f_=gates[64+tid], g_=gates[128+tid], o_=gates[192+tid];
    float c=sigmoidf_(f_)*cl[b*64+tid]+sigmoidf_(i_)*tanhf(g_);
    float hn=sigmoidf_(o_)*tanhf(c);
    cl[b*64+tid]=c; hl[b*64+tid]=hn;
    qstar[b*128+tid]=hn;
  }
}

extern "C" void kernel_launch(void* const* d_in, const int* in_sizes, int n_in,
                              void* d_out, int out_size, void* d_ws, size_t ws_size,
                              hipStream_t stream){
  const float* x      =(const float*)d_in[0];
  const int*   ei     =(const int*)d_in[1];
  const int*   batch  =(const int*)d_in[2];
  const float* lin0_w =(const float*)d_in[3];
  const float* lin0_b =(const float*)d_in[4];
  const float* conv_w =(const float*)d_in[5];
  const float* conv_b =(const float*)d_in[6];
  const float* gwih   =(const float*)d_in[7];
  const float* gwhh   =(const float*)d_in[8];
  const float* gbih   =(const float*)d_in[9];
  const float* gbhh   =(const float*)d_in[10];
  const float* lwih   =(const float*)d_in[11];
  const float* lwhh   =(const float*)d_in[12];
  const float* lbih   =(const float*)d_in[13];
  const float* lbhh   =(const float*)d_in[14];

  int N = in_sizes[0]/FEATD;
  int E = in_sizes[1]/2;
  const int* row = ei;
  const int* col = ei + E;

  float* qstar = (float*)d_out;            // [256,128]
  float* h     = (float*)d_out + NB*2*DIM; // [N,64] 'feat' = f32 h (written by last k_gruagg)

  char* ws=(char*)d_ws;
  size_t off=0;
  auto alloc=[&](size_t bytes)->void*{ void* p=ws+off; off=(off+bytes+255)&~(size_t)255; return p; };
  int*   deg  =(int*)  alloc((size_t)N*4);
  float* dinv =(float*)alloc((size_t)N*4);
  int*   rp   =(int*)  alloc((size_t)(N+1)*4);
  int*   part =(int*)  alloc((size_t)SCB*4);
  int*   gcur =(int*)  alloc((size_t)NBUCKMAX*32*4);
  unsigned* tmp=(unsigned*)alloc((size_t)E*4);
  int2*  epack=(int2*) alloc((size_t)E*8);
  unsigned short* hb0  =(unsigned short*)alloc((size_t)N*64*2);
  unsigned short* hb1  =(unsigned short*)alloc((size_t)N*64*2);
  float* hl   =(float*)alloc((size_t)NB*DIM*4);
  float* cl   =(float*)alloc((size_t)NB*DIM*4);
  float* apart=(float*)alloc((size_t)NB*KB*68*4);
  unsigned short* Bgru =(unsigned short*)alloc(128*256*2);
  unsigned short* Blin =(unsigned short*)alloc(128*64*2);
  unsigned short* Bcnv =(unsigned short*)alloc(64*64*2);

  hipMemsetAsync(deg ,0,(size_t)N*4,stream);
  hipMemsetAsync(hl  ,0,(size_t)NB*DIM*4,stream);
  hipMemsetAsync(cl  ,0,(size_t)NB*DIM*4,stream);
  hipMemsetAsync(qstar,0,(size_t)NB*2*DIM*4,stream);

  int nbuck=(N+RNG-1)/RNG;

  k_count<<<(E+255)/256,256,0,stream>>>(col,deg,E);
  k_dinv <<<(N+255)/256,256,0,stream>>>(deg,dinv,N);
  k_scan_part<<<SCB,256,0,stream>>>(deg,part,N);
  k_scan_mid <<<1,256,0,stream>>>(part);
  k_scan_out <<<SCB,256,0,stream>>>(deg,part,rp,gcur,N);
  k_binscat<<<(E+CH1-1)/CH1,256,0,stream>>>(row,col,gcur,tmp,E,nbuck);
  k_place<<<nbuck,256,0,stream>>>(tmp,rp,dinv,epack,N,nbuck);

  k_prep_plain<<<(128*64+255)/256,256,0,stream>>>(lin0_w,Blin,128,64);
  k_prep_plain<<<(64*64+255)/256,256,0,stream>>>(conv_w,Bcnv,64,64);
  k_prep_gru  <<<(128*256+255)/256,256,0,stream>>>(gwih,gwhh,Bgru);

  int ngrp=(N+15)/16;
  int gb=(ngrp+3)/4;

  k_lin0<<<gb,256,0,stream>>>(x,Blin,lin0_b,hb0,ngrp);

  // h double-buffer: it0 hb0->hb1, it1 hb1->hb0, it2 hb0->hb1 (final in hb1)
  k_gruagg<<<gb,256,0,stream>>>(hb0,hb1,rp,epack,dinv,Bcnv,conv_b,Bgru,gbih,gbhh,h,0,ngrp,N);
  k_gruagg<<<gb,256,0,stream>>>(hb1,hb0,rp,epack,dinv,Bcnv,conv_b,Bgru,gbih,gbhh,h,0,ngrp,N);
  k_gruagg<<<gb,256,0,stream>>>(hb0,hb1,rp,epack,dinv,Bcnv,conv_b,Bgru,gbih,gbhh,h,1,ngrp,N);

  // Set2Set: lstm0; [attn, merge+lstm] x2; attn; merge(final)
  k_merge_lstm<<<NB,256,0,stream>>>(apart,qstar,hl,cl,lwih,lwhh,lbih,lbhh,0,1);
  for(int st=0;st<3;st++){
    k_attn_part<<<NB*KB,256,0,stream>>>(hb1,batch,hl,apart,N);
    int do_lstm = (st<2)? 1:0;
    k_merge_lstm<<<NB,256,0,stream>>>(apart,qstar,hl,cl,lwih,lwhh,lbih,lbhh,1,do_lstm);
  }
}